// Round 7
// baseline (245.381 us; speedup 1.0000x reference)
//
#include <hip/hip_runtime.h>
#include <stdint.h>

#define NB 64
#define NS 512
#define NC 256
#define NH 8
#define ND 32

typedef __attribute__((ext_vector_type(8))) short s8v;
typedef __attribute__((ext_vector_type(8))) unsigned short u8v;
typedef __attribute__((ext_vector_type(4))) float f4v;

#define LOG2E 1.4426950408889634f

static __device__ __forceinline__ uint16_t f2bf(float f) {
    uint32_t u = __builtin_bit_cast(uint32_t, f);
    u += 0x7fffu + ((u >> 16) & 1u);
    return (uint16_t)(u >> 16);
}
static __device__ __forceinline__ float bf2f(uint16_t h) {
    uint32_t u = ((uint32_t)h) << 16;
    return __builtin_bit_cast(float, u);
}
static __device__ __forceinline__ uint32_t cvtpk(float lo, float hi) {
    uint32_t r;
    asm("v_cvt_pk_bf16_f32 %0, %1, %2" : "=v"(r) : "v"(lo), "v"(hi));
    return r;
}

// ---------------- Kernel 0: bulk fp32 -> bf16 convert (n multiple of 2048) ----
__global__ __launch_bounds__(256) void cvt_f2bf(const float* __restrict__ in,
                                                uint16_t* __restrict__ out) {
    int i = (blockIdx.x * 256 + threadIdx.x) * 8;
    f4v a = *(const f4v*)(in + i);
    f4v b = *(const f4v*)(in + i + 4);
    uint4 w;
    w.x = cvtpk(a[0], a[1]); w.y = cvtpk(a[2], a[3]);
    w.z = cvtpk(b[0], b[1]); w.w = cvtpk(b[2], b[3]);
    *(uint4*)(out + i) = w;
}

// ---------------- Kernel 1: expand relative-position bias (pre-scaled by log2e)
__global__ __launch_bounds__(256) void bias_fill(const float* __restrict__ rel,
                                                 uint16_t* __restrict__ bias) {
    int id = blockIdx.x * 256 + threadIdx.x;       // 8*512*512 = 2M total
    int t = id & 511, s = (id >> 9) & 511, h = id >> 18;
    int ti = s >> 4, li = s & 15, tj = t >> 4, lj = t & 15;
    int ridx = ((((ti - tj + 31) << 4) + li) << 4) + lj;
    bias[id] = f2bf(rel[ridx * 8 + h] * LOG2E);
}

// ---------------- Kernel 2: QKV GEMM (A = bf16 X, B = fp32 W) ----------------
// writes q (scaled by SCALE*log2e, [bh][s][d]), k ([bh][s][d]), v^T ([bh][d][s])
__global__ __launch_bounds__(256) void qkv_gemm(const uint16_t* __restrict__ X,
                                                const float* __restrict__ W,
                                                const float* __restrict__ Bv,
                                                uint16_t* __restrict__ Qo,
                                                uint16_t* __restrict__ Ko,
                                                uint16_t* __restrict__ Vo) {
    __shared__ uint16_t As[128 * 40];
    __shared__ uint16_t Bs[128 * 40];
    const int tid = threadIdx.x;
    const int bn = blockIdx.x * 128;
    const int bm = blockIdx.y * 128;
    const int lane = tid & 63, wv = tid >> 6;
    const int wm = (wv >> 1) * 64, wn = (wv & 1) * 64;
    const int lq = lane & 15, g = lane >> 4;
    const int srow = tid >> 1;
    const int scol = (tid & 1) * 16;

    f4v acc[4][4] = {};

    for (int ks = 0; ks < 8; ++ks) {
        const int k0 = ks * 32;
        __syncthreads();
        {
            const uint16_t* src = X + (size_t)(bm + srow) * 256 + k0 + scol;
            u8v p0 = *(const u8v*)(src);
            u8v p1 = *(const u8v*)(src + 8);
            *(u8v*)(As + srow * 40 + scol)     = p0;
            *(u8v*)(As + srow * 40 + scol + 8) = p1;

            const float* srcb = W + (size_t)(bn + srow) * 256 + k0 + scol;
            f4v b0 = *(const f4v*)(srcb);
            f4v b1 = *(const f4v*)(srcb + 4);
            f4v b2 = *(const f4v*)(srcb + 8);
            f4v b3 = *(const f4v*)(srcb + 12);
            uint4 q0, q1;
            q0.x = cvtpk(b0[0], b0[1]); q0.y = cvtpk(b0[2], b0[3]);
            q0.z = cvtpk(b1[0], b1[1]); q0.w = cvtpk(b1[2], b1[3]);
            q1.x = cvtpk(b2[0], b2[1]); q1.y = cvtpk(b2[2], b2[3]);
            q1.z = cvtpk(b3[0], b3[1]); q1.w = cvtpk(b3[2], b3[3]);
            *(uint4*)(Bs + srow * 40 + scol)     = q0;
            *(uint4*)(Bs + srow * 40 + scol + 8) = q1;
        }
        __syncthreads();
        s8v af[4], bf[4];
        #pragma unroll
        for (int i = 0; i < 4; ++i) {
            af[i] = *(const s8v*)(As + (wm + i * 16 + lq) * 40 + g * 8);
            bf[i] = *(const s8v*)(Bs + (wn + i * 16 + lq) * 40 + g * 8);
        }
        #pragma unroll
        for (int mt = 0; mt < 4; ++mt)
            #pragma unroll
            for (int nt = 0; nt < 4; ++nt)
                acc[mt][nt] = __builtin_amdgcn_mfma_f32_16x16x32_bf16(af[mt], bf[nt], acc[mt][nt], 0, 0, 0);
    }

    const int gsel = bn >> 8;   // 0=q, 1=k, 2=v
    const float scl = (gsel == 0) ? (0.35355339059327373f * LOG2E) : 1.0f;
    #pragma unroll
    for (int nt = 0; nt < 4; ++nt) {
        const int ng = bn + wn + nt * 16 + lq;
        const float bv = Bv[ng];
        const int c = ng & 255, hh = c >> 5, dd = c & 31;
        #pragma unroll
        for (int mt = 0; mt < 4; ++mt) {
            #pragma unroll
            for (int r = 0; r < 4; ++r) {
                const int m = bm + wm + mt * 16 + g * 4 + r;
                const int b = m >> 9, s = m & 511;
                const uint16_t val = f2bf((acc[mt][nt][r] + bv) * scl);
                if (gsel == 0)      Qo[((size_t)(b * 8 + hh) * 512 + s) * 32 + dd] = val;
                else if (gsel == 1) Ko[((size_t)(b * 8 + hh) * 512 + s) * 32 + dd] = val;
                else                Vo[((size_t)(b * 8 + hh) * 32 + dd) * 512 + s] = val;
            }
        }
    }
}

// ---------------- Kernel 3: flash attention, online softmax, prefetched ------
// EXACT green (round-3) math: defer-rescale online softmax + in-register
// relayout PV. Only change: K+bias of tile t+1 and V of tile t are loaded at
// the top of iteration t (register double-buffer) to hide load latency.
// 1-D grid 4096, h = p&7 pins each head to one XCD.
__global__ __launch_bounds__(256) void attn_kern(const uint16_t* __restrict__ Q,
                                                 const uint16_t* __restrict__ K,
                                                 const uint16_t* __restrict__ V,
                                                 const uint16_t* __restrict__ BIAS,
                                                 uint16_t* __restrict__ AO) {
    const int p = blockIdx.x;
    const int h  = p & 7;                          // XCD-pinned head
    const int qt = (p >> 3) & 7;                   // qt fastest within an XCD
    const int b  = p >> 6;
    const int tid = threadIdx.x, lane = tid & 63, wv = tid >> 6;
    const int lq = lane & 15, g = lane >> 4;
    const bool godd = (g & 1);
    const bool ghi = (g >= 2);
    const int bh = b * 8 + h;
    const int qw = qt * 64 + wv * 16;              // window-local q base of wave

    s8v qf = *(const s8v*)(Q + ((size_t)bh * 512 + qw + lq) * 32 + g * 8);
    const uint16_t* kbase = K + (size_t)bh * 16384 + lq * 32 + g * 8;
    const uint16_t* vbase = V + (size_t)bh * 16384 + lq * 512 + g * 8;
    const uint16_t* bbase = BIAS + ((size_t)h * 512 + qw + lq) * 512 + g * 4;

    f4v o0 = {}, o1 = {};
    float mrow = -3.0e38f, lrow = 0.f;

    // ---- prefetch tile 0: K-frags + bias ----
    s8v kf0 = *(const s8v*)(kbase + 0 * 512);
    s8v kf1 = *(const s8v*)(kbase + 1 * 512);
    s8v kf2 = *(const s8v*)(kbase + 2 * 512);
    s8v kf3 = *(const s8v*)(kbase + 3 * 512);
    ushort4 bz0 = *(const ushort4*)(bbase + 0);
    ushort4 bz1 = *(const ushort4*)(bbase + 16);
    ushort4 bz2 = *(const ushort4*)(bbase + 32);
    ushort4 bz3 = *(const ushort4*)(bbase + 48);

    #pragma unroll 2
    for (int tile = 0; tile < 8; ++tile) {
        const int t0 = tile * 64;
        const int tn = (tile < 7) ? t0 + 64 : t0;  // clamped dummy on last iter

        // ---- issue-early loads: V of tile t, K+bias of tile t+1 ----
        s8v vf0 = *(const s8v*)(vbase + t0);
        s8v vf1 = *(const s8v*)(vbase + t0 + 32);
        s8v vf2 = *(const s8v*)(vbase + 8192 + t0);
        s8v vf3 = *(const s8v*)(vbase + 8192 + t0 + 32);
        s8v kn0 = *(const s8v*)(kbase + (tn +  0) * 32);
        s8v kn1 = *(const s8v*)(kbase + (tn + 16) * 32);
        s8v kn2 = *(const s8v*)(kbase + (tn + 32) * 32);
        s8v kn3 = *(const s8v*)(kbase + (tn + 48) * 32);
        ushort4 bn0 = *(const ushort4*)(bbase + tn);
        ushort4 bn1 = *(const ushort4*)(bbase + tn + 16);
        ushort4 bn2 = *(const ushort4*)(bbase + tn + 32);
        ushort4 bn3 = *(const ushort4*)(bbase + tn + 48);

        // ---- S-tile = bias (C-init) + K.Q^T, log2 domain ----
        f4v a0, a1, a2, a3;
        a0[0]=bf2f(bz0.x); a0[1]=bf2f(bz0.y); a0[2]=bf2f(bz0.z); a0[3]=bf2f(bz0.w);
        a1[0]=bf2f(bz1.x); a1[1]=bf2f(bz1.y); a1[2]=bf2f(bz1.z); a1[3]=bf2f(bz1.w);
        a2[0]=bf2f(bz2.x); a2[1]=bf2f(bz2.y); a2[2]=bf2f(bz2.z); a2[3]=bf2f(bz2.w);
        a3[0]=bf2f(bz3.x); a3[1]=bf2f(bz3.y); a3[2]=bf2f(bz3.z); a3[3]=bf2f(bz3.w);
        a0 = __builtin_amdgcn_mfma_f32_16x16x32_bf16(kf0, qf, a0, 0, 0, 0);
        a1 = __builtin_amdgcn_mfma_f32_16x16x32_bf16(kf1, qf, a1, 0, 0, 0);
        a2 = __builtin_amdgcn_mfma_f32_16x16x32_bf16(kf2, qf, a2, 0, 0, 0);
        a3 = __builtin_amdgcn_mfma_f32_16x16x32_bf16(kf3, qf, a3, 0, 0, 0);

        // ---- row max (green): row q = lq lives in lanes {lq,lq+16,lq+32,lq+48}
        float pmax = fmaxf(fmaxf(a0[0], a0[1]), fmaxf(a0[2], a0[3]));
        pmax = fmaxf(pmax, fmaxf(fmaxf(a1[0], a1[1]), fmaxf(a1[2], a1[3])));
        pmax = fmaxf(pmax, fmaxf(fmaxf(a2[0], a2[1]), fmaxf(a2[2], a2[3])));
        pmax = fmaxf(pmax, fmaxf(fmaxf(a3[0], a3[1]), fmaxf(a3[2], a3[3])));
        pmax = fmaxf(pmax, __shfl_xor(pmax, 16));
        pmax = fmaxf(pmax, __shfl_xor(pmax, 32));

        // ---- online-softmax update, defer-rescale threshold 8 (green) ----
        if (!__all(pmax - mrow <= 8.0f)) {
            float mnew = fmaxf(mrow, pmax);
            float scale = __builtin_amdgcn_exp2f(mrow - mnew);
            lrow *= scale;
            float s0 = __shfl(scale, g * 4 + 0);
            float s1 = __shfl(scale, g * 4 + 1);
            float s2 = __shfl(scale, g * 4 + 2);
            float s3 = __shfl(scale, g * 4 + 3);
            o0[0] *= s0; o0[1] *= s1; o0[2] *= s2; o0[3] *= s3;
            o1[0] *= s0; o1[1] *= s1; o1[2] *= s2; o1[3] *= s3;
            mrow = mnew;
        }

        // ---- P = exp2(S - m), per-lane partial row-sum (green) ----
        float lsum = 0.f;
        #pragma unroll
        for (int r = 0; r < 4; ++r) {
            a0[r] = __builtin_amdgcn_exp2f(a0[r] - mrow); lsum += a0[r];
            a1[r] = __builtin_amdgcn_exp2f(a1[r] - mrow); lsum += a1[r];
            a2[r] = __builtin_amdgcn_exp2f(a2[r] - mrow); lsum += a2[r];
            a3[r] = __builtin_amdgcn_exp2f(a3[r] - mrow); lsum += a3[r];
        }
        lrow += lsum;

        // ---- in-register re-layout P -> PV A-fragments (green) ----
        {   // tc = 0: P chunks a0,a1 ; V = vf0 (d 0-15), vf2 (d 16-31)
            uint32_t A0 = cvtpk(a0[0], a0[1]);
            uint32_t A1 = cvtpk(a0[2], a0[3]);
            uint32_t B0 = cvtpk(a1[0], a1[1]);
            uint32_t B1 = cvtpk(a1[2], a1[3]);
            uint32_t xA0 = (uint32_t)__shfl_xor((int)A0, 32);
            uint32_t xA1 = (uint32_t)__shfl_xor((int)A1, 32);
            uint32_t xB0 = (uint32_t)__shfl_xor((int)B0, 32);
            uint32_t xB1 = (uint32_t)__shfl_xor((int)B1, 32);
            uint32_t Ap0 = ghi ? xB0 : A0;
            uint32_t Ap1 = ghi ? xB1 : A1;
            uint32_t Bp0 = ghi ? B0 : xA0;
            uint32_t Bp1 = ghi ? B1 : xA1;
            uint32_t Z0 = godd ? Ap0 : Bp0;
            uint32_t Z1 = godd ? Ap1 : Bp1;
            uint32_t sZ0 = (uint32_t)__shfl_xor((int)Z0, 16);
            uint32_t sZ1 = (uint32_t)__shfl_xor((int)Z1, 16);
            uint4 wq;
            wq.x = godd ? sZ0 : Ap0;
            wq.y = godd ? sZ1 : Ap1;
            wq.z = godd ? Bp0 : sZ0;
            wq.w = godd ? Bp1 : sZ1;
            s8v pf = __builtin_bit_cast(s8v, wq);
            o0 = __builtin_amdgcn_mfma_f32_16x16x32_bf16(pf, vf0, o0, 0, 0, 0);
            o1 = __builtin_amdgcn_mfma_f32_16x16x32_bf16(pf, vf2, o1, 0, 0, 0);
        }
        {   // tc = 1: P chunks a2,a3 ; V = vf1, vf3
            uint32_t A0 = cvtpk(a2[0], a2[1]);
            uint32_t A1 = cvtpk(a2[2], a2[3]);
            uint32_t B0 = cvtpk(a3[0], a3[1]);
            uint32_t B1 = cvtpk(a3[2], a3[3]);
            uint32_t xA0 = (uint32_t)__shfl_xor((int)A0, 32);
            uint32_t xA1 = (uint32_t)__shfl_xor((int)A1, 32);
            uint32_t xB0 = (uint32_t)__shfl_xor((int)B0, 32);
            uint32_t xB1 = (uint32_t)__shfl_xor((int)B1, 32);
            uint32_t Ap0 = ghi ? xB0 : A0;
            uint32_t Ap1 = ghi ? xB1 : A1;
            uint32_t Bp0 = ghi ? B0 : xA0;
            uint32_t Bp1 = ghi ? B1 : xA1;
            uint32_t Z0 = godd ? Ap0 : Bp0;
            uint32_t Z1 = godd ? Ap1 : Bp1;
            uint32_t sZ0 = (uint32_t)__shfl_xor((int)Z0, 16);
            uint32_t sZ1 = (uint32_t)__shfl_xor((int)Z1, 16);
            uint4 wq;
            wq.x = godd ? sZ0 : Ap0;
            wq.y = godd ? sZ1 : Ap1;
            wq.z = godd ? Bp0 : sZ0;
            wq.w = godd ? Bp1 : sZ1;
            s8v pf = __builtin_bit_cast(s8v, wq);
            o0 = __builtin_amdgcn_mfma_f32_16x16x32_bf16(pf, vf1, o0, 0, 0, 0);
            o1 = __builtin_amdgcn_mfma_f32_16x16x32_bf16(pf, vf3, o1, 0, 0, 0);
        }

        // ---- rotate double-buffer ----
        kf0 = kn0; kf1 = kn1; kf2 = kn2; kf3 = kn3;
        bz0 = bn0; bz1 = bn1; bz2 = bn2; bz3 = bn3;
    }

    // ---- finalize: row sum across g, normalize, store (green) ----
    lrow += __shfl_xor(lrow, 16);
    lrow += __shfl_xor(lrow, 32);
    const float inv = 1.0f / lrow;                 // valid for row lq
    #pragma unroll
    for (int r = 0; r < 4; ++r) {
        const float iv = __shfl(inv, g * 4 + r);   // row g*4+r's denom
        const int srow = b * 512 + qw + g * 4 + r;
        uint16_t* dst = AO + (size_t)srow * 256 + h * 32 + lq;
        dst[0]  = f2bf(o0[r] * iv);
        dst[16] = f2bf(o1[r] * iv);
    }
}

// ---------------- Kernel 4: output projection ----------------
__global__ __launch_bounds__(256) void proj_gemm(const uint16_t* __restrict__ A,
                                                 const float* __restrict__ W,
                                                 const float* __restrict__ Bv,
                                                 float* __restrict__ Out) {
    __shared__ uint16_t As[128 * 40];
    __shared__ uint16_t Bs[128 * 40];
    const int tid = threadIdx.x;
    const int bn = blockIdx.x * 128;
    const int bm = blockIdx.y * 128;
    const int lane = tid & 63, wv = tid >> 6;
    const int wm = (wv >> 1) * 64, wn = (wv & 1) * 64;
    const int lq = lane & 15, g = lane >> 4;
    const int srow = tid >> 1;
    const int scol = (tid & 1) * 16;

    f4v acc[4][4] = {};

    for (int ks = 0; ks < 8; ++ks) {
        const int k0 = ks * 32;
        __syncthreads();
        {
            const uint16_t* src = A + (size_t)(bm + srow) * 256 + k0 + scol;
            u8v p0 = *(const u8v*)(src);
            u8v p1 = *(const u8v*)(src + 8);
            *(u8v*)(As + srow * 40 + scol)     = p0;
            *(u8v*)(As + srow * 40 + scol + 8) = p1;

            const float* srcb = W + (size_t)(bn + srow) * 256 + k0 + scol;
            f4v b0 = *(const f4v*)(srcb);
            f4v b1 = *(const f4v*)(srcb + 4);
            f4v b2 = *(const f4v*)(srcb + 8);
            f4v b3 = *(const f4v*)(srcb + 12);
            uint4 q0, q1;
            q0.x = cvtpk(b0[0], b0[1]); q0.y = cvtpk(b0[2], b0[3]);
            q0.z = cvtpk(b1[0], b1[1]); q0.w = cvtpk(b1[2], b1[3]);
            q1.x = cvtpk(b2[0], b2[1]); q1.y = cvtpk(b2[2], b2[3]);
            q1.z = cvtpk(b3[0], b3[1]); q1.w = cvtpk(b3[2], b3[3]);
            *(uint4*)(Bs + srow * 40 + scol)     = q0;
            *(uint4*)(Bs + srow * 40 + scol + 8) = q1;
        }
        __syncthreads();
        s8v af[4], bf[4];
        #pragma unroll
        for (int i = 0; i < 4; ++i) {
            af[i] = *(const s8v*)(As + (wm + i * 16 + lq) * 40 + g * 8);
            bf[i] = *(const s8v*)(Bs + (wn + i * 16 + lq) * 40 + g * 8);
        }
        #pragma unroll
        for (int mt = 0; mt < 4; ++mt)
            #pragma unroll
            for (int nt = 0; nt < 4; ++nt)
                acc[mt][nt] = __builtin_amdgcn_mfma_f32_16x16x32_bf16(af[mt], bf[nt], acc[mt][nt], 0, 0, 0);
    }

    #pragma unroll
    for (int nt = 0; nt < 4; ++nt) {
        const int n = bn + wn + nt * 16 + lq;
        const float bv = Bv[n];
        #pragma unroll
        for (int mt = 0; mt < 4; ++mt) {
            #pragma unroll
            for (int r = 0; r < 4; ++r) {
                const int mm = bm + wm + mt * 16 + g * 4 + r;
                Out[(size_t)mm * 256 + n] = acc[mt][nt][r] + bv;
            }
        }
    }
}

extern "C" void kernel_launch(void* const* d_in, const int* in_sizes, int n_in,
                              void* d_out, int out_size, void* d_ws, size_t ws_size,
                              hipStream_t stream) {
    const float* x      = (const float*)d_in[0];
    const float* qkv_w  = (const float*)d_in[1];
    const float* qkv_b  = (const float*)d_in[2];
    const float* proj_w = (const float*)d_in[3];
    const float* proj_b = (const float*)d_in[4];
    const float* rel    = (const float*)d_in[5];
    float* out = (float*)d_out;

    uint16_t* ws = (uint16_t*)d_ws;
    const size_t QE = (size_t)NB * NH * NS * ND;          // 8,388,608 elems
    uint16_t* Qb   = ws;                                  // 16 MiB
    uint16_t* Kb   = Qb + QE;                             // 16 MiB
    uint16_t* Vb   = Kb + QE;                             // 16 MiB
    uint16_t* Rb   = Vb + QE;                             // 16 MiB: Xbf, then AO
    uint16_t* BIAS = Rb + QE;                             // 4 MiB (2M elems)

    cvt_f2bf<<<4096, 256, 0, stream>>>(x, Rb);            // X -> bf16
    bias_fill<<<8192, 256, 0, stream>>>(rel, BIAS);
    qkv_gemm<<<dim3(6, 256), 256, 0, stream>>>(Rb, qkv_w, qkv_b, Qb, Kb, Vb);
    attn_kern<<<4096, 256, 0, stream>>>(Qb, Kb, Vb, BIAS, Rb);
    proj_gemm<<<dim3(2, 256), 256, 0, stream>>>(Rb, proj_w, proj_b, out);
}

// Round 8
// 235.456 us; speedup vs baseline: 1.0422x; 1.0422x over previous
//
#include <hip/hip_runtime.h>
#include <stdint.h>

#define NB 64
#define NS 512
#define NC 256
#define NH 8
#define ND 32

typedef __attribute__((ext_vector_type(8))) short s8v;
typedef __attribute__((ext_vector_type(8))) unsigned short u8v;
typedef __attribute__((ext_vector_type(4))) float f4v;

#define LOG2E 1.4426950408889634f

static __device__ __forceinline__ uint16_t f2bf(float f) {
    uint32_t u = __builtin_bit_cast(uint32_t, f);
    u += 0x7fffu + ((u >> 16) & 1u);
    return (uint16_t)(u >> 16);
}
static __device__ __forceinline__ float bf2f(uint16_t h) {
    uint32_t u = ((uint32_t)h) << 16;
    return __builtin_bit_cast(float, u);
}
static __device__ __forceinline__ uint32_t cvtpk(float lo, float hi) {
    uint32_t r;
    asm("v_cvt_pk_bf16_f32 %0, %1, %2" : "=v"(r) : "v"(lo), "v"(hi));
    return r;
}

// ---------------- Kernel 0: bulk fp32 -> bf16 convert (n multiple of 2048) ----
__global__ __launch_bounds__(256) void cvt_f2bf(const float* __restrict__ in,
                                                uint16_t* __restrict__ out) {
    int i = (blockIdx.x * 256 + threadIdx.x) * 8;
    f4v a = *(const f4v*)(in + i);
    f4v b = *(const f4v*)(in + i + 4);
    uint4 w;
    w.x = cvtpk(a[0], a[1]); w.y = cvtpk(a[2], a[3]);
    w.z = cvtpk(b[0], b[1]); w.w = cvtpk(b[2], b[3]);
    *(uint4*)(out + i) = w;
}

// ---------------- Kernel 1: expand relative-position bias (pre-scaled by log2e)
__global__ __launch_bounds__(256) void bias_fill(const float* __restrict__ rel,
                                                 uint16_t* __restrict__ bias) {
    int id = blockIdx.x * 256 + threadIdx.x;       // 8*512*512 = 2M total
    int t = id & 511, s = (id >> 9) & 511, h = id >> 18;
    int ti = s >> 4, li = s & 15, tj = t >> 4, lj = t & 15;
    int ridx = ((((ti - tj + 31) << 4) + li) << 4) + lj;
    bias[id] = f2bf(rel[ridx * 8 + h] * LOG2E);
}

// ---------------- Kernel 2: QKV GEMM (A = bf16 X, B = fp32 W) ----------------
// writes q (scaled by SCALE*log2e, [bh][s][d]), k ([bh][s][d]), v^T ([bh][d][s])
__global__ __launch_bounds__(256) void qkv_gemm(const uint16_t* __restrict__ X,
                                                const float* __restrict__ W,
                                                const float* __restrict__ Bv,
                                                uint16_t* __restrict__ Qo,
                                                uint16_t* __restrict__ Ko,
                                                uint16_t* __restrict__ Vo) {
    __shared__ uint16_t As[128 * 40];
    __shared__ uint16_t Bs[128 * 40];
    const int tid = threadIdx.x;
    const int bn = blockIdx.x * 128;
    const int bm = blockIdx.y * 128;
    const int lane = tid & 63, wv = tid >> 6;
    const int wm = (wv >> 1) * 64, wn = (wv & 1) * 64;
    const int lq = lane & 15, g = lane >> 4;
    const int srow = tid >> 1;
    const int scol = (tid & 1) * 16;

    f4v acc[4][4] = {};

    for (int ks = 0; ks < 8; ++ks) {
        const int k0 = ks * 32;
        __syncthreads();
        {
            const uint16_t* src = X + (size_t)(bm + srow) * 256 + k0 + scol;
            u8v p0 = *(const u8v*)(src);
            u8v p1 = *(const u8v*)(src + 8);
            *(u8v*)(As + srow * 40 + scol)     = p0;
            *(u8v*)(As + srow * 40 + scol + 8) = p1;

            const float* srcb = W + (size_t)(bn + srow) * 256 + k0 + scol;
            f4v b0 = *(const f4v*)(srcb);
            f4v b1 = *(const f4v*)(srcb + 4);
            f4v b2 = *(const f4v*)(srcb + 8);
            f4v b3 = *(const f4v*)(srcb + 12);
            uint4 q0, q1;
            q0.x = cvtpk(b0[0], b0[1]); q0.y = cvtpk(b0[2], b0[3]);
            q0.z = cvtpk(b1[0], b1[1]); q0.w = cvtpk(b1[2], b1[3]);
            q1.x = cvtpk(b2[0], b2[1]); q1.y = cvtpk(b2[2], b2[3]);
            q1.z = cvtpk(b3[0], b3[1]); q1.w = cvtpk(b3[2], b3[3]);
            *(uint4*)(Bs + srow * 40 + scol)     = q0;
            *(uint4*)(Bs + srow * 40 + scol + 8) = q1;
        }
        __syncthreads();
        s8v af[4], bf[4];
        #pragma unroll
        for (int i = 0; i < 4; ++i) {
            af[i] = *(const s8v*)(As + (wm + i * 16 + lq) * 40 + g * 8);
            bf[i] = *(const s8v*)(Bs + (wn + i * 16 + lq) * 40 + g * 8);
        }
        #pragma unroll
        for (int mt = 0; mt < 4; ++mt)
            #pragma unroll
            for (int nt = 0; nt < 4; ++nt)
                acc[mt][nt] = __builtin_amdgcn_mfma_f32_16x16x32_bf16(af[mt], bf[nt], acc[mt][nt], 0, 0, 0);
    }

    const int gsel = bn >> 8;   // 0=q, 1=k, 2=v
    const float scl = (gsel == 0) ? (0.35355339059327373f * LOG2E) : 1.0f;
    #pragma unroll
    for (int nt = 0; nt < 4; ++nt) {
        const int ng = bn + wn + nt * 16 + lq;
        const float bv = Bv[ng];
        const int c = ng & 255, hh = c >> 5, dd = c & 31;
        #pragma unroll
        for (int mt = 0; mt < 4; ++mt) {
            #pragma unroll
            for (int r = 0; r < 4; ++r) {
                const int m = bm + wm + mt * 16 + g * 4 + r;
                const int b = m >> 9, s = m & 511;
                const uint16_t val = f2bf((acc[mt][nt][r] + bv) * scl);
                if (gsel == 0)      Qo[((size_t)(b * 8 + hh) * 512 + s) * 32 + dd] = val;
                else if (gsel == 1) Ko[((size_t)(b * 8 + hh) * 512 + s) * 32 + dd] = val;
                else                Vo[((size_t)(b * 8 + hh) * 32 + dd) * 512 + s] = val;
            }
        }
    }
}

// ---------------- Kernel 3: flash attention, DUAL softmax states -------------
// Green (round-4) math per state. State A handles tiles {0,2,4,6}, state B
// {1,3,5,7}; the two dependency chains are independent -> the SIMD scheduler
// interleaves them, halving effective serial latency. End merge is the
// standard split-K flash combine. 1-D grid 4096, h = p&7 pins heads to XCDs.
__global__ __launch_bounds__(256) void attn_kern(const uint16_t* __restrict__ Q,
                                                 const uint16_t* __restrict__ K,
                                                 const uint16_t* __restrict__ V,
                                                 const uint16_t* __restrict__ BIAS,
                                                 uint16_t* __restrict__ AO) {
    const int p = blockIdx.x;
    const int h  = p & 7;                          // XCD-pinned head
    const int qt = (p >> 3) & 7;
    const int b  = p >> 6;
    const int tid = threadIdx.x, lane = tid & 63, wv = tid >> 6;
    const int lq = lane & 15, g = lane >> 4;
    const bool godd = (g & 1);
    const bool ghi = (g >= 2);
    const int bh = b * 8 + h;
    const int qw = qt * 64 + wv * 16;              // window-local q base of wave

    s8v qf = *(const s8v*)(Q + ((size_t)bh * 512 + qw + lq) * 32 + g * 8);
    const uint16_t* kbase = K + (size_t)bh * 16384 + lq * 32 + g * 8;
    const uint16_t* vbase = V + (size_t)bh * 16384 + lq * 512 + g * 8;
    const uint16_t* bbase = BIAS + ((size_t)h * 512 + qw + lq) * 512 + g * 4;

    f4v oA0 = {}, oA1 = {}, oB0 = {}, oB1 = {};
    float mA = -3.0e38f, lA = 0.f;
    float mB = -3.0e38f, lB = 0.f;

    for (int it = 0; it < 4; ++it) {
        const int tA = it * 128;
        const int tB = tA + 64;

        // ======== QK^T tile A (bias C-init), log2 domain ========
        f4v a0, a1, a2, a3;
        {
            ushort4 z0 = *(const ushort4*)(bbase + tA);
            ushort4 z1 = *(const ushort4*)(bbase + tA + 16);
            ushort4 z2 = *(const ushort4*)(bbase + tA + 32);
            ushort4 z3 = *(const ushort4*)(bbase + tA + 48);
            a0[0]=bf2f(z0.x); a0[1]=bf2f(z0.y); a0[2]=bf2f(z0.z); a0[3]=bf2f(z0.w);
            a1[0]=bf2f(z1.x); a1[1]=bf2f(z1.y); a1[2]=bf2f(z1.z); a1[3]=bf2f(z1.w);
            a2[0]=bf2f(z2.x); a2[1]=bf2f(z2.y); a2[2]=bf2f(z2.z); a2[3]=bf2f(z2.w);
            a3[0]=bf2f(z3.x); a3[1]=bf2f(z3.y); a3[2]=bf2f(z3.z); a3[3]=bf2f(z3.w);
            a0 = __builtin_amdgcn_mfma_f32_16x16x32_bf16(*(const s8v*)(kbase + (tA +  0) * 32), qf, a0, 0, 0, 0);
            a1 = __builtin_amdgcn_mfma_f32_16x16x32_bf16(*(const s8v*)(kbase + (tA + 16) * 32), qf, a1, 0, 0, 0);
            a2 = __builtin_amdgcn_mfma_f32_16x16x32_bf16(*(const s8v*)(kbase + (tA + 32) * 32), qf, a2, 0, 0, 0);
            a3 = __builtin_amdgcn_mfma_f32_16x16x32_bf16(*(const s8v*)(kbase + (tA + 48) * 32), qf, a3, 0, 0, 0);
        }
        // ======== QK^T tile B ========
        f4v c0, c1, c2, c3;
        {
            ushort4 z0 = *(const ushort4*)(bbase + tB);
            ushort4 z1 = *(const ushort4*)(bbase + tB + 16);
            ushort4 z2 = *(const ushort4*)(bbase + tB + 32);
            ushort4 z3 = *(const ushort4*)(bbase + tB + 48);
            c0[0]=bf2f(z0.x); c0[1]=bf2f(z0.y); c0[2]=bf2f(z0.z); c0[3]=bf2f(z0.w);
            c1[0]=bf2f(z1.x); c1[1]=bf2f(z1.y); c1[2]=bf2f(z1.z); c1[3]=bf2f(z1.w);
            c2[0]=bf2f(z2.x); c2[1]=bf2f(z2.y); c2[2]=bf2f(z2.z); c2[3]=bf2f(z2.w);
            c3[0]=bf2f(z3.x); c3[1]=bf2f(z3.y); c3[2]=bf2f(z3.z); c3[3]=bf2f(z3.w);
            c0 = __builtin_amdgcn_mfma_f32_16x16x32_bf16(*(const s8v*)(kbase + (tB +  0) * 32), qf, c0, 0, 0, 0);
            c1 = __builtin_amdgcn_mfma_f32_16x16x32_bf16(*(const s8v*)(kbase + (tB + 16) * 32), qf, c1, 0, 0, 0);
            c2 = __builtin_amdgcn_mfma_f32_16x16x32_bf16(*(const s8v*)(kbase + (tB + 32) * 32), qf, c2, 0, 0, 0);
            c3 = __builtin_amdgcn_mfma_f32_16x16x32_bf16(*(const s8v*)(kbase + (tB + 48) * 32), qf, c3, 0, 0, 0);
        }

        // ======== softmax A (green defer-rescale) ========
        {
            float p01 = fmaxf(fmaxf(a0[0], a0[1]), fmaxf(a0[2], a0[3]));
            float p23 = fmaxf(fmaxf(a1[0], a1[1]), fmaxf(a1[2], a1[3]));
            float p45 = fmaxf(fmaxf(a2[0], a2[1]), fmaxf(a2[2], a2[3]));
            float p67 = fmaxf(fmaxf(a3[0], a3[1]), fmaxf(a3[2], a3[3]));
            float pmax = fmaxf(fmaxf(p01, p23), fmaxf(p45, p67));
            pmax = fmaxf(pmax, __shfl_xor(pmax, 16));
            pmax = fmaxf(pmax, __shfl_xor(pmax, 32));
            if (!__all(pmax - mA <= 8.0f)) {
                float mnew = fmaxf(mA, pmax);
                float scale = __builtin_amdgcn_exp2f(mA - mnew);
                lA *= scale;
                float s0 = __shfl(scale, g * 4 + 0);
                float s1 = __shfl(scale, g * 4 + 1);
                float s2 = __shfl(scale, g * 4 + 2);
                float s3 = __shfl(scale, g * 4 + 3);
                oA0[0] *= s0; oA0[1] *= s1; oA0[2] *= s2; oA0[3] *= s3;
                oA1[0] *= s0; oA1[1] *= s1; oA1[2] *= s2; oA1[3] *= s3;
                mA = mnew;
            }
            float lsum = 0.f;
            #pragma unroll
            for (int r = 0; r < 4; ++r) {
                a0[r] = __builtin_amdgcn_exp2f(a0[r] - mA); lsum += a0[r];
                a1[r] = __builtin_amdgcn_exp2f(a1[r] - mA); lsum += a1[r];
                a2[r] = __builtin_amdgcn_exp2f(a2[r] - mA); lsum += a2[r];
                a3[r] = __builtin_amdgcn_exp2f(a3[r] - mA); lsum += a3[r];
            }
            lA += lsum;
        }
        // ======== softmax B ========
        {
            float p01 = fmaxf(fmaxf(c0[0], c0[1]), fmaxf(c0[2], c0[3]));
            float p23 = fmaxf(fmaxf(c1[0], c1[1]), fmaxf(c1[2], c1[3]));
            float p45 = fmaxf(fmaxf(c2[0], c2[1]), fmaxf(c2[2], c2[3]));
            float p67 = fmaxf(fmaxf(c3[0], c3[1]), fmaxf(c3[2], c3[3]));
            float pmax = fmaxf(fmaxf(p01, p23), fmaxf(p45, p67));
            pmax = fmaxf(pmax, __shfl_xor(pmax, 16));
            pmax = fmaxf(pmax, __shfl_xor(pmax, 32));
            if (!__all(pmax - mB <= 8.0f)) {
                float mnew = fmaxf(mB, pmax);
                float scale = __builtin_amdgcn_exp2f(mB - mnew);
                lB *= scale;
                float s0 = __shfl(scale, g * 4 + 0);
                float s1 = __shfl(scale, g * 4 + 1);
                float s2 = __shfl(scale, g * 4 + 2);
                float s3 = __shfl(scale, g * 4 + 3);
                oB0[0] *= s0; oB0[1] *= s1; oB0[2] *= s2; oB0[3] *= s3;
                oB1[0] *= s0; oB1[1] *= s1; oB1[2] *= s2; oB1[3] *= s3;
                mB = mnew;
            }
            float lsum = 0.f;
            #pragma unroll
            for (int r = 0; r < 4; ++r) {
                c0[r] = __builtin_amdgcn_exp2f(c0[r] - mB); lsum += c0[r];
                c1[r] = __builtin_amdgcn_exp2f(c1[r] - mB); lsum += c1[r];
                c2[r] = __builtin_amdgcn_exp2f(c2[r] - mB); lsum += c2[r];
                c3[r] = __builtin_amdgcn_exp2f(c3[r] - mB); lsum += c3[r];
            }
            lB += lsum;
        }

        // ======== relayout + PV, tile A (green verbatim) ========
        {   // tc = 0: chunks a0,a1 ; V = vbase+tA (d 0-15), +8192 (d 16-31)
            uint32_t A0 = cvtpk(a0[0], a0[1]);
            uint32_t A1 = cvtpk(a0[2], a0[3]);
            uint32_t B0 = cvtpk(a1[0], a1[1]);
            uint32_t B1 = cvtpk(a1[2], a1[3]);
            uint32_t xA0 = (uint32_t)__shfl_xor((int)A0, 32);
            uint32_t xA1 = (uint32_t)__shfl_xor((int)A1, 32);
            uint32_t xB0 = (uint32_t)__shfl_xor((int)B0, 32);
            uint32_t xB1 = (uint32_t)__shfl_xor((int)B1, 32);
            uint32_t Ap0 = ghi ? xB0 : A0, Ap1 = ghi ? xB1 : A1;
            uint32_t Bp0 = ghi ? B0 : xA0, Bp1 = ghi ? B1 : xA1;
            uint32_t Z0 = godd ? Ap0 : Bp0, Z1 = godd ? Ap1 : Bp1;
            uint32_t sZ0 = (uint32_t)__shfl_xor((int)Z0, 16);
            uint32_t sZ1 = (uint32_t)__shfl_xor((int)Z1, 16);
            uint4 wq;
            wq.x = godd ? sZ0 : Ap0; wq.y = godd ? sZ1 : Ap1;
            wq.z = godd ? Bp0 : sZ0; wq.w = godd ? Bp1 : sZ1;
            s8v pf = __builtin_bit_cast(s8v, wq);
            oA0 = __builtin_amdgcn_mfma_f32_16x16x32_bf16(pf, *(const s8v*)(vbase + tA),        oA0, 0, 0, 0);
            oA1 = __builtin_amdgcn_mfma_f32_16x16x32_bf16(pf, *(const s8v*)(vbase + 8192 + tA), oA1, 0, 0, 0);
        }
        {   // tc = 1: chunks a2,a3 ; V = vbase+tA+32, +8192+32
            uint32_t A0 = cvtpk(a2[0], a2[1]);
            uint32_t A1 = cvtpk(a2[2], a2[3]);
            uint32_t B0 = cvtpk(a3[0], a3[1]);
            uint32_t B1 = cvtpk(a3[2], a3[3]);
            uint32_t xA0 = (uint32_t)__shfl_xor((int)A0, 32);
            uint32_t xA1 = (uint32_t)__shfl_xor((int)A1, 32);
            uint32_t xB0 = (uint32_t)__shfl_xor((int)B0, 32);
            uint32_t xB1 = (uint32_t)__shfl_xor((int)B1, 32);
            uint32_t Ap0 = ghi ? xB0 : A0, Ap1 = ghi ? xB1 : A1;
            uint32_t Bp0 = ghi ? B0 : xA0, Bp1 = ghi ? B1 : xA1;
            uint32_t Z0 = godd ? Ap0 : Bp0, Z1 = godd ? Ap1 : Bp1;
            uint32_t sZ0 = (uint32_t)__shfl_xor((int)Z0, 16);
            uint32_t sZ1 = (uint32_t)__shfl_xor((int)Z1, 16);
            uint4 wq;
            wq.x = godd ? sZ0 : Ap0; wq.y = godd ? sZ1 : Ap1;
            wq.z = godd ? Bp0 : sZ0; wq.w = godd ? Bp1 : sZ1;
            s8v pf = __builtin_bit_cast(s8v, wq);
            oA0 = __builtin_amdgcn_mfma_f32_16x16x32_bf16(pf, *(const s8v*)(vbase + tA + 32),        oA0, 0, 0, 0);
            oA1 = __builtin_amdgcn_mfma_f32_16x16x32_bf16(pf, *(const s8v*)(vbase + 8192 + tA + 32), oA1, 0, 0, 0);
        }
        // ======== relayout + PV, tile B ========
        {   // tc = 0: chunks c0,c1
            uint32_t A0 = cvtpk(c0[0], c0[1]);
            uint32_t A1 = cvtpk(c0[2], c0[3]);
            uint32_t B0 = cvtpk(c1[0], c1[1]);
            uint32_t B1 = cvtpk(c1[2], c1[3]);
            uint32_t xA0 = (uint32_t)__shfl_xor((int)A0, 32);
            uint32_t xA1 = (uint32_t)__shfl_xor((int)A1, 32);
            uint32_t xB0 = (uint32_t)__shfl_xor((int)B0, 32);
            uint32_t xB1 = (uint32_t)__shfl_xor((int)B1, 32);
            uint32_t Ap0 = ghi ? xB0 : A0, Ap1 = ghi ? xB1 : A1;
            uint32_t Bp0 = ghi ? B0 : xA0, Bp1 = ghi ? B1 : xA1;
            uint32_t Z0 = godd ? Ap0 : Bp0, Z1 = godd ? Ap1 : Bp1;
            uint32_t sZ0 = (uint32_t)__shfl_xor((int)Z0, 16);
            uint32_t sZ1 = (uint32_t)__shfl_xor((int)Z1, 16);
            uint4 wq;
            wq.x = godd ? sZ0 : Ap0; wq.y = godd ? sZ1 : Ap1;
            wq.z = godd ? Bp0 : sZ0; wq.w = godd ? Bp1 : sZ1;
            s8v pf = __builtin_bit_cast(s8v, wq);
            oB0 = __builtin_amdgcn_mfma_f32_16x16x32_bf16(pf, *(const s8v*)(vbase + tB),        oB0, 0, 0, 0);
            oB1 = __builtin_amdgcn_mfma_f32_16x16x32_bf16(pf, *(const s8v*)(vbase + 8192 + tB), oB1, 0, 0, 0);
        }
        {   // tc = 1: chunks c2,c3
            uint32_t A0 = cvtpk(c2[0], c2[1]);
            uint32_t A1 = cvtpk(c2[2], c2[3]);
            uint32_t B0 = cvtpk(c3[0], c3[1]);
            uint32_t B1 = cvtpk(c3[2], c3[3]);
            uint32_t xA0 = (uint32_t)__shfl_xor((int)A0, 32);
            uint32_t xA1 = (uint32_t)__shfl_xor((int)A1, 32);
            uint32_t xB0 = (uint32_t)__shfl_xor((int)B0, 32);
            uint32_t xB1 = (uint32_t)__shfl_xor((int)B1, 32);
            uint32_t Ap0 = ghi ? xB0 : A0, Ap1 = ghi ? xB1 : A1;
            uint32_t Bp0 = ghi ? B0 : xA0, Bp1 = ghi ? B1 : xA1;
            uint32_t Z0 = godd ? Ap0 : Bp0, Z1 = godd ? Ap1 : Bp1;
            uint32_t sZ0 = (uint32_t)__shfl_xor((int)Z0, 16);
            uint32_t sZ1 = (uint32_t)__shfl_xor((int)Z1, 16);
            uint4 wq;
            wq.x = godd ? sZ0 : Ap0; wq.y = godd ? sZ1 : Ap1;
            wq.z = godd ? Bp0 : sZ0; wq.w = godd ? Bp1 : sZ1;
            s8v pf = __builtin_bit_cast(s8v, wq);
            oB0 = __builtin_amdgcn_mfma_f32_16x16x32_bf16(pf, *(const s8v*)(vbase + tB + 32),        oB0, 0, 0, 0);
            oB1 = __builtin_amdgcn_mfma_f32_16x16x32_bf16(pf, *(const s8v*)(vbase + 8192 + tB + 32), oB1, 0, 0, 0);
        }
    }

    // ======== merge states (split-K flash combine) + store ========
    const float mM = fmaxf(mA, mB);
    const float sA = __builtin_amdgcn_exp2f(mA - mM);
    const float sB = __builtin_amdgcn_exp2f(mB - mM);
    float lsum = lA * sA + lB * sB;
    lsum += __shfl_xor(lsum, 16);
    lsum += __shfl_xor(lsum, 32);
    const float inv = 1.0f / lsum;                 // valid for row lq
    #pragma unroll
    for (int r = 0; r < 4; ++r) {
        const float sAr = __shfl(sA, g * 4 + r);   // row g*4+r's state-A scale
        const float sBr = __shfl(sB, g * 4 + r);
        const float ivr = __shfl(inv, g * 4 + r);
        const int srow = b * 512 + qw + g * 4 + r;
        uint16_t* dst = AO + (size_t)srow * 256 + h * 32 + lq;
        dst[0]  = f2bf((oA0[r] * sAr + oB0[r] * sBr) * ivr);
        dst[16] = f2bf((oA1[r] * sAr + oB1[r] * sBr) * ivr);
    }
}

// ---------------- Kernel 4: output projection ----------------
__global__ __launch_bounds__(256) void proj_gemm(const uint16_t* __restrict__ A,
                                                 const float* __restrict__ W,
                                                 const float* __restrict__ Bv,
                                                 float* __restrict__ Out) {
    __shared__ uint16_t As[128 * 40];
    __shared__ uint16_t Bs[128 * 40];
    const int tid = threadIdx.x;
    const int bn = blockIdx.x * 128;
    const int bm = blockIdx.y * 128;
    const int lane = tid & 63, wv = tid >> 6;
    const int wm = (wv >> 1) * 64, wn = (wv & 1) * 64;
    const int lq = lane & 15, g = lane >> 4;
    const int srow = tid >> 1;
    const int scol = (tid & 1) * 16;

    f4v acc[4][4] = {};

    for (int ks = 0; ks < 8; ++ks) {
        const int k0 = ks * 32;
        __syncthreads();
        {
            const uint16_t* src = A + (size_t)(bm + srow) * 256 + k0 + scol;
            u8v p0 = *(const u8v*)(src);
            u8v p1 = *(const u8v*)(src + 8);
            *(u8v*)(As + srow * 40 + scol)     = p0;
            *(u8v*)(As + srow * 40 + scol + 8) = p1;

            const float* srcb = W + (size_t)(bn + srow) * 256 + k0 + scol;
            f4v b0 = *(const f4v*)(srcb);
            f4v b1 = *(const f4v*)(srcb + 4);
            f4v b2 = *(const f4v*)(srcb + 8);
            f4v b3 = *(const f4v*)(srcb + 12);
            uint4 q0, q1;
            q0.x = cvtpk(b0[0], b0[1]); q0.y = cvtpk(b0[2], b0[3]);
            q0.z = cvtpk(b1[0], b1[1]); q0.w = cvtpk(b1[2], b1[3]);
            q1.x = cvtpk(b2[0], b2[1]); q1.y = cvtpk(b2[2], b2[3]);
            q1.z = cvtpk(b3[0], b3[1]); q1.w = cvtpk(b3[2], b3[3]);
            *(uint4*)(Bs + srow * 40 + scol)     = q0;
            *(uint4*)(Bs + srow * 40 + scol + 8) = q1;
        }
        __syncthreads();
        s8v af[4], bf[4];
        #pragma unroll
        for (int i = 0; i < 4; ++i) {
            af[i] = *(const s8v*)(As + (wm + i * 16 + lq) * 40 + g * 8);
            bf[i] = *(const s8v*)(Bs + (wn + i * 16 + lq) * 40 + g * 8);
        }
        #pragma unroll
        for (int mt = 0; mt < 4; ++mt)
            #pragma unroll
            for (int nt = 0; nt < 4; ++nt)
                acc[mt][nt] = __builtin_amdgcn_mfma_f32_16x16x32_bf16(af[mt], bf[nt], acc[mt][nt], 0, 0, 0);
    }

    #pragma unroll
    for (int nt = 0; nt < 4; ++nt) {
        const int n = bn + wn + nt * 16 + lq;
        const float bv = Bv[n];
        #pragma unroll
        for (int mt = 0; mt < 4; ++mt) {
            #pragma unroll
            for (int r = 0; r < 4; ++r) {
                const int mm = bm + wm + mt * 16 + g * 4 + r;
                Out[(size_t)mm * 256 + n] = acc[mt][nt][r] + bv;
            }
        }
    }
}

extern "C" void kernel_launch(void* const* d_in, const int* in_sizes, int n_in,
                              void* d_out, int out_size, void* d_ws, size_t ws_size,
                              hipStream_t stream) {
    const float* x      = (const float*)d_in[0];
    const float* qkv_w  = (const float*)d_in[1];
    const float* qkv_b  = (const float*)d_in[2];
    const float* proj_w = (const float*)d_in[3];
    const float* proj_b = (const float*)d_in[4];
    const float* rel    = (const float*)d_in[5];
    float* out = (float*)d_out;

    uint16_t* ws = (uint16_t*)d_ws;
    const size_t QE = (size_t)NB * NH * NS * ND;          // 8,388,608 elems
    uint16_t* Qb   = ws;                                  // 16 MiB
    uint16_t* Kb   = Qb + QE;                             // 16 MiB
    uint16_t* Vb   = Kb + QE;                             // 16 MiB
    uint16_t* Rb   = Vb + QE;                             // 16 MiB: Xbf, then AO
    uint16_t* BIAS = Rb + QE;                             // 4 MiB (2M elems)

    cvt_f2bf<<<4096, 256, 0, stream>>>(x, Rb);            // X -> bf16
    bias_fill<<<8192, 256, 0, stream>>>(rel, BIAS);
    qkv_gemm<<<dim3(6, 256), 256, 0, stream>>>(Rb, qkv_w, qkv_b, Qb, Kb, Vb);
    attn_kern<<<4096, 256, 0, stream>>>(Qb, Kb, Vb, BIAS, Rb);
    proj_gemm<<<dim3(2, 256), 256, 0, stream>>>(Rb, proj_w, proj_b, out);
}

// Round 10
// 169.706 us; speedup vs baseline: 1.4459x; 1.3874x over previous
//
#include <hip/hip_runtime.h>
#include <stdint.h>

#define NB 64
#define NS 512
#define NC 256
#define NH 8
#define ND 32

typedef __attribute__((ext_vector_type(8))) short s8v;
typedef __attribute__((ext_vector_type(8))) unsigned short u8v;
typedef __attribute__((ext_vector_type(4))) float f4v;

#define LOG2E 1.4426950408889634f

static __device__ __forceinline__ uint16_t f2bf(float f) {
    uint32_t u = __builtin_bit_cast(uint32_t, f);
    u += 0x7fffu + ((u >> 16) & 1u);
    return (uint16_t)(u >> 16);
}
static __device__ __forceinline__ float bf2f(uint16_t h) {
    uint32_t u = ((uint32_t)h) << 16;
    return __builtin_bit_cast(float, u);
}
static __device__ __forceinline__ uint32_t cvtpk(float lo, float hi) {
    uint32_t r;
    asm("v_cvt_pk_bf16_f32 %0, %1, %2" : "=v"(r) : "v"(lo), "v"(hi));
    return r;
}

// ---------------- Kernel 0: bulk fp32 -> bf16 convert (n multiple of 2048) ----
__global__ __launch_bounds__(256) void cvt_f2bf(const float* __restrict__ in,
                                                uint16_t* __restrict__ out) {
    int i = (blockIdx.x * 256 + threadIdx.x) * 8;
    f4v a = *(const f4v*)(in + i);
    f4v b = *(const f4v*)(in + i + 4);
    uint4 w;
    w.x = cvtpk(a[0], a[1]); w.y = cvtpk(a[2], a[3]);
    w.z = cvtpk(b[0], b[1]); w.w = cvtpk(b[2], b[3]);
    *(uint4*)(out + i) = w;
}

// ---------------- Kernel 1: expand relative-position bias (pre-scaled by log2e)
__global__ __launch_bounds__(256) void bias_fill(const float* __restrict__ rel,
                                                 uint16_t* __restrict__ bias) {
    int id = blockIdx.x * 256 + threadIdx.x;       // 8*512*512 = 2M total
    int t = id & 511, s = (id >> 9) & 511, h = id >> 18;
    int ti = s >> 4, li = s & 15, tj = t >> 4, lj = t & 15;
    int ridx = ((((ti - tj + 31) << 4) + li) << 4) + lj;
    bias[id] = f2bf(rel[ridx * 8 + h] * LOG2E);
}

// ---------------- Kernel 2: QKV GEMM (A = bf16 X, B = fp32 W) ----------------
// writes q (scaled by SCALE*log2e, [bh][s][d]), k ([bh][s][d]), v^T ([bh][d][s])
__global__ __launch_bounds__(256) void qkv_gemm(const uint16_t* __restrict__ X,
                                                const float* __restrict__ W,
                                                const float* __restrict__ Bv,
                                                uint16_t* __restrict__ Qo,
                                                uint16_t* __restrict__ Ko,
                                                uint16_t* __restrict__ Vo) {
    __shared__ uint16_t As[128 * 40];
    __shared__ uint16_t Bs[128 * 40];
    const int tid = threadIdx.x;
    const int bn = blockIdx.x * 128;
    const int bm = blockIdx.y * 128;
    const int lane = tid & 63, wv = tid >> 6;
    const int wm = (wv >> 1) * 64, wn = (wv & 1) * 64;
    const int lq = lane & 15, g = lane >> 4;
    const int srow = tid >> 1;
    const int scol = (tid & 1) * 16;

    f4v acc[4][4] = {};

    for (int ks = 0; ks < 8; ++ks) {
        const int k0 = ks * 32;
        __syncthreads();
        {
            const uint16_t* src = X + (size_t)(bm + srow) * 256 + k0 + scol;
            u8v p0 = *(const u8v*)(src);
            u8v p1 = *(const u8v*)(src + 8);
            *(u8v*)(As + srow * 40 + scol)     = p0;
            *(u8v*)(As + srow * 40 + scol + 8) = p1;

            const float* srcb = W + (size_t)(bn + srow) * 256 + k0 + scol;
            f4v b0 = *(const f4v*)(srcb);
            f4v b1 = *(const f4v*)(srcb + 4);
            f4v b2 = *(const f4v*)(srcb + 8);
            f4v b3 = *(const f4v*)(srcb + 12);
            uint4 q0, q1;
            q0.x = cvtpk(b0[0], b0[1]); q0.y = cvtpk(b0[2], b0[3]);
            q0.z = cvtpk(b1[0], b1[1]); q0.w = cvtpk(b1[2], b1[3]);
            q1.x = cvtpk(b2[0], b2[1]); q1.y = cvtpk(b2[2], b2[3]);
            q1.z = cvtpk(b3[0], b3[1]); q1.w = cvtpk(b3[2], b3[3]);
            *(uint4*)(Bs + srow * 40 + scol)     = q0;
            *(uint4*)(Bs + srow * 40 + scol + 8) = q1;
        }
        __syncthreads();
        s8v af[4], bf[4];
        #pragma unroll
        for (int i = 0; i < 4; ++i) {
            af[i] = *(const s8v*)(As + (wm + i * 16 + lq) * 40 + g * 8);
            bf[i] = *(const s8v*)(Bs + (wn + i * 16 + lq) * 40 + g * 8);
        }
        #pragma unroll
        for (int mt = 0; mt < 4; ++mt)
            #pragma unroll
            for (int nt = 0; nt < 4; ++nt)
                acc[mt][nt] = __builtin_amdgcn_mfma_f32_16x16x32_bf16(af[mt], bf[nt], acc[mt][nt], 0, 0, 0);
    }

    const int gsel = bn >> 8;   // 0=q, 1=k, 2=v
    const float scl = (gsel == 0) ? (0.35355339059327373f * LOG2E) : 1.0f;
    #pragma unroll
    for (int nt = 0; nt < 4; ++nt) {
        const int ng = bn + wn + nt * 16 + lq;
        const float bv = Bv[ng];
        const int c = ng & 255, hh = c >> 5, dd = c & 31;
        #pragma unroll
        for (int mt = 0; mt < 4; ++mt) {
            #pragma unroll
            for (int r = 0; r < 4; ++r) {
                const int m = bm + wm + mt * 16 + g * 4 + r;
                const int b = m >> 9, s = m & 511;
                const uint16_t val = f2bf((acc[mt][nt][r] + bv) * scl);
                if (gsel == 0)      Qo[((size_t)(b * 8 + hh) * 512 + s) * 32 + dd] = val;
                else if (gsel == 1) Ko[((size_t)(b * 8 + hh) * 512 + s) * 32 + dd] = val;
                else                Vo[((size_t)(b * 8 + hh) * 32 + dd) * 512 + s] = val;
            }
        }
    }
}

// ---------------- Kernel 3: flash attention, LDS-staged K/V ------------------
// R4-green math verbatim (defer-rescale softmax, shuffle relayout, XCD pin).
// ONE change: K and V tiles are cooperatively staged into LDS once per block
// (4 waves share), cutting per-CU L2->L1 streaming 4x and making the global
// reads line-dense (256 thr x 16B contiguous) instead of 16-line scatter.
__global__ __launch_bounds__(256) void attn_kern(const uint16_t* __restrict__ Q,
                                                 const uint16_t* __restrict__ K,
                                                 const uint16_t* __restrict__ V,
                                                 const uint16_t* __restrict__ BIAS,
                                                 uint16_t* __restrict__ AO) {
    __shared__ uint16_t Ks[64 * 40];               // K tile: 64 t-rows x 32 d (pad 40)
    __shared__ uint16_t Vs[32 * 80];               // V^T tile: 32 d-rows x 64 t (pad 80)

    const int p = blockIdx.x;
    const int h  = p & 7;                          // XCD-pinned head
    const int qt = (p >> 3) & 7;
    const int b  = p >> 6;
    const int tid = threadIdx.x, lane = tid & 63, wv = tid >> 6;
    const int lq = lane & 15, g = lane >> 4;
    const bool godd = (g & 1);
    const bool ghi = (g >= 2);
    const int bh = b * 8 + h;
    const int qw = qt * 64 + wv * 16;              // window-local q base of wave

    s8v qf = *(const s8v*)(Q + ((size_t)bh * 512 + qw + lq) * 32 + g * 8);
    const uint16_t* kg = K + (size_t)bh * 16384;   // K rows t, 32 d each
    const uint16_t* vg = V + (size_t)bh * 16384;   // V^T rows d, 512 t each
    const uint16_t* bbase = BIAS + ((size_t)h * 512 + qw + lq) * 512 + g * 4;

    // staging indices (block-wide cooperative, line-dense)
    const int ktrow = tid >> 2, ktcol = (tid & 3) * 8;   // 64 rows x 32 elems
    const int vtrow = tid >> 3, vtcol = (tid & 7) * 8;   // 32 rows x 64 elems

    f4v o0 = {}, o1 = {};
    float mrow = -3.0e38f, lrow = 0.f;

    for (int tile = 0; tile < 8; ++tile) {
        const int t0 = tile * 64;

        // ---- stage K tile + V^T tile into LDS (shared by 4 waves) ----
        __syncthreads();                           // prev tile's reads done
        *(u8v*)(Ks + ktrow * 40 + ktcol) =
            *(const u8v*)(kg + (size_t)(t0 + ktrow) * 32 + ktcol);
        *(u8v*)(Vs + vtrow * 80 + vtcol) =
            *(const u8v*)(vg + (size_t)vtrow * 512 + t0 + vtcol);
        __syncthreads();

        // ---- S-tile = bias (C-init) + K.Q^T, log2 domain (green) ----
        f4v a0, a1, a2, a3;
        {
            ushort4 z0 = *(const ushort4*)(bbase + t0);
            ushort4 z1 = *(const ushort4*)(bbase + t0 + 16);
            ushort4 z2 = *(const ushort4*)(bbase + t0 + 32);
            ushort4 z3 = *(const ushort4*)(bbase + t0 + 48);
            a0[0]=bf2f(z0.x); a0[1]=bf2f(z0.y); a0[2]=bf2f(z0.z); a0[3]=bf2f(z0.w);
            a1[0]=bf2f(z1.x); a1[1]=bf2f(z1.y); a1[2]=bf2f(z1.z); a1[3]=bf2f(z1.w);
            a2[0]=bf2f(z2.x); a2[1]=bf2f(z2.y); a2[2]=bf2f(z2.z); a2[3]=bf2f(z2.w);
            a3[0]=bf2f(z3.x); a3[1]=bf2f(z3.y); a3[2]=bf2f(z3.z); a3[3]=bf2f(z3.w);
        }
        a0 = __builtin_amdgcn_mfma_f32_16x16x32_bf16(*(const s8v*)(Ks + ( 0 + lq) * 40 + g * 8), qf, a0, 0, 0, 0);
        a1 = __builtin_amdgcn_mfma_f32_16x16x32_bf16(*(const s8v*)(Ks + (16 + lq) * 40 + g * 8), qf, a1, 0, 0, 0);
        a2 = __builtin_amdgcn_mfma_f32_16x16x32_bf16(*(const s8v*)(Ks + (32 + lq) * 40 + g * 8), qf, a2, 0, 0, 0);
        a3 = __builtin_amdgcn_mfma_f32_16x16x32_bf16(*(const s8v*)(Ks + (48 + lq) * 40 + g * 8), qf, a3, 0, 0, 0);

        // ---- row max (green) ----
        float p01 = fmaxf(fmaxf(a0[0], a0[1]), fmaxf(a0[2], a0[3]));
        float p23 = fmaxf(fmaxf(a1[0], a1[1]), fmaxf(a1[2], a1[3]));
        float p45 = fmaxf(fmaxf(a2[0], a2[1]), fmaxf(a2[2], a2[3]));
        float p67 = fmaxf(fmaxf(a3[0], a3[1]), fmaxf(a3[2], a3[3]));
        float pmax = fmaxf(fmaxf(p01, p23), fmaxf(p45, p67));
        pmax = fmaxf(pmax, __shfl_xor(pmax, 16));
        pmax = fmaxf(pmax, __shfl_xor(pmax, 32));

        // ---- online-softmax update, defer-rescale threshold 8 (green) ----
        if (!__all(pmax - mrow <= 8.0f)) {
            float mnew = fmaxf(mrow, pmax);
            float scale = __builtin_amdgcn_exp2f(mrow - mnew);
            lrow *= scale;
            float s0 = __shfl(scale, g * 4 + 0);
            float s1 = __shfl(scale, g * 4 + 1);
            float s2 = __shfl(scale, g * 4 + 2);
            float s3 = __shfl(scale, g * 4 + 3);
            o0[0] *= s0; o0[1] *= s1; o0[2] *= s2; o0[3] *= s3;
            o1[0] *= s0; o1[1] *= s1; o1[2] *= s2; o1[3] *= s3;
            mrow = mnew;
        }

        // ---- P = exp2(S - m), per-lane partial row-sum (green) ----
        float lsum = 0.f;
        #pragma unroll
        for (int r = 0; r < 4; ++r) {
            a0[r] = __builtin_amdgcn_exp2f(a0[r] - mrow); lsum += a0[r];
            a1[r] = __builtin_amdgcn_exp2f(a1[r] - mrow); lsum += a1[r];
            a2[r] = __builtin_amdgcn_exp2f(a2[r] - mrow); lsum += a2[r];
            a3[r] = __builtin_amdgcn_exp2f(a3[r] - mrow); lsum += a3[r];
        }
        lrow += lsum;

        // ---- in-register re-layout P -> PV A-fragments (green verbatim) ----
        {   // tc = 0: chunks a0,a1 ; V = Vs rows lq (d 0-15) / lq+16 (d 16-31)
            uint32_t A0 = cvtpk(a0[0], a0[1]);
            uint32_t A1 = cvtpk(a0[2], a0[3]);
            uint32_t B0 = cvtpk(a1[0], a1[1]);
            uint32_t B1 = cvtpk(a1[2], a1[3]);
            uint32_t xA0 = (uint32_t)__shfl_xor((int)A0, 32);
            uint32_t xA1 = (uint32_t)__shfl_xor((int)A1, 32);
            uint32_t xB0 = (uint32_t)__shfl_xor((int)B0, 32);
            uint32_t xB1 = (uint32_t)__shfl_xor((int)B1, 32);
            uint32_t Ap0 = ghi ? xB0 : A0, Ap1 = ghi ? xB1 : A1;
            uint32_t Bp0 = ghi ? B0 : xA0, Bp1 = ghi ? B1 : xA1;
            uint32_t Z0 = godd ? Ap0 : Bp0, Z1 = godd ? Ap1 : Bp1;
            uint32_t sZ0 = (uint32_t)__shfl_xor((int)Z0, 16);
            uint32_t sZ1 = (uint32_t)__shfl_xor((int)Z1, 16);
            uint4 wq;
            wq.x = godd ? sZ0 : Ap0; wq.y = godd ? sZ1 : Ap1;
            wq.z = godd ? Bp0 : sZ0; wq.w = godd ? Bp1 : sZ1;
            s8v pf = __builtin_bit_cast(s8v, wq);
            s8v vf0 = *(const s8v*)(Vs + lq * 80 + g * 8);
            s8v vf2 = *(const s8v*)(Vs + (lq + 16) * 80 + g * 8);
            o0 = __builtin_amdgcn_mfma_f32_16x16x32_bf16(pf, vf0, o0, 0, 0, 0);
            o1 = __builtin_amdgcn_mfma_f32_16x16x32_bf16(pf, vf2, o1, 0, 0, 0);
        }
        {   // tc = 1: chunks a2,a3 ; V cols t0+32
            uint32_t A0 = cvtpk(a2[0], a2[1]);
            uint32_t A1 = cvtpk(a2[2], a2[3]);
            uint32_t B0 = cvtpk(a3[0], a3[1]);
            uint32_t B1 = cvtpk(a3[2], a3[3]);
            uint32_t xA0 = (uint32_t)__shfl_xor((int)A0, 32);
            uint32_t xA1 = (uint32_t)__shfl_xor((int)A1, 32);
            uint32_t xB0 = (uint32_t)__shfl_xor((int)B0, 32);
            uint32_t xB1 = (uint32_t)__shfl_xor((int)B1, 32);
            uint32_t Ap0 = ghi ? xB0 : A0, Ap1 = ghi ? xB1 : A1;
            uint32_t Bp0 = ghi ? B0 : xA0, Bp1 = ghi ? B1 : xA1;
            uint32_t Z0 = godd ? Ap0 : Bp0, Z1 = godd ? Ap1 : Bp1;
            uint32_t sZ0 = (uint32_t)__shfl_xor((int)Z0, 16);
            uint32_t sZ1 = (uint32_t)__shfl_xor((int)Z1, 16);
            uint4 wq;
            wq.x = godd ? sZ0 : Ap0; wq.y = godd ? sZ1 : Ap1;
            wq.z = godd ? Bp0 : sZ0; wq.w = godd ? Bp1 : sZ1;
            s8v pf = __builtin_bit_cast(s8v, wq);
            s8v vf1 = *(const s8v*)(Vs + lq * 80 + 32 + g * 8);
            s8v vf3 = *(const s8v*)(Vs + (lq + 16) * 80 + 32 + g * 8);
            o0 = __builtin_amdgcn_mfma_f32_16x16x32_bf16(pf, vf1, o0, 0, 0, 0);
            o1 = __builtin_amdgcn_mfma_f32_16x16x32_bf16(pf, vf3, o1, 0, 0, 0);
        }
    }

    // ---- finalize: row sum across g, normalize, store (green) ----
    lrow += __shfl_xor(lrow, 16);
    lrow += __shfl_xor(lrow, 32);
    const float inv = 1.0f / lrow;                 // valid for row lq
    #pragma unroll
    for (int r = 0; r < 4; ++r) {
        const float iv = __shfl(inv, g * 4 + r);   // row g*4+r's denom
        const int srow = b * 512 + qw + g * 4 + r;
        uint16_t* dst = AO + (size_t)srow * 256 + h * 32 + lq;
        dst[0]  = f2bf(o0[r] * iv);
        dst[16] = f2bf(o1[r] * iv);
    }
}

// ---------------- Kernel 4: output projection ----------------
__global__ __launch_bounds__(256) void proj_gemm(const uint16_t* __restrict__ A,
                                                 const float* __restrict__ W,
                                                 const float* __restrict__ Bv,
                                                 float* __restrict__ Out) {
    __shared__ uint16_t As[128 * 40];
    __shared__ uint16_t Bs[128 * 40];
    const int tid = threadIdx.x;
    const int bn = blockIdx.x * 128;
    const int bm = blockIdx.y * 128;
    const int lane = tid & 63, wv = tid >> 6;
    const int wm = (wv >> 1) * 64, wn = (wv & 1) * 64;
    const int lq = lane & 15, g = lane >> 4;
    const int srow = tid >> 1;
    const int scol = (tid & 1) * 16;

    f4v acc[4][4] = {};

    for (int ks = 0; ks < 8; ++ks) {
        const int k0 = ks * 32;
        __syncthreads();
        {
            const uint16_t* src = A + (size_t)(bm + srow) * 256 + k0 + scol;
            u8v p0 = *(const u8v*)(src);
            u8v p1 = *(const u8v*)(src + 8);
            *(u8v*)(As + srow * 40 + scol)     = p0;
            *(u8v*)(As + srow * 40 + scol + 8) = p1;

            const float* srcb = W + (size_t)(bn + srow) * 256 + k0 + scol;
            f4v b0 = *(const f4v*)(srcb);
            f4v b1 = *(const f4v*)(srcb + 4);
            f4v b2 = *(const f4v*)(srcb + 8);
            f4v b3 = *(const f4v*)(srcb + 12);
            uint4 q0, q1;
            q0.x = cvtpk(b0[0], b0[1]); q0.y = cvtpk(b0[2], b0[3]);
            q0.z = cvtpk(b1[0], b1[1]); q0.w = cvtpk(b1[2], b1[3]);
            q1.x = cvtpk(b2[0], b2[1]); q1.y = cvtpk(b2[2], b2[3]);
            q1.z = cvtpk(b3[0], b3[1]); q1.w = cvtpk(b3[2], b3[3]);
            *(uint4*)(Bs + srow * 40 + scol)     = q0;
            *(uint4*)(Bs + srow * 40 + scol + 8) = q1;
        }
        __syncthreads();
        s8v af[4], bf[4];
        #pragma unroll
        for (int i = 0; i < 4; ++i) {
            af[i] = *(const s8v*)(As + (wm + i * 16 + lq) * 40 + g * 8);
            bf[i] = *(const s8v*)(Bs + (wn + i * 16 + lq) * 40 + g * 8);
        }
        #pragma unroll
        for (int mt = 0; mt < 4; ++mt)
            #pragma unroll
            for (int nt = 0; nt < 4; ++nt)
                acc[mt][nt] = __builtin_amdgcn_mfma_f32_16x16x32_bf16(af[mt], bf[nt], acc[mt][nt], 0, 0, 0);
    }

    #pragma unroll
    for (int nt = 0; nt < 4; ++nt) {
        const int n = bn + wn + nt * 16 + lq;
        const float bv = Bv[n];
        #pragma unroll
        for (int mt = 0; mt < 4; ++mt) {
            #pragma unroll
            for (int r = 0; r < 4; ++r) {
                const int mm = bm + wm + mt * 16 + g * 4 + r;
                Out[(size_t)mm * 256 + n] = acc[mt][nt][r] + bv;
            }
        }
    }
}

extern "C" void kernel_launch(void* const* d_in, const int* in_sizes, int n_in,
                              void* d_out, int out_size, void* d_ws, size_t ws_size,
                              hipStream_t stream) {
    const float* x      = (const float*)d_in[0];
    const float* qkv_w  = (const float*)d_in[1];
    const float* qkv_b  = (const float*)d_in[2];
    const float* proj_w = (const float*)d_in[3];
    const float* proj_b = (const float*)d_in[4];
    const float* rel    = (const float*)d_in[5];
    float* out = (float*)d_out;

    uint16_t* ws = (uint16_t*)d_ws;
    const size_t QE = (size_t)NB * NH * NS * ND;          // 8,388,608 elems
    uint16_t* Qb   = ws;                                  // 16 MiB
    uint16_t* Kb   = Qb + QE;                             // 16 MiB
    uint16_t* Vb   = Kb + QE;                             // 16 MiB
    uint16_t* Rb   = Vb + QE;                             // 16 MiB: Xbf, then AO
    uint16_t* BIAS = Rb + QE;                             // 4 MiB (2M elems)

    cvt_f2bf<<<4096, 256, 0, stream>>>(x, Rb);            // X -> bf16
    bias_fill<<<8192, 256, 0, stream>>>(rel, BIAS);
    qkv_gemm<<<dim3(6, 256), 256, 0, stream>>>(Rb, qkv_w, qkv_b, Qb, Kb, Vb);
    attn_kern<<<4096, 256, 0, stream>>>(Qb, Kb, Vb, BIAS, Rb);
    proj_gemm<<<dim3(2, 256), 256, 0, stream>>>(Rb, proj_w, proj_b, out);
}

// Round 11
// 167.298 us; speedup vs baseline: 1.4667x; 1.0144x over previous
//
#include <hip/hip_runtime.h>
#include <stdint.h>

#define NB 64
#define NS 512
#define NC 256
#define NH 8
#define ND 32

typedef __attribute__((ext_vector_type(8))) short s8v;
typedef __attribute__((ext_vector_type(8))) unsigned short u8v;
typedef __attribute__((ext_vector_type(4))) float f4v;

#define LOG2E 1.4426950408889634f

static __device__ __forceinline__ uint16_t f2bf(float f) {
    uint32_t u = __builtin_bit_cast(uint32_t, f);
    u += 0x7fffu + ((u >> 16) & 1u);
    return (uint16_t)(u >> 16);
}
static __device__ __forceinline__ float bf2f(uint16_t h) {
    uint32_t u = ((uint32_t)h) << 16;
    return __builtin_bit_cast(float, u);
}
static __device__ __forceinline__ uint32_t cvtpk(float lo, float hi) {
    uint32_t r;
    asm("v_cvt_pk_bf16_f32 %0, %1, %2" : "=v"(r) : "v"(lo), "v"(hi));
    return r;
}

// ---------------- Kernel 0: bulk fp32 -> bf16 convert (n multiple of 2048) ----
__global__ __launch_bounds__(256) void cvt_f2bf(const float* __restrict__ in,
                                                uint16_t* __restrict__ out) {
    int i = (blockIdx.x * 256 + threadIdx.x) * 8;
    f4v a = *(const f4v*)(in + i);
    f4v b = *(const f4v*)(in + i + 4);
    uint4 w;
    w.x = cvtpk(a[0], a[1]); w.y = cvtpk(a[2], a[3]);
    w.z = cvtpk(b[0], b[1]); w.w = cvtpk(b[2], b[3]);
    *(uint4*)(out + i) = w;
}

// ---------------- Kernel 1: expand relative-position bias (pre-scaled by log2e)
__global__ __launch_bounds__(256) void bias_fill(const float* __restrict__ rel,
                                                 uint16_t* __restrict__ bias) {
    int id = blockIdx.x * 256 + threadIdx.x;       // 8*512*512 = 2M total
    int t = id & 511, s = (id >> 9) & 511, h = id >> 18;
    int ti = s >> 4, li = s & 15, tj = t >> 4, lj = t & 15;
    int ridx = ((((ti - tj + 31) << 4) + li) << 4) + lj;
    bias[id] = f2bf(rel[ridx * 8 + h] * LOG2E);
}

// ---------------- Kernel 2: QKV GEMM (A = bf16 X, B = bf16 W) ----------------
// writes q (scaled by SCALE*log2e, [bh][s][d]), k ([bh][s][d]), v^T ([bh][d][s])
__global__ __launch_bounds__(256) void qkv_gemm(const uint16_t* __restrict__ X,
                                                const uint16_t* __restrict__ W,
                                                const float* __restrict__ Bv,
                                                uint16_t* __restrict__ Qo,
                                                uint16_t* __restrict__ Ko,
                                                uint16_t* __restrict__ Vo) {
    __shared__ uint16_t As[128 * 40];
    __shared__ uint16_t Bs[128 * 40];
    const int tid = threadIdx.x;
    const int bn = blockIdx.x * 128;
    const int bm = blockIdx.y * 128;
    const int lane = tid & 63, wv = tid >> 6;
    const int wm = (wv >> 1) * 64, wn = (wv & 1) * 64;
    const int lq = lane & 15, g = lane >> 4;
    const int srow = tid >> 1;
    const int scol = (tid & 1) * 16;

    f4v acc[4][4] = {};

    for (int ks = 0; ks < 8; ++ks) {
        const int k0 = ks * 32;
        __syncthreads();
        {
            const uint16_t* src = X + (size_t)(bm + srow) * 256 + k0 + scol;
            u8v p0 = *(const u8v*)(src);
            u8v p1 = *(const u8v*)(src + 8);
            *(u8v*)(As + srow * 40 + scol)     = p0;
            *(u8v*)(As + srow * 40 + scol + 8) = p1;

            const uint16_t* srcb = W + (size_t)(bn + srow) * 256 + k0 + scol;
            u8v q0 = *(const u8v*)(srcb);
            u8v q1 = *(const u8v*)(srcb + 8);
            *(u8v*)(Bs + srow * 40 + scol)     = q0;
            *(u8v*)(Bs + srow * 40 + scol + 8) = q1;
        }
        __syncthreads();
        s8v af[4], bf[4];
        #pragma unroll
        for (int i = 0; i < 4; ++i) {
            af[i] = *(const s8v*)(As + (wm + i * 16 + lq) * 40 + g * 8);
            bf[i] = *(const s8v*)(Bs + (wn + i * 16 + lq) * 40 + g * 8);
        }
        #pragma unroll
        for (int mt = 0; mt < 4; ++mt)
            #pragma unroll
            for (int nt = 0; nt < 4; ++nt)
                acc[mt][nt] = __builtin_amdgcn_mfma_f32_16x16x32_bf16(af[mt], bf[nt], acc[mt][nt], 0, 0, 0);
    }

    const int gsel = bn >> 8;   // 0=q, 1=k, 2=v
    const float scl = (gsel == 0) ? (0.35355339059327373f * LOG2E) : 1.0f;
    #pragma unroll
    for (int nt = 0; nt < 4; ++nt) {
        const int ng = bn + wn + nt * 16 + lq;
        const float bv = Bv[ng];
        const int c = ng & 255, hh = c >> 5, dd = c & 31;
        #pragma unroll
        for (int mt = 0; mt < 4; ++mt) {
            #pragma unroll
            for (int r = 0; r < 4; ++r) {
                const int m = bm + wm + mt * 16 + g * 4 + r;
                const int b = m >> 9, s = m & 511;
                const uint16_t val = f2bf((acc[mt][nt][r] + bv) * scl);
                if (gsel == 0)      Qo[((size_t)(b * 8 + hh) * 512 + s) * 32 + dd] = val;
                else if (gsel == 1) Ko[((size_t)(b * 8 + hh) * 512 + s) * 32 + dd] = val;
                else                Vo[((size_t)(b * 8 + hh) * 32 + dd) * 512 + s] = val;
            }
        }
    }
}

// ---------------- Kernel 3: flash attention, LDS-staged K/V, issue-early -----
// R10-green math verbatim. ONE change: global loads for tile t+1 are issued
// into registers right after tile t's write-barrier (before compute), so L2
// latency hides under tile t's softmax/MFMA instead of sitting serially
// between the two barriers.
__global__ __launch_bounds__(256) void attn_kern(const uint16_t* __restrict__ Q,
                                                 const uint16_t* __restrict__ K,
                                                 const uint16_t* __restrict__ V,
                                                 const uint16_t* __restrict__ BIAS,
                                                 uint16_t* __restrict__ AO) {
    __shared__ uint16_t Ks[64 * 40];               // K tile: 64 t-rows x 32 d (pad 40)
    __shared__ uint16_t Vs[32 * 80];               // V^T tile: 32 d-rows x 64 t (pad 80)

    const int p = blockIdx.x;
    const int h  = p & 7;                          // XCD-pinned head
    const int qt = (p >> 3) & 7;
    const int b  = p >> 6;
    const int tid = threadIdx.x, lane = tid & 63, wv = tid >> 6;
    const int lq = lane & 15, g = lane >> 4;
    const bool godd = (g & 1);
    const bool ghi = (g >= 2);
    const int bh = b * 8 + h;
    const int qw = qt * 64 + wv * 16;              // window-local q base of wave

    s8v qf = *(const s8v*)(Q + ((size_t)bh * 512 + qw + lq) * 32 + g * 8);
    const uint16_t* kg = K + (size_t)bh * 16384;   // K rows t, 32 d each
    const uint16_t* vg = V + (size_t)bh * 16384;   // V^T rows d, 512 t each
    const uint16_t* bbase = BIAS + ((size_t)h * 512 + qw + lq) * 512 + g * 4;

    // staging indices (block-wide cooperative, line-dense)
    const int ktrow = tid >> 2, ktcol = (tid & 3) * 8;   // 64 rows x 32 elems
    const int vtrow = tid >> 3, vtcol = (tid & 7) * 8;   // 32 rows x 64 elems
    const uint16_t* kgs = kg + (size_t)ktrow * 32 + ktcol;
    const uint16_t* vgs = vg + (size_t)vtrow * 512 + vtcol;

    f4v o0 = {}, o1 = {};
    float mrow = -3.0e38f, lrow = 0.f;

    // prologue: load tile 0 into registers
    u8v kreg = *(const u8v*)(kgs);
    u8v vreg = *(const u8v*)(vgs);

    for (int tile = 0; tile < 8; ++tile) {
        const int t0 = tile * 64;

        __syncthreads();                           // prev tile's LDS reads done
        *(u8v*)(Ks + ktrow * 40 + ktcol) = kreg;
        *(u8v*)(Vs + vtrow * 80 + vtcol) = vreg;
        __syncthreads();                           // writes visible

        // issue-early: next tile's global loads hide under this tile's compute
        if (tile < 7) {
            kreg = *(const u8v*)(kgs + (t0 + 64) * 32);
            vreg = *(const u8v*)(vgs + (t0 + 64));
        }

        // ---- S-tile = bias (C-init) + K.Q^T, log2 domain (green) ----
        f4v a0, a1, a2, a3;
        {
            ushort4 z0 = *(const ushort4*)(bbase + t0);
            ushort4 z1 = *(const ushort4*)(bbase + t0 + 16);
            ushort4 z2 = *(const ushort4*)(bbase + t0 + 32);
            ushort4 z3 = *(const ushort4*)(bbase + t0 + 48);
            a0[0]=bf2f(z0.x); a0[1]=bf2f(z0.y); a0[2]=bf2f(z0.z); a0[3]=bf2f(z0.w);
            a1[0]=bf2f(z1.x); a1[1]=bf2f(z1.y); a1[2]=bf2f(z1.z); a1[3]=bf2f(z1.w);
            a2[0]=bf2f(z2.x); a2[1]=bf2f(z2.y); a2[2]=bf2f(z2.z); a2[3]=bf2f(z2.w);
            a3[0]=bf2f(z3.x); a3[1]=bf2f(z3.y); a3[2]=bf2f(z3.z); a3[3]=bf2f(z3.w);
        }
        a0 = __builtin_amdgcn_mfma_f32_16x16x32_bf16(*(const s8v*)(Ks + ( 0 + lq) * 40 + g * 8), qf, a0, 0, 0, 0);
        a1 = __builtin_amdgcn_mfma_f32_16x16x32_bf16(*(const s8v*)(Ks + (16 + lq) * 40 + g * 8), qf, a1, 0, 0, 0);
        a2 = __builtin_amdgcn_mfma_f32_16x16x32_bf16(*(const s8v*)(Ks + (32 + lq) * 40 + g * 8), qf, a2, 0, 0, 0);
        a3 = __builtin_amdgcn_mfma_f32_16x16x32_bf16(*(const s8v*)(Ks + (48 + lq) * 40 + g * 8), qf, a3, 0, 0, 0);

        // ---- row max (green) ----
        float p01 = fmaxf(fmaxf(a0[0], a0[1]), fmaxf(a0[2], a0[3]));
        float p23 = fmaxf(fmaxf(a1[0], a1[1]), fmaxf(a1[2], a1[3]));
        float p45 = fmaxf(fmaxf(a2[0], a2[1]), fmaxf(a2[2], a2[3]));
        float p67 = fmaxf(fmaxf(a3[0], a3[1]), fmaxf(a3[2], a3[3]));
        float pmax = fmaxf(fmaxf(p01, p23), fmaxf(p45, p67));
        pmax = fmaxf(pmax, __shfl_xor(pmax, 16));
        pmax = fmaxf(pmax, __shfl_xor(pmax, 32));

        // ---- online-softmax update, defer-rescale threshold 8 (green) ----
        if (!__all(pmax - mrow <= 8.0f)) {
            float mnew = fmaxf(mrow, pmax);
            float scale = __builtin_amdgcn_exp2f(mrow - mnew);
            lrow *= scale;
            float s0 = __shfl(scale, g * 4 + 0);
            float s1 = __shfl(scale, g * 4 + 1);
            float s2 = __shfl(scale, g * 4 + 2);
            float s3 = __shfl(scale, g * 4 + 3);
            o0[0] *= s0; o0[1] *= s1; o0[2] *= s2; o0[3] *= s3;
            o1[0] *= s0; o1[1] *= s1; o1[2] *= s2; o1[3] *= s3;
            mrow = mnew;
        }

        // ---- P = exp2(S - m), per-lane partial row-sum (green) ----
        float lsum = 0.f;
        #pragma unroll
        for (int r = 0; r < 4; ++r) {
            a0[r] = __builtin_amdgcn_exp2f(a0[r] - mrow); lsum += a0[r];
            a1[r] = __builtin_amdgcn_exp2f(a1[r] - mrow); lsum += a1[r];
            a2[r] = __builtin_amdgcn_exp2f(a2[r] - mrow); lsum += a2[r];
            a3[r] = __builtin_amdgcn_exp2f(a3[r] - mrow); lsum += a3[r];
        }
        lrow += lsum;

        // ---- in-register re-layout P -> PV A-fragments (green verbatim) ----
        {   // tc = 0: chunks a0,a1 ; V = Vs rows lq (d 0-15) / lq+16 (d 16-31)
            uint32_t A0 = cvtpk(a0[0], a0[1]);
            uint32_t A1 = cvtpk(a0[2], a0[3]);
            uint32_t B0 = cvtpk(a1[0], a1[1]);
            uint32_t B1 = cvtpk(a1[2], a1[3]);
            uint32_t xA0 = (uint32_t)__shfl_xor((int)A0, 32);
            uint32_t xA1 = (uint32_t)__shfl_xor((int)A1, 32);
            uint32_t xB0 = (uint32_t)__shfl_xor((int)B0, 32);
            uint32_t xB1 = (uint32_t)__shfl_xor((int)B1, 32);
            uint32_t Ap0 = ghi ? xB0 : A0, Ap1 = ghi ? xB1 : A1;
            uint32_t Bp0 = ghi ? B0 : xA0, Bp1 = ghi ? B1 : xA1;
            uint32_t Z0 = godd ? Ap0 : Bp0, Z1 = godd ? Ap1 : Bp1;
            uint32_t sZ0 = (uint32_t)__shfl_xor((int)Z0, 16);
            uint32_t sZ1 = (uint32_t)__shfl_xor((int)Z1, 16);
            uint4 wq;
            wq.x = godd ? sZ0 : Ap0; wq.y = godd ? sZ1 : Ap1;
            wq.z = godd ? Bp0 : sZ0; wq.w = godd ? Bp1 : sZ1;
            s8v pf = __builtin_bit_cast(s8v, wq);
            s8v vf0 = *(const s8v*)(Vs + lq * 80 + g * 8);
            s8v vf2 = *(const s8v*)(Vs + (lq + 16) * 80 + g * 8);
            o0 = __builtin_amdgcn_mfma_f32_16x16x32_bf16(pf, vf0, o0, 0, 0, 0);
            o1 = __builtin_amdgcn_mfma_f32_16x16x32_bf16(pf, vf2, o1, 0, 0, 0);
        }
        {   // tc = 1: chunks a2,a3 ; V cols t0+32
            uint32_t A0 = cvtpk(a2[0], a2[1]);
            uint32_t A1 = cvtpk(a2[2], a2[3]);
            uint32_t B0 = cvtpk(a3[0], a3[1]);
            uint32_t B1 = cvtpk(a3[2], a3[3]);
            uint32_t xA0 = (uint32_t)__shfl_xor((int)A0, 32);
            uint32_t xA1 = (uint32_t)__shfl_xor((int)A1, 32);
            uint32_t xB0 = (uint32_t)__shfl_xor((int)B0, 32);
            uint32_t xB1 = (uint32_t)__shfl_xor((int)B1, 32);
            uint32_t Ap0 = ghi ? xB0 : A0, Ap1 = ghi ? xB1 : A1;
            uint32_t Bp0 = ghi ? B0 : xA0, Bp1 = ghi ? B1 : xA1;
            uint32_t Z0 = godd ? Ap0 : Bp0, Z1 = godd ? Ap1 : Bp1;
            uint32_t sZ0 = (uint32_t)__shfl_xor((int)Z0, 16);
            uint32_t sZ1 = (uint32_t)__shfl_xor((int)Z1, 16);
            uint4 wq;
            wq.x = godd ? sZ0 : Ap0; wq.y = godd ? sZ1 : Ap1;
            wq.z = godd ? Bp0 : sZ0; wq.w = godd ? Bp1 : sZ1;
            s8v pf = __builtin_bit_cast(s8v, wq);
            s8v vf1 = *(const s8v*)(Vs + lq * 80 + 32 + g * 8);
            s8v vf3 = *(const s8v*)(Vs + (lq + 16) * 80 + 32 + g * 8);
            o0 = __builtin_amdgcn_mfma_f32_16x16x32_bf16(pf, vf1, o0, 0, 0, 0);
            o1 = __builtin_amdgcn_mfma_f32_16x16x32_bf16(pf, vf3, o1, 0, 0, 0);
        }
    }

    // ---- finalize: row sum across g, normalize, store (green) ----
    lrow += __shfl_xor(lrow, 16);
    lrow += __shfl_xor(lrow, 32);
    const float inv = 1.0f / lrow;                 // valid for row lq
    #pragma unroll
    for (int r = 0; r < 4; ++r) {
        const float iv = __shfl(inv, g * 4 + r);   // row g*4+r's denom
        const int srow = b * 512 + qw + g * 4 + r;
        uint16_t* dst = AO + (size_t)srow * 256 + h * 32 + lq;
        dst[0]  = f2bf(o0[r] * iv);
        dst[16] = f2bf(o1[r] * iv);
    }
}

// ---------------- Kernel 4: output projection (A bf16, W bf16) ---------------
__global__ __launch_bounds__(256) void proj_gemm(const uint16_t* __restrict__ A,
                                                 const uint16_t* __restrict__ W,
                                                 const float* __restrict__ Bv,
                                                 float* __restrict__ Out) {
    __shared__ uint16_t As[128 * 40];
    __shared__ uint16_t Bs[128 * 40];
    const int tid = threadIdx.x;
    const int bn = blockIdx.x * 128;
    const int bm = blockIdx.y * 128;
    const int lane = tid & 63, wv = tid >> 6;
    const int wm = (wv >> 1) * 64, wn = (wv & 1) * 64;
    const int lq = lane & 15, g = lane >> 4;
    const int srow = tid >> 1;
    const int scol = (tid & 1) * 16;

    f4v acc[4][4] = {};

    for (int ks = 0; ks < 8; ++ks) {
        const int k0 = ks * 32;
        __syncthreads();
        {
            const uint16_t* src = A + (size_t)(bm + srow) * 256 + k0 + scol;
            u8v p0 = *(const u8v*)(src);
            u8v p1 = *(const u8v*)(src + 8);
            *(u8v*)(As + srow * 40 + scol)     = p0;
            *(u8v*)(As + srow * 40 + scol + 8) = p1;

            const uint16_t* srcb = W + (size_t)(bn + srow) * 256 + k0 + scol;
            u8v q0 = *(const u8v*)(srcb);
            u8v q1 = *(const u8v*)(srcb + 8);
            *(u8v*)(Bs + srow * 40 + scol)     = q0;
            *(u8v*)(Bs + srow * 40 + scol + 8) = q1;
        }
        __syncthreads();
        s8v af[4], bf[4];
        #pragma unroll
        for (int i = 0; i < 4; ++i) {
            af[i] = *(const s8v*)(As + (wm + i * 16 + lq) * 40 + g * 8);
            bf[i] = *(const s8v*)(Bs + (wn + i * 16 + lq) * 40 + g * 8);
        }
        #pragma unroll
        for (int mt = 0; mt < 4; ++mt)
            #pragma unroll
            for (int nt = 0; nt < 4; ++nt)
                acc[mt][nt] = __builtin_amdgcn_mfma_f32_16x16x32_bf16(af[mt], bf[nt], acc[mt][nt], 0, 0, 0);
    }

    #pragma unroll
    for (int nt = 0; nt < 4; ++nt) {
        const int n = bn + wn + nt * 16 + lq;
        const float bv = Bv[n];
        #pragma unroll
        for (int mt = 0; mt < 4; ++mt) {
            #pragma unroll
            for (int r = 0; r < 4; ++r) {
                const int mm = bm + wm + mt * 16 + g * 4 + r;
                Out[(size_t)mm * 256 + n] = acc[mt][nt][r] + bv;
            }
        }
    }
}

extern "C" void kernel_launch(void* const* d_in, const int* in_sizes, int n_in,
                              void* d_out, int out_size, void* d_ws, size_t ws_size,
                              hipStream_t stream) {
    const float* x      = (const float*)d_in[0];
    const float* qkv_w  = (const float*)d_in[1];
    const float* qkv_b  = (const float*)d_in[2];
    const float* proj_w = (const float*)d_in[3];
    const float* proj_b = (const float*)d_in[4];
    const float* rel    = (const float*)d_in[5];
    float* out = (float*)d_out;

    uint16_t* ws = (uint16_t*)d_ws;
    const size_t QE = (size_t)NB * NH * NS * ND;          // 8,388,608 elems
    uint16_t* Qb   = ws;                                  // 16 MiB
    uint16_t* Kb   = Qb + QE;                             // 16 MiB
    uint16_t* Vb   = Kb + QE;                             // 16 MiB
    uint16_t* Rb   = Vb + QE;                             // 16 MiB: Xbf, then AO
    uint16_t* BIAS = Rb + QE;                             // 4 MiB (2M elems)
    uint16_t* Wqb  = BIAS + 2097152;                      // 768x256 bf16 (384 KiB)
    uint16_t* Wpb  = Wqb + 196608;                        // 256x256 bf16 (128 KiB)

    cvt_f2bf<<<4096, 256, 0, stream>>>(x, Rb);            // X -> bf16
    cvt_f2bf<<<96, 256, 0, stream>>>(qkv_w, Wqb);         // qkv_w -> bf16 (once)
    cvt_f2bf<<<32, 256, 0, stream>>>(proj_w, Wpb);        // proj_w -> bf16 (once)
    bias_fill<<<8192, 256, 0, stream>>>(rel, BIAS);
    qkv_gemm<<<dim3(6, 256), 256, 0, stream>>>(Rb, Wqb, qkv_b, Qb, Kb, Vb);
    attn_kern<<<4096, 256, 0, stream>>>(Qb, Kb, Vb, BIAS, Rb);
    proj_gemm<<<dim3(2, 256), 256, 0, stream>>>(Rb, Wpb, proj_b, out);
}

// Round 12
// 155.407 us; speedup vs baseline: 1.5790x; 1.0765x over previous
//
#include <hip/hip_runtime.h>
#include <stdint.h>

#define NB 64
#define NS 512
#define NC 256
#define NH 8
#define ND 32

typedef __attribute__((ext_vector_type(8))) short s8v;
typedef __attribute__((ext_vector_type(8))) unsigned short u8v;
typedef __attribute__((ext_vector_type(4))) float f4v;

#define LOG2E 1.4426950408889634f

static __device__ __forceinline__ uint16_t f2bf(float f) {
    uint32_t u = __builtin_bit_cast(uint32_t, f);
    u += 0x7fffu + ((u >> 16) & 1u);
    return (uint16_t)(u >> 16);
}
static __device__ __forceinline__ float bf2f(uint16_t h) {
    uint32_t u = ((uint32_t)h) << 16;
    return __builtin_bit_cast(float, u);
}
static __device__ __forceinline__ uint32_t cvtpk(float lo, float hi) {
    uint32_t r;
    asm("v_cvt_pk_bf16_f32 %0, %1, %2" : "=v"(r) : "v"(lo), "v"(hi));
    return r;
}

// ---------------- Kernel 0: bulk fp32 -> bf16 convert (n multiple of 2048) ----
__global__ __launch_bounds__(256) void cvt_f2bf(const float* __restrict__ in,
                                                uint16_t* __restrict__ out) {
    int i = (blockIdx.x * 256 + threadIdx.x) * 8;
    f4v a = *(const f4v*)(in + i);
    f4v b = *(const f4v*)(in + i + 4);
    uint4 w;
    w.x = cvtpk(a[0], a[1]); w.y = cvtpk(a[2], a[3]);
    w.z = cvtpk(b[0], b[1]); w.w = cvtpk(b[2], b[3]);
    *(uint4*)(out + i) = w;
}

// ---------------- Kernel 1: compact per-head rel table (pre-scaled by log2e) --
// REL2[h][dt][li][lj], dt in [0,63] (63 used, 64 for pow2 stride), bf16.
// Same f2bf(rel * LOG2E) rounding as before -> bit-identical bias values.
__global__ __launch_bounds__(256) void rel_fill(const float* __restrict__ rel,
                                                uint16_t* __restrict__ rel2) {
    int id = blockIdx.x * 256 + threadIdx.x;       // 8 * 16384 = 131072
    int h = id >> 14, r = id & 16383;
    int dt = r >> 8, li = (r >> 4) & 15, lj = r & 15;
    float v = (dt < 63) ? rel[(((dt << 4) + li) * 16 + lj) * 8 + h] * LOG2E : 0.f;
    rel2[id] = f2bf(v);
}

// ---------------- Kernel 2: QKV GEMM (A = bf16 X, B = bf16 W) ----------------
// writes q (scaled by SCALE*log2e, [bh][s][d]), k ([bh][s][d]), v^T ([bh][d][s])
__global__ __launch_bounds__(256) void qkv_gemm(const uint16_t* __restrict__ X,
                                                const uint16_t* __restrict__ W,
                                                const float* __restrict__ Bv,
                                                uint16_t* __restrict__ Qo,
                                                uint16_t* __restrict__ Ko,
                                                uint16_t* __restrict__ Vo) {
    __shared__ uint16_t As[128 * 40];
    __shared__ uint16_t Bs[128 * 40];
    const int tid = threadIdx.x;
    const int bn = blockIdx.x * 128;
    const int bm = blockIdx.y * 128;
    const int lane = tid & 63, wv = tid >> 6;
    const int wm = (wv >> 1) * 64, wn = (wv & 1) * 64;
    const int lq = lane & 15, g = lane >> 4;
    const int srow = tid >> 1;
    const int scol = (tid & 1) * 16;

    f4v acc[4][4] = {};

    for (int ks = 0; ks < 8; ++ks) {
        const int k0 = ks * 32;
        __syncthreads();
        {
            const uint16_t* src = X + (size_t)(bm + srow) * 256 + k0 + scol;
            u8v p0 = *(const u8v*)(src);
            u8v p1 = *(const u8v*)(src + 8);
            *(u8v*)(As + srow * 40 + scol)     = p0;
            *(u8v*)(As + srow * 40 + scol + 8) = p1;

            const uint16_t* srcb = W + (size_t)(bn + srow) * 256 + k0 + scol;
            u8v q0 = *(const u8v*)(srcb);
            u8v q1 = *(const u8v*)(srcb + 8);
            *(u8v*)(Bs + srow * 40 + scol)     = q0;
            *(u8v*)(Bs + srow * 40 + scol + 8) = q1;
        }
        __syncthreads();
        s8v af[4], bf[4];
        #pragma unroll
        for (int i = 0; i < 4; ++i) {
            af[i] = *(const s8v*)(As + (wm + i * 16 + lq) * 40 + g * 8);
            bf[i] = *(const s8v*)(Bs + (wn + i * 16 + lq) * 40 + g * 8);
        }
        #pragma unroll
        for (int mt = 0; mt < 4; ++mt)
            #pragma unroll
            for (int nt = 0; nt < 4; ++nt)
                acc[mt][nt] = __builtin_amdgcn_mfma_f32_16x16x32_bf16(af[mt], bf[nt], acc[mt][nt], 0, 0, 0);
    }

    const int gsel = bn >> 8;   // 0=q, 1=k, 2=v
    const float scl = (gsel == 0) ? (0.35355339059327373f * LOG2E) : 1.0f;
    #pragma unroll
    for (int nt = 0; nt < 4; ++nt) {
        const int ng = bn + wn + nt * 16 + lq;
        const float bv = Bv[ng];
        const int c = ng & 255, hh = c >> 5, dd = c & 31;
        #pragma unroll
        for (int mt = 0; mt < 4; ++mt) {
            #pragma unroll
            for (int r = 0; r < 4; ++r) {
                const int m = bm + wm + mt * 16 + g * 4 + r;
                const int b = m >> 9, s = m & 511;
                const uint16_t val = f2bf((acc[mt][nt][r] + bv) * scl);
                if (gsel == 0)      Qo[((size_t)(b * 8 + hh) * 512 + s) * 32 + dd] = val;
                else if (gsel == 1) Ko[((size_t)(b * 8 + hh) * 512 + s) * 32 + dd] = val;
                else                Vo[((size_t)(b * 8 + hh) * 32 + dd) * 512 + s] = val;
            }
        }
    }
}

// ---------------- Kernel 3: flash attention, all operands LDS-staged ---------
// R11-green math verbatim. ONE change: bias comes from the compact per-head
// rel slice (32 KB) staged in LDS once per block -- zero in-loop global bias
// traffic. Within a wave ti and tj are uniform, so the bias read is a
// conflict-free sequential ds_read_b64: Rel + dt*512B + lq*32B + g*8B.
__global__ __launch_bounds__(256) void attn_kern(const uint16_t* __restrict__ Q,
                                                 const uint16_t* __restrict__ K,
                                                 const uint16_t* __restrict__ V,
                                                 const uint16_t* __restrict__ REL2,
                                                 uint16_t* __restrict__ AO) {
    __shared__ uint16_t Ks[64 * 40];               // K tile: 64 t-rows x 32 d (pad 40)
    __shared__ uint16_t Vs[32 * 80];               // V^T tile: 32 d-rows x 64 t (pad 80)
    __shared__ uint16_t Rel[16384];                // per-head compact rel slice (32 KB)

    const int p = blockIdx.x;
    const int h  = p & 7;                          // XCD-pinned head
    const int qt = (p >> 3) & 7;
    const int b  = p >> 6;
    const int tid = threadIdx.x, lane = tid & 63, wv = tid >> 6;
    const int lq = lane & 15, g = lane >> 4;
    const bool godd = (g & 1);
    const bool ghi = (g >= 2);
    const int bh = b * 8 + h;
    const int qw = qt * 64 + wv * 16;              // window-local q base of wave
    const int ti = qw >> 4;                        // uniform per wave

    s8v qf = *(const s8v*)(Q + ((size_t)bh * 512 + qw + lq) * 32 + g * 8);
    const uint16_t* kg = K + (size_t)bh * 16384;   // K rows t, 32 d each
    const uint16_t* vg = V + (size_t)bh * 16384;   // V^T rows d, 512 t each

    // ---- stage the per-head rel slice once (line-dense, shared by block) ----
    {
        const uint16_t* rsrc = REL2 + ((size_t)h << 14);
        #pragma unroll
        for (int it = 0; it < 8; ++it) {
            int off = it * 2048 + tid * 8;
            *(u8v*)(Rel + off) = *(const u8v*)(rsrc + off);
        }
    }

    // staging indices (block-wide cooperative, line-dense)
    const int ktrow = tid >> 2, ktcol = (tid & 3) * 8;   // 64 rows x 32 elems
    const int vtrow = tid >> 3, vtcol = (tid & 7) * 8;   // 32 rows x 64 elems
    const uint16_t* kgs = kg + (size_t)ktrow * 32 + ktcol;
    const uint16_t* vgs = vg + (size_t)vtrow * 512 + vtcol;

    f4v o0 = {}, o1 = {};
    float mrow = -3.0e38f, lrow = 0.f;

    // prologue: load tile 0 into registers
    u8v kreg = *(const u8v*)(kgs);
    u8v vreg = *(const u8v*)(vgs);

    for (int tile = 0; tile < 8; ++tile) {
        const int t0 = tile * 64;

        __syncthreads();                           // prev tile's LDS reads done
        *(u8v*)(Ks + ktrow * 40 + ktcol) = kreg;
        *(u8v*)(Vs + vtrow * 80 + vtcol) = vreg;
        __syncthreads();                           // writes visible (incl. Rel @ tile 0)

        // issue-early: next tile's global loads hide under this tile's compute
        if (tile < 7) {
            kreg = *(const u8v*)(kgs + (t0 + 64) * 32);
            vreg = *(const u8v*)(vgs + (t0 + 64));
        }

        // ---- S-tile = bias (C-init from LDS rel slice) + K.Q^T, log2 domain --
        f4v a0, a1, a2, a3;
        {
            const int tj0 = t0 >> 4;               // uniform per wave
            const uint16_t* rb = Rel + (lq << 4) + (g << 2);
            ushort4 z0 = *(const ushort4*)(rb + ((ti - tj0 - 0 + 31) << 8));
            ushort4 z1 = *(const ushort4*)(rb + ((ti - tj0 - 1 + 31) << 8));
            ushort4 z2 = *(const ushort4*)(rb + ((ti - tj0 - 2 + 31) << 8));
            ushort4 z3 = *(const ushort4*)(rb + ((ti - tj0 - 3 + 31) << 8));
            a0[0]=bf2f(z0.x); a0[1]=bf2f(z0.y); a0[2]=bf2f(z0.z); a0[3]=bf2f(z0.w);
            a1[0]=bf2f(z1.x); a1[1]=bf2f(z1.y); a1[2]=bf2f(z1.z); a1[3]=bf2f(z1.w);
            a2[0]=bf2f(z2.x); a2[1]=bf2f(z2.y); a2[2]=bf2f(z2.z); a2[3]=bf2f(z2.w);
            a3[0]=bf2f(z3.x); a3[1]=bf2f(z3.y); a3[2]=bf2f(z3.z); a3[3]=bf2f(z3.w);
        }
        a0 = __builtin_amdgcn_mfma_f32_16x16x32_bf16(*(const s8v*)(Ks + ( 0 + lq) * 40 + g * 8), qf, a0, 0, 0, 0);
        a1 = __builtin_amdgcn_mfma_f32_16x16x32_bf16(*(const s8v*)(Ks + (16 + lq) * 40 + g * 8), qf, a1, 0, 0, 0);
        a2 = __builtin_amdgcn_mfma_f32_16x16x32_bf16(*(const s8v*)(Ks + (32 + lq) * 40 + g * 8), qf, a2, 0, 0, 0);
        a3 = __builtin_amdgcn_mfma_f32_16x16x32_bf16(*(const s8v*)(Ks + (48 + lq) * 40 + g * 8), qf, a3, 0, 0, 0);

        // ---- row max (green) ----
        float p01 = fmaxf(fmaxf(a0[0], a0[1]), fmaxf(a0[2], a0[3]));
        float p23 = fmaxf(fmaxf(a1[0], a1[1]), fmaxf(a1[2], a1[3]));
        float p45 = fmaxf(fmaxf(a2[0], a2[1]), fmaxf(a2[2], a2[3]));
        float p67 = fmaxf(fmaxf(a3[0], a3[1]), fmaxf(a3[2], a3[3]));
        float pmax = fmaxf(fmaxf(p01, p23), fmaxf(p45, p67));
        pmax = fmaxf(pmax, __shfl_xor(pmax, 16));
        pmax = fmaxf(pmax, __shfl_xor(pmax, 32));

        // ---- online-softmax update, defer-rescale threshold 8 (green) ----
        if (!__all(pmax - mrow <= 8.0f)) {
            float mnew = fmaxf(mrow, pmax);
            float scale = __builtin_amdgcn_exp2f(mrow - mnew);
            lrow *= scale;
            float s0 = __shfl(scale, g * 4 + 0);
            float s1 = __shfl(scale, g * 4 + 1);
            float s2 = __shfl(scale, g * 4 + 2);
            float s3 = __shfl(scale, g * 4 + 3);
            o0[0] *= s0; o0[1] *= s1; o0[2] *= s2; o0[3] *= s3;
            o1[0] *= s0; o1[1] *= s1; o1[2] *= s2; o1[3] *= s3;
            mrow = mnew;
        }

        // ---- P = exp2(S - m), per-lane partial row-sum (green) ----
        float lsum = 0.f;
        #pragma unroll
        for (int r = 0; r < 4; ++r) {
            a0[r] = __builtin_amdgcn_exp2f(a0[r] - mrow); lsum += a0[r];
            a1[r] = __builtin_amdgcn_exp2f(a1[r] - mrow); lsum += a1[r];
            a2[r] = __builtin_amdgcn_exp2f(a2[r] - mrow); lsum += a2[r];
            a3[r] = __builtin_amdgcn_exp2f(a3[r] - mrow); lsum += a3[r];
        }
        lrow += lsum;

        // ---- in-register re-layout P -> PV A-fragments (green verbatim) ----
        {   // tc = 0: chunks a0,a1 ; V = Vs rows lq (d 0-15) / lq+16 (d 16-31)
            uint32_t A0 = cvtpk(a0[0], a0[1]);
            uint32_t A1 = cvtpk(a0[2], a0[3]);
            uint32_t B0 = cvtpk(a1[0], a1[1]);
            uint32_t B1 = cvtpk(a1[2], a1[3]);
            uint32_t xA0 = (uint32_t)__shfl_xor((int)A0, 32);
            uint32_t xA1 = (uint32_t)__shfl_xor((int)A1, 32);
            uint32_t xB0 = (uint32_t)__shfl_xor((int)B0, 32);
            uint32_t xB1 = (uint32_t)__shfl_xor((int)B1, 32);
            uint32_t Ap0 = ghi ? xB0 : A0, Ap1 = ghi ? xB1 : A1;
            uint32_t Bp0 = ghi ? B0 : xA0, Bp1 = ghi ? B1 : xA1;
            uint32_t Z0 = godd ? Ap0 : Bp0, Z1 = godd ? Ap1 : Bp1;
            uint32_t sZ0 = (uint32_t)__shfl_xor((int)Z0, 16);
            uint32_t sZ1 = (uint32_t)__shfl_xor((int)Z1, 16);
            uint4 wq;
            wq.x = godd ? sZ0 : Ap0; wq.y = godd ? sZ1 : Ap1;
            wq.z = godd ? Bp0 : sZ0; wq.w = godd ? Bp1 : sZ1;
            s8v pf = __builtin_bit_cast(s8v, wq);
            s8v vf0 = *(const s8v*)(Vs + lq * 80 + g * 8);
            s8v vf2 = *(const s8v*)(Vs + (lq + 16) * 80 + g * 8);
            o0 = __builtin_amdgcn_mfma_f32_16x16x32_bf16(pf, vf0, o0, 0, 0, 0);
            o1 = __builtin_amdgcn_mfma_f32_16x16x32_bf16(pf, vf2, o1, 0, 0, 0);
        }
        {   // tc = 1: chunks a2,a3 ; V cols t0+32
            uint32_t A0 = cvtpk(a2[0], a2[1]);
            uint32_t A1 = cvtpk(a2[2], a2[3]);
            uint32_t B0 = cvtpk(a3[0], a3[1]);
            uint32_t B1 = cvtpk(a3[2], a3[3]);
            uint32_t xA0 = (uint32_t)__shfl_xor((int)A0, 32);
            uint32_t xA1 = (uint32_t)__shfl_xor((int)A1, 32);
            uint32_t xB0 = (uint32_t)__shfl_xor((int)B0, 32);
            uint32_t xB1 = (uint32_t)__shfl_xor((int)B1, 32);
            uint32_t Ap0 = ghi ? xB0 : A0, Ap1 = ghi ? xB1 : A1;
            uint32_t Bp0 = ghi ? B0 : xA0, Bp1 = ghi ? B1 : xA1;
            uint32_t Z0 = godd ? Ap0 : Bp0, Z1 = godd ? Ap1 : Bp1;
            uint32_t sZ0 = (uint32_t)__shfl_xor((int)Z0, 16);
            uint32_t sZ1 = (uint32_t)__shfl_xor((int)Z1, 16);
            uint4 wq;
            wq.x = godd ? sZ0 : Ap0; wq.y = godd ? sZ1 : Ap1;
            wq.z = godd ? Bp0 : sZ0; wq.w = godd ? Bp1 : sZ1;
            s8v pf = __builtin_bit_cast(s8v, wq);
            s8v vf1 = *(const s8v*)(Vs + lq * 80 + 32 + g * 8);
            s8v vf3 = *(const s8v*)(Vs + (lq + 16) * 80 + 32 + g * 8);
            o0 = __builtin_amdgcn_mfma_f32_16x16x32_bf16(pf, vf1, o0, 0, 0, 0);
            o1 = __builtin_amdgcn_mfma_f32_16x16x32_bf16(pf, vf3, o1, 0, 0, 0);
        }
    }

    // ---- finalize: row sum across g, normalize, store (green) ----
    lrow += __shfl_xor(lrow, 16);
    lrow += __shfl_xor(lrow, 32);
    const float inv = 1.0f / lrow;                 // valid for row lq
    #pragma unroll
    for (int r = 0; r < 4; ++r) {
        const float iv = __shfl(inv, g * 4 + r);   // row g*4+r's denom
        const int srow = b * 512 + qw + g * 4 + r;
        uint16_t* dst = AO + (size_t)srow * 256 + h * 32 + lq;
        dst[0]  = f2bf(o0[r] * iv);
        dst[16] = f2bf(o1[r] * iv);
    }
}

// ---------------- Kernel 4: output projection (A bf16, W bf16) ---------------
__global__ __launch_bounds__(256) void proj_gemm(const uint16_t* __restrict__ A,
                                                 const uint16_t* __restrict__ W,
                                                 const float* __restrict__ Bv,
                                                 float* __restrict__ Out) {
    __shared__ uint16_t As[128 * 40];
    __shared__ uint16_t Bs[128 * 40];
    const int tid = threadIdx.x;
    const int bn = blockIdx.x * 128;
    const int bm = blockIdx.y * 128;
    const int lane = tid & 63, wv = tid >> 6;
    const int wm = (wv >> 1) * 64, wn = (wv & 1) * 64;
    const int lq = lane & 15, g = lane >> 4;
    const int srow = tid >> 1;
    const int scol = (tid & 1) * 16;

    f4v acc[4][4] = {};

    for (int ks = 0; ks < 8; ++ks) {
        const int k0 = ks * 32;
        __syncthreads();
        {
            const uint16_t* src = A + (size_t)(bm + srow) * 256 + k0 + scol;
            u8v p0 = *(const u8v*)(src);
            u8v p1 = *(const u8v*)(src + 8);
            *(u8v*)(As + srow * 40 + scol)     = p0;
            *(u8v*)(As + srow * 40 + scol + 8) = p1;

            const uint16_t* srcb = W + (size_t)(bn + srow) * 256 + k0 + scol;
            u8v q0 = *(const u8v*)(srcb);
            u8v q1 = *(const u8v*)(srcb + 8);
            *(u8v*)(Bs + srow * 40 + scol)     = q0;
            *(u8v*)(Bs + srow * 40 + scol + 8) = q1;
        }
        __syncthreads();
        s8v af[4], bf[4];
        #pragma unroll
        for (int i = 0; i < 4; ++i) {
            af[i] = *(const s8v*)(As + (wm + i * 16 + lq) * 40 + g * 8);
            bf[i] = *(const s8v*)(Bs + (wn + i * 16 + lq) * 40 + g * 8);
        }
        #pragma unroll
        for (int mt = 0; mt < 4; ++mt)
            #pragma unroll
            for (int nt = 0; nt < 4; ++nt)
                acc[mt][nt] = __builtin_amdgcn_mfma_f32_16x16x32_bf16(af[mt], bf[nt], acc[mt][nt], 0, 0, 0);
    }

    #pragma unroll
    for (int nt = 0; nt < 4; ++nt) {
        const int n = bn + wn + nt * 16 + lq;
        const float bv = Bv[n];
        #pragma unroll
        for (int mt = 0; mt < 4; ++mt) {
            #pragma unroll
            for (int r = 0; r < 4; ++r) {
                const int mm = bm + wm + mt * 16 + g * 4 + r;
                Out[(size_t)mm * 256 + n] = acc[mt][nt][r] + bv;
            }
        }
    }
}

extern "C" void kernel_launch(void* const* d_in, const int* in_sizes, int n_in,
                              void* d_out, int out_size, void* d_ws, size_t ws_size,
                              hipStream_t stream) {
    const float* x      = (const float*)d_in[0];
    const float* qkv_w  = (const float*)d_in[1];
    const float* qkv_b  = (const float*)d_in[2];
    const float* proj_w = (const float*)d_in[3];
    const float* proj_b = (const float*)d_in[4];
    const float* rel    = (const float*)d_in[5];
    float* out = (float*)d_out;

    uint16_t* ws = (uint16_t*)d_ws;
    const size_t QE = (size_t)NB * NH * NS * ND;          // 8,388,608 elems
    uint16_t* Qb   = ws;                                  // 16 MiB
    uint16_t* Kb   = Qb + QE;                             // 16 MiB
    uint16_t* Vb   = Kb + QE;                             // 16 MiB
    uint16_t* Rb   = Vb + QE;                             // 16 MiB: Xbf, then AO
    uint16_t* REL2 = Rb + QE;                             // 8 x 16384 bf16 (256 KiB)
    uint16_t* Wqb  = REL2 + 131072;                       // 768x256 bf16 (384 KiB)
    uint16_t* Wpb  = Wqb + 196608;                        // 256x256 bf16 (128 KiB)

    cvt_f2bf<<<4096, 256, 0, stream>>>(x, Rb);            // X -> bf16
    cvt_f2bf<<<96, 256, 0, stream>>>(qkv_w, Wqb);         // qkv_w -> bf16 (once)
    cvt_f2bf<<<32, 256, 0, stream>>>(proj_w, Wpb);        // proj_w -> bf16 (once)
    rel_fill<<<512, 256, 0, stream>>>(rel, REL2);
    qkv_gemm<<<dim3(6, 256), 256, 0, stream>>>(Rb, Wqb, qkv_b, Qb, Kb, Vb);
    attn_kern<<<4096, 256, 0, stream>>>(Qb, Kb, Vb, REL2, Rb);
    proj_gemm<<<dim3(2, 256), 256, 0, stream>>>(Rb, Wpb, proj_b, out);
}

// Round 13
// 134.469 us; speedup vs baseline: 1.8248x; 1.1557x over previous
//
#include <hip/hip_runtime.h>
#include <stdint.h>

#define NB 64
#define NS 512
#define NC 256
#define NH 8
#define ND 32

typedef __attribute__((ext_vector_type(8))) short s8v;
typedef __attribute__((ext_vector_type(8))) unsigned short u8v;
typedef __attribute__((ext_vector_type(4))) float f4v;

#define LOG2E 1.4426950408889634f

static __device__ __forceinline__ uint16_t f2bf(float f) {
    uint32_t u = __builtin_bit_cast(uint32_t, f);
    u += 0x7fffu + ((u >> 16) & 1u);
    return (uint16_t)(u >> 16);
}
static __device__ __forceinline__ float bf2f(uint16_t h) {
    uint32_t u = ((uint32_t)h) << 16;
    return __builtin_bit_cast(float, u);
}
static __device__ __forceinline__ uint32_t cvtpk(float lo, float hi) {
    uint32_t r;
    asm("v_cvt_pk_bf16_f32 %0, %1, %2" : "=v"(r) : "v"(lo), "v"(hi));
    return r;
}

// ---------------- Kernel 0: bulk fp32 -> bf16 convert (n multiple of 2048) ----
__global__ __launch_bounds__(256) void cvt_f2bf(const float* __restrict__ in,
                                                uint16_t* __restrict__ out) {
    int i = (blockIdx.x * 256 + threadIdx.x) * 8;
    f4v a = *(const f4v*)(in + i);
    f4v b = *(const f4v*)(in + i + 4);
    uint4 w;
    w.x = cvtpk(a[0], a[1]); w.y = cvtpk(a[2], a[3]);
    w.z = cvtpk(b[0], b[1]); w.w = cvtpk(b[2], b[3]);
    *(uint4*)(out + i) = w;
}

// ---------------- Kernel 1: compact per-head rel table, PADDED ---------------
// REL2[h][dt][li*20 + lj], dt in [0,63] (63 used), li-stride 20 (bank-spread).
// Same f2bf(rel * LOG2E) rounding -> bit-identical bias values. Pad = 0.
__global__ __launch_bounds__(256) void rel_fill(const float* __restrict__ rel,
                                                uint16_t* __restrict__ rel2) {
    int id = blockIdx.x * 256 + threadIdx.x;       // 8 * 64 * 320 = 163840
    int h = id / 20480, rem = id % 20480;
    int dt = rem / 320, q = rem % 320;
    int li = q / 20, lj = q % 20;
    float v = (lj < 16 && dt < 63) ? rel[(((dt << 4) + li) * 16 + lj) * 8 + h] * LOG2E : 0.f;
    rel2[id] = f2bf(v);
}

// ---------------- Kernel 2: QKV GEMM (A = bf16 X, B = bf16 W) ----------------
// writes q (scaled by SCALE*log2e, [bh][s][d]), k ([bh][s][d]), v^T ([bh][d][s])
__global__ __launch_bounds__(256) void qkv_gemm(const uint16_t* __restrict__ X,
                                                const uint16_t* __restrict__ W,
                                                const float* __restrict__ Bv,
                                                uint16_t* __restrict__ Qo,
                                                uint16_t* __restrict__ Ko,
                                                uint16_t* __restrict__ Vo) {
    __shared__ uint16_t As[128 * 40];
    __shared__ uint16_t Bs[128 * 40];
    const int tid = threadIdx.x;
    const int bn = blockIdx.x * 128;
    const int bm = blockIdx.y * 128;
    const int lane = tid & 63, wv = tid >> 6;
    const int wm = (wv >> 1) * 64, wn = (wv & 1) * 64;
    const int lq = lane & 15, g = lane >> 4;
    const int srow = tid >> 1;
    const int scol = (tid & 1) * 16;

    f4v acc[4][4] = {};

    for (int ks = 0; ks < 8; ++ks) {
        const int k0 = ks * 32;
        __syncthreads();
        {
            const uint16_t* src = X + (size_t)(bm + srow) * 256 + k0 + scol;
            u8v p0 = *(const u8v*)(src);
            u8v p1 = *(const u8v*)(src + 8);
            *(u8v*)(As + srow * 40 + scol)     = p0;
            *(u8v*)(As + srow * 40 + scol + 8) = p1;

            const uint16_t* srcb = W + (size_t)(bn + srow) * 256 + k0 + scol;
            u8v q0 = *(const u8v*)(srcb);
            u8v q1 = *(const u8v*)(srcb + 8);
            *(u8v*)(Bs + srow * 40 + scol)     = q0;
            *(u8v*)(Bs + srow * 40 + scol + 8) = q1;
        }
        __syncthreads();
        s8v af[4], bf[4];
        #pragma unroll
        for (int i = 0; i < 4; ++i) {
            af[i] = *(const s8v*)(As + (wm + i * 16 + lq) * 40 + g * 8);
            bf[i] = *(const s8v*)(Bs + (wn + i * 16 + lq) * 40 + g * 8);
        }
        #pragma unroll
        for (int mt = 0; mt < 4; ++mt)
            #pragma unroll
            for (int nt = 0; nt < 4; ++nt)
                acc[mt][nt] = __builtin_amdgcn_mfma_f32_16x16x32_bf16(af[mt], bf[nt], acc[mt][nt], 0, 0, 0);
    }

    const int gsel = bn >> 8;   // 0=q, 1=k, 2=v
    const float scl = (gsel == 0) ? (0.35355339059327373f * LOG2E) : 1.0f;
    #pragma unroll
    for (int nt = 0; nt < 4; ++nt) {
        const int ng = bn + wn + nt * 16 + lq;
        const float bv = Bv[ng];
        const int c = ng & 255, hh = c >> 5, dd = c & 31;
        #pragma unroll
        for (int mt = 0; mt < 4; ++mt) {
            #pragma unroll
            for (int r = 0; r < 4; ++r) {
                const int m = bm + wm + mt * 16 + g * 4 + r;
                const int b = m >> 9, s = m & 511;
                const uint16_t val = f2bf((acc[mt][nt][r] + bv) * scl);
                if (gsel == 0)      Qo[((size_t)(b * 8 + hh) * 512 + s) * 32 + dd] = val;
                else if (gsel == 1) Ko[((size_t)(b * 8 + hh) * 512 + s) * 32 + dd] = val;
                else                Vo[((size_t)(b * 8 + hh) * 32 + dd) * 512 + s] = val;
            }
        }
    }
}

// ---------------- Kernel 3: flash attention, 512-thread blocks ---------------
// R12-green per-wave math verbatim. Changes: (a) 8 waves/block covering 128
// q-rows -> Ks/Vs/Rel staging amortized over 2x work, 24 waves/CU at same
// LDS; (b) Rel li-stride padded to 20 elems -> bank-conflict-free read.
// Staging split: threads 0-255 stage K, 256-511 stage V (one u8v each).
// 1-D grid 2048: h = p&7 (XCD pin), qq = (p>>3)&3, b = p>>5.
__global__ __launch_bounds__(512) void attn_kern(const uint16_t* __restrict__ Q,
                                                 const uint16_t* __restrict__ K,
                                                 const uint16_t* __restrict__ V,
                                                 const uint16_t* __restrict__ REL2,
                                                 uint16_t* __restrict__ AO) {
    __shared__ uint16_t Ks[64 * 40];               // K tile: 64 t-rows x 32 d (pad 40)
    __shared__ uint16_t Vs[32 * 80];               // V^T tile: 32 d-rows x 64 t (pad 80)
    __shared__ uint16_t Rel[64 * 320];             // padded rel slice (40 KB)

    const int p = blockIdx.x;
    const int h  = p & 7;                          // XCD-pinned head
    const int qq = (p >> 3) & 3;
    const int b  = p >> 5;
    const int tid = threadIdx.x, lane = tid & 63, wv = tid >> 6;
    const int lq = lane & 15, g = lane >> 4;
    const bool godd = (g & 1);
    const bool ghi = (g >= 2);
    const int bh = b * 8 + h;
    const int qw = qq * 128 + wv * 16;             // window-local q base of wave
    const int ti = (qw >> 4);                      // uniform per wave

    s8v qf = *(const s8v*)(Q + ((size_t)bh * 512 + qw + lq) * 32 + g * 8);
    const uint16_t* kg = K + (size_t)bh * 16384;   // K rows t, 32 d each
    const uint16_t* vg = V + (size_t)bh * 16384;   // V^T rows d, 512 t each

    // ---- stage the per-head padded rel slice once (line-dense) ----
    {
        const uint16_t* rsrc = REL2 + (size_t)h * 20480;
        #pragma unroll
        for (int it = 0; it < 5; ++it) {
            int off = it * 4096 + tid * 8;
            *(u8v*)(Rel + off) = *(const u8v*)(rsrc + off);
        }
    }

    // staging indices: lower half stages K, upper half stages V (line-dense)
    const bool isK = (tid < 256);
    const int t2 = tid & 255;
    const int ktrow = t2 >> 2, ktcol = (t2 & 3) * 8;     // 64 rows x 32 elems
    const int vtrow = t2 >> 3, vtcol = (t2 & 7) * 8;     // 32 rows x 64 elems
    const uint16_t* gsrc = isK ? (kg + (size_t)ktrow * 32 + ktcol)
                               : (vg + (size_t)vtrow * 512 + vtcol);
    uint16_t* ldst = isK ? (Ks + ktrow * 40 + ktcol)
                         : (Vs + vtrow * 80 + vtcol);
    const int gstep = isK ? (64 * 32) : 64;        // per-tile advance (elems)

    f4v o0 = {}, o1 = {};
    float mrow = -3.0e38f, lrow = 0.f;

    // prologue: load tile 0 into registers
    u8v sreg = *(const u8v*)(gsrc);

    for (int tile = 0; tile < 8; ++tile) {
        const int t0 = tile * 64;

        __syncthreads();                           // prev tile's LDS reads done
        *(u8v*)(ldst) = sreg;
        __syncthreads();                           // writes visible (incl. Rel @ tile 0)

        // issue-early: next tile's global loads hide under this tile's compute
        if (tile < 7) {
            sreg = *(const u8v*)(gsrc + (size_t)(tile + 1) * gstep);
        }

        // ---- S-tile = bias (C-init from padded LDS rel) + K.Q^T, log2 domain
        f4v a0, a1, a2, a3;
        {
            const int tj0 = t0 >> 4;               // uniform per wave
            const uint16_t* rb = Rel + lq * 20 + g * 4;
            ushort4 z0 = *(const ushort4*)(rb + (ti - tj0 - 0 + 31) * 320);
            ushort4 z1 = *(const ushort4*)(rb + (ti - tj0 - 1 + 31) * 320);
            ushort4 z2 = *(const ushort4*)(rb + (ti - tj0 - 2 + 31) * 320);
            ushort4 z3 = *(const ushort4*)(rb + (ti - tj0 - 3 + 31) * 320);
            a0[0]=bf2f(z0.x); a0[1]=bf2f(z0.y); a0[2]=bf2f(z0.z); a0[3]=bf2f(z0.w);
            a1[0]=bf2f(z1.x); a1[1]=bf2f(z1.y); a1[2]=bf2f(z1.z); a1[3]=bf2f(z1.w);
            a2[0]=bf2f(z2.x); a2[1]=bf2f(z2.y); a2[2]=bf2f(z2.z); a2[3]=bf2f(z2.w);
            a3[0]=bf2f(z3.x); a3[1]=bf2f(z3.y); a3[2]=bf2f(z3.z); a3[3]=bf2f(z3.w);
        }
        a0 = __builtin_amdgcn_mfma_f32_16x16x32_bf16(*(const s8v*)(Ks + ( 0 + lq) * 40 + g * 8), qf, a0, 0, 0, 0);
        a1 = __builtin_amdgcn_mfma_f32_16x16x32_bf16(*(const s8v*)(Ks + (16 + lq) * 40 + g * 8), qf, a1, 0, 0, 0);
        a2 = __builtin_amdgcn_mfma_f32_16x16x32_bf16(*(const s8v*)(Ks + (32 + lq) * 40 + g * 8), qf, a2, 0, 0, 0);
        a3 = __builtin_amdgcn_mfma_f32_16x16x32_bf16(*(const s8v*)(Ks + (48 + lq) * 40 + g * 8), qf, a3, 0, 0, 0);

        // ---- row max (green) ----
        float p01 = fmaxf(fmaxf(a0[0], a0[1]), fmaxf(a0[2], a0[3]));
        float p23 = fmaxf(fmaxf(a1[0], a1[1]), fmaxf(a1[2], a1[3]));
        float p45 = fmaxf(fmaxf(a2[0], a2[1]), fmaxf(a2[2], a2[3]));
        float p67 = fmaxf(fmaxf(a3[0], a3[1]), fmaxf(a3[2], a3[3]));
        float pmax = fmaxf(fmaxf(p01, p23), fmaxf(p45, p67));
        pmax = fmaxf(pmax, __shfl_xor(pmax, 16));
        pmax = fmaxf(pmax, __shfl_xor(pmax, 32));

        // ---- online-softmax update, defer-rescale threshold 8 (green) ----
        if (!__all(pmax - mrow <= 8.0f)) {
            float mnew = fmaxf(mrow, pmax);
            float scale = __builtin_amdgcn_exp2f(mrow - mnew);
            lrow *= scale;
            float s0 = __shfl(scale, g * 4 + 0);
            float s1 = __shfl(scale, g * 4 + 1);
            float s2 = __shfl(scale, g * 4 + 2);
            float s3 = __shfl(scale, g * 4 + 3);
            o0[0] *= s0; o0[1] *= s1; o0[2] *= s2; o0[3] *= s3;
            o1[0] *= s0; o1[1] *= s1; o1[2] *= s2; o1[3] *= s3;
            mrow = mnew;
        }

        // ---- P = exp2(S - m), per-lane partial row-sum (green) ----
        float lsum = 0.f;
        #pragma unroll
        for (int r = 0; r < 4; ++r) {
            a0[r] = __builtin_amdgcn_exp2f(a0[r] - mrow); lsum += a0[r];
            a1[r] = __builtin_amdgcn_exp2f(a1[r] - mrow); lsum += a1[r];
            a2[r] = __builtin_amdgcn_exp2f(a2[r] - mrow); lsum += a2[r];
            a3[r] = __builtin_amdgcn_exp2f(a3[r] - mrow); lsum += a3[r];
        }
        lrow += lsum;

        // ---- in-register re-layout P -> PV A-fragments (green verbatim) ----
        {   // tc = 0: chunks a0,a1 ; V = Vs rows lq (d 0-15) / lq+16 (d 16-31)
            uint32_t A0 = cvtpk(a0[0], a0[1]);
            uint32_t A1 = cvtpk(a0[2], a0[3]);
            uint32_t B0 = cvtpk(a1[0], a1[1]);
            uint32_t B1 = cvtpk(a1[2], a1[3]);
            uint32_t xA0 = (uint32_t)__shfl_xor((int)A0, 32);
            uint32_t xA1 = (uint32_t)__shfl_xor((int)A1, 32);
            uint32_t xB0 = (uint32_t)__shfl_xor((int)B0, 32);
            uint32_t xB1 = (uint32_t)__shfl_xor((int)B1, 32);
            uint32_t Ap0 = ghi ? xB0 : A0, Ap1 = ghi ? xB1 : A1;
            uint32_t Bp0 = ghi ? B0 : xA0, Bp1 = ghi ? B1 : xA1;
            uint32_t Z0 = godd ? Ap0 : Bp0, Z1 = godd ? Ap1 : Bp1;
            uint32_t sZ0 = (uint32_t)__shfl_xor((int)Z0, 16);
            uint32_t sZ1 = (uint32_t)__shfl_xor((int)Z1, 16);
            uint4 wq;
            wq.x = godd ? sZ0 : Ap0; wq.y = godd ? sZ1 : Ap1;
            wq.z = godd ? Bp0 : sZ0; wq.w = godd ? Bp1 : sZ1;
            s8v pf = __builtin_bit_cast(s8v, wq);
            s8v vf0 = *(const s8v*)(Vs + lq * 80 + g * 8);
            s8v vf2 = *(const s8v*)(Vs + (lq + 16) * 80 + g * 8);
            o0 = __builtin_amdgcn_mfma_f32_16x16x32_bf16(pf, vf0, o0, 0, 0, 0);
            o1 = __builtin_amdgcn_mfma_f32_16x16x32_bf16(pf, vf2, o1, 0, 0, 0);
        }
        {   // tc = 1: chunks a2,a3 ; V cols t0+32
            uint32_t A0 = cvtpk(a2[0], a2[1]);
            uint32_t A1 = cvtpk(a2[2], a2[3]);
            uint32_t B0 = cvtpk(a3[0], a3[1]);
            uint32_t B1 = cvtpk(a3[2], a3[3]);
            uint32_t xA0 = (uint32_t)__shfl_xor((int)A0, 32);
            uint32_t xA1 = (uint32_t)__shfl_xor((int)A1, 32);
            uint32_t xB0 = (uint32_t)__shfl_xor((int)B0, 32);
            uint32_t xB1 = (uint32_t)__shfl_xor((int)B1, 32);
            uint32_t Ap0 = ghi ? xB0 : A0, Ap1 = ghi ? xB1 : A1;
            uint32_t Bp0 = ghi ? B0 : xA0, Bp1 = ghi ? B1 : xA1;
            uint32_t Z0 = godd ? Ap0 : Bp0, Z1 = godd ? Ap1 : Bp1;
            uint32_t sZ0 = (uint32_t)__shfl_xor((int)Z0, 16);
            uint32_t sZ1 = (uint32_t)__shfl_xor((int)Z1, 16);
            uint4 wq;
            wq.x = godd ? sZ0 : Ap0; wq.y = godd ? sZ1 : Ap1;
            wq.z = godd ? Bp0 : sZ0; wq.w = godd ? Bp1 : sZ1;
            s8v pf = __builtin_bit_cast(s8v, wq);
            s8v vf1 = *(const s8v*)(Vs + lq * 80 + 32 + g * 8);
            s8v vf3 = *(const s8v*)(Vs + (lq + 16) * 80 + 32 + g * 8);
            o0 = __builtin_amdgcn_mfma_f32_16x16x32_bf16(pf, vf1, o0, 0, 0, 0);
            o1 = __builtin_amdgcn_mfma_f32_16x16x32_bf16(pf, vf3, o1, 0, 0, 0);
        }
    }

    // ---- finalize: row sum across g, normalize, store (green) ----
    lrow += __shfl_xor(lrow, 16);
    lrow += __shfl_xor(lrow, 32);
    const float inv = 1.0f / lrow;                 // valid for row lq
    #pragma unroll
    for (int r = 0; r < 4; ++r) {
        const float iv = __shfl(inv, g * 4 + r);   // row g*4+r's denom
        const int srow = b * 512 + qw + g * 4 + r;
        uint16_t* dst = AO + (size_t)srow * 256 + h * 32 + lq;
        dst[0]  = f2bf(o0[r] * iv);
        dst[16] = f2bf(o1[r] * iv);
    }
}

// ---------------- Kernel 4: output projection (A bf16, W bf16) ---------------
__global__ __launch_bounds__(256) void proj_gemm(const uint16_t* __restrict__ A,
                                                 const uint16_t* __restrict__ W,
                                                 const float* __restrict__ Bv,
                                                 float* __restrict__ Out) {
    __shared__ uint16_t As[128 * 40];
    __shared__ uint16_t Bs[128 * 40];
    const int tid = threadIdx.x;
    const int bn = blockIdx.x * 128;
    const int bm = blockIdx.y * 128;
    const int lane = tid & 63, wv = tid >> 6;
    const int wm = (wv >> 1) * 64, wn = (wv & 1) * 64;
    const int lq = lane & 15, g = lane >> 4;
    const int srow = tid >> 1;
    const int scol = (tid & 1) * 16;

    f4v acc[4][4] = {};

    for (int ks = 0; ks < 8; ++ks) {
        const int k0 = ks * 32;
        __syncthreads();
        {
            const uint16_t* src = A + (size_t)(bm + srow) * 256 + k0 + scol;
            u8v p0 = *(const u8v*)(src);
            u8v p1 = *(const u8v*)(src + 8);
            *(u8v*)(As + srow * 40 + scol)     = p0;
            *(u8v*)(As + srow * 40 + scol + 8) = p1;

            const uint16_t* srcb = W + (size_t)(bn + srow) * 256 + k0 + scol;
            u8v q0 = *(const u8v*)(srcb);
            u8v q1 = *(const u8v*)(srcb + 8);
            *(u8v*)(Bs + srow * 40 + scol)     = q0;
            *(u8v*)(Bs + srow * 40 + scol + 8) = q1;
        }
        __syncthreads();
        s8v af[4], bf[4];
        #pragma unroll
        for (int i = 0; i < 4; ++i) {
            af[i] = *(const s8v*)(As + (wm + i * 16 + lq) * 40 + g * 8);
            bf[i] = *(const s8v*)(Bs + (wn + i * 16 + lq) * 40 + g * 8);
        }
        #pragma unroll
        for (int mt = 0; mt < 4; ++mt)
            #pragma unroll
            for (int nt = 0; nt < 4; ++nt)
                acc[mt][nt] = __builtin_amdgcn_mfma_f32_16x16x32_bf16(af[mt], bf[nt], acc[mt][nt], 0, 0, 0);
    }

    #pragma unroll
    for (int nt = 0; nt < 4; ++nt) {
        const int n = bn + wn + nt * 16 + lq;
        const float bv = Bv[n];
        #pragma unroll
        for (int mt = 0; mt < 4; ++mt) {
            #pragma unroll
            for (int r = 0; r < 4; ++r) {
                const int mm = bm + wm + mt * 16 + g * 4 + r;
                Out[(size_t)mm * 256 + n] = acc[mt][nt][r] + bv;
            }
        }
    }
}

extern "C" void kernel_launch(void* const* d_in, const int* in_sizes, int n_in,
                              void* d_out, int out_size, void* d_ws, size_t ws_size,
                              hipStream_t stream) {
    const float* x      = (const float*)d_in[0];
    const float* qkv_w  = (const float*)d_in[1];
    const float* qkv_b  = (const float*)d_in[2];
    const float* proj_w = (const float*)d_in[3];
    const float* proj_b = (const float*)d_in[4];
    const float* rel    = (const float*)d_in[5];
    float* out = (float*)d_out;

    uint16_t* ws = (uint16_t*)d_ws;
    const size_t QE = (size_t)NB * NH * NS * ND;          // 8,388,608 elems
    uint16_t* Qb   = ws;                                  // 16 MiB
    uint16_t* Kb   = Qb + QE;                             // 16 MiB
    uint16_t* Vb   = Kb + QE;                             // 16 MiB
    uint16_t* Rb   = Vb + QE;                             // 16 MiB: Xbf, then AO
    uint16_t* REL2 = Rb + QE;                             // 8 x 20480 bf16 (320 KiB)
    uint16_t* Wqb  = REL2 + 163840;                       // 768x256 bf16 (384 KiB)
    uint16_t* Wpb  = Wqb + 196608;                        // 256x256 bf16 (128 KiB)

    cvt_f2bf<<<4096, 256, 0, stream>>>(x, Rb);            // X -> bf16
    cvt_f2bf<<<96, 256, 0, stream>>>(qkv_w, Wqb);         // qkv_w -> bf16 (once)
    cvt_f2bf<<<32, 256, 0, stream>>>(proj_w, Wpb);        // proj_w -> bf16 (once)
    rel_fill<<<640, 256, 0, stream>>>(rel, REL2);
    qkv_gemm<<<dim3(6, 256), 256, 0, stream>>>(Rb, Wqb, qkv_b, Qb, Kb, Vb);
    attn_kern<<<2048, 512, 0, stream>>>(Qb, Kb, Vb, REL2, Rb);
    proj_gemm<<<dim3(2, 256), 256, 0, stream>>>(Rb, Wpb, proj_b, out);
}

// Round 15
// 121.160 us; speedup vs baseline: 2.0253x; 1.1098x over previous
//
#include <hip/hip_runtime.h>
#include <stdint.h>

#define NB 64
#define NS 512
#define NC 256
#define NH 8
#define ND 32

typedef __attribute__((ext_vector_type(8))) short s8v;
typedef __attribute__((ext_vector_type(8))) unsigned short u8v;
typedef __attribute__((ext_vector_type(4))) float f4v;

#define LOG2E 1.4426950408889634f

static __device__ __forceinline__ uint16_t f2bf(float f) {
    uint32_t u = __builtin_bit_cast(uint32_t, f);
    u += 0x7fffu + ((u >> 16) & 1u);
    return (uint16_t)(u >> 16);
}
static __device__ __forceinline__ float bf2f(uint16_t h) {
    uint32_t u = ((uint32_t)h) << 16;
    return __builtin_bit_cast(float, u);
}
static __device__ __forceinline__ uint32_t cvtpk(float lo, float hi) {
    uint32_t r;
    asm("v_cvt_pk_bf16_f32 %0, %1, %2" : "=v"(r) : "v"(lo), "v"(hi));
    return r;
}

// ---------------- Kernel 0: bulk fp32 -> bf16 convert (n multiple of 2048) ----
__global__ __launch_bounds__(256) void cvt_f2bf(const float* __restrict__ in,
                                                uint16_t* __restrict__ out) {
    int i = (blockIdx.x * 256 + threadIdx.x) * 8;
    f4v a = *(const f4v*)(in + i);
    f4v b = *(const f4v*)(in + i + 4);
    uint4 w;
    w.x = cvtpk(a[0], a[1]); w.y = cvtpk(a[2], a[3]);
    w.z = cvtpk(b[0], b[1]); w.w = cvtpk(b[2], b[3]);
    *(uint4*)(out + i) = w;
}

// ---------------- Kernel 1: compact per-head rel table, PADDED ---------------
// REL2[h][dt][li*20 + lj], dt in [0,63] (63 used), li-stride 20 (bank-spread).
// Same f2bf(rel * LOG2E) rounding -> bit-identical bias values. Pad = 0.
__global__ __launch_bounds__(256) void rel_fill(const float* __restrict__ rel,
                                                uint16_t* __restrict__ rel2) {
    int id = blockIdx.x * 256 + threadIdx.x;       // 8 * 64 * 320 = 163840
    int h = id / 20480, rem = id % 20480;
    int dt = rem / 320, q = rem % 320;
    int li = q / 20, lj = q % 20;
    float v = (lj < 16 && dt < 63) ? rel[(((dt << 4) + li) * 16 + lj) * 8 + h] * LOG2E : 0.f;
    rel2[id] = f2bf(v);
}

// ---------------- Kernel 2: QKV GEMM (A = bf16 X, B = bf16 W) ----------------
// Grid dim3(256,6): bm = blockIdx.x, bn = blockIdx.y. Linear id = bm + 256*bn,
// and 256 % 8 == 0, so all 6 bn-passes over one bm land on the SAME XCD ->
// each X tile is fetched into exactly one L2 and reused 6x (96 -> 16 MB).
// writes q (scaled by SCALE*log2e, [bh][s][d]), k ([bh][s][d]), v^T ([bh][d][s])
__global__ __launch_bounds__(256) void qkv_gemm(const uint16_t* __restrict__ X,
                                                const uint16_t* __restrict__ W,
                                                const float* __restrict__ Bv,
                                                uint16_t* __restrict__ Qo,
                                                uint16_t* __restrict__ Ko,
                                                uint16_t* __restrict__ Vo) {
    __shared__ uint16_t As[128 * 40];
    __shared__ uint16_t Bs[128 * 40];
    const int tid = threadIdx.x;
    const int bn = blockIdx.y * 128;
    const int bm = blockIdx.x * 128;
    const int lane = tid & 63, wv = tid >> 6;
    const int wm = (wv >> 1) * 64, wn = (wv & 1) * 64;
    const int lq = lane & 15, g = lane >> 4;
    const int srow = tid >> 1;
    const int scol = (tid & 1) * 16;

    f4v acc[4][4] = {};

    for (int ks = 0; ks < 8; ++ks) {
        const int k0 = ks * 32;
        __syncthreads();
        {
            const uint16_t* src = X + (size_t)(bm + srow) * 256 + k0 + scol;
            u8v p0 = *(const u8v*)(src);
            u8v p1 = *(const u8v*)(src + 8);
            *(u8v*)(As + srow * 40 + scol)     = p0;
            *(u8v*)(As + srow * 40 + scol + 8) = p1;

            const uint16_t* srcb = W + (size_t)(bn + srow) * 256 + k0 + scol;
            u8v q0 = *(const u8v*)(srcb);
            u8v q1 = *(const u8v*)(srcb + 8);
            *(u8v*)(Bs + srow * 40 + scol)     = q0;
            *(u8v*)(Bs + srow * 40 + scol + 8) = q1;
        }
        __syncthreads();
        s8v af[4], bf[4];
        #pragma unroll
        for (int i = 0; i < 4; ++i) {
            af[i] = *(const s8v*)(As + (wm + i * 16 + lq) * 40 + g * 8);
            bf[i] = *(const s8v*)(Bs + (wn + i * 16 + lq) * 40 + g * 8);
        }
        #pragma unroll
        for (int mt = 0; mt < 4; ++mt)
            #pragma unroll
            for (int nt = 0; nt < 4; ++nt)
                acc[mt][nt] = __builtin_amdgcn_mfma_f32_16x16x32_bf16(af[mt], bf[nt], acc[mt][nt], 0, 0, 0);
    }

    const int gsel = bn >> 8;   // 0=q, 1=k, 2=v
    const float scl = (gsel == 0) ? (0.35355339059327373f * LOG2E) : 1.0f;
    #pragma unroll
    for (int nt = 0; nt < 4; ++nt) {
        const int ng = bn + wn + nt * 16 + lq;
        const float bv = Bv[ng];
        const int c = ng & 255, hh = c >> 5, dd = c & 31;
        #pragma unroll
        for (int mt = 0; mt < 4; ++mt) {
            #pragma unroll
            for (int r = 0; r < 4; ++r) {
                const int m = bm + wm + mt * 16 + g * 4 + r;
                const int b = m >> 9, s = m & 511;
                const uint16_t val = f2bf((acc[mt][nt][r] + bv) * scl);
                if (gsel == 0)      Qo[((size_t)(b * 8 + hh) * 512 + s) * 32 + dd] = val;
                else if (gsel == 1) Ko[((size_t)(b * 8 + hh) * 512 + s) * 32 + dd] = val;
                else                Vo[((size_t)(b * 8 + hh) * 32 + dd) * 512 + s] = val;
            }
        }
    }
}

// ---------------- Kernel 3: flash attention, 512-thread blocks (R13-green) ---
// LDS-staged K/V/Rel, 8 waves covering 128 q-rows, XCD pin, defer-rescale
// softmax, shuffle relayout + 16x16x32 PV (4x verified).
__global__ __launch_bounds__(512) void attn_kern(const uint16_t* __restrict__ Q,
                                                 const uint16_t* __restrict__ K,
                                                 const uint16_t* __restrict__ V,
                                                 const uint16_t* __restrict__ REL2,
                                                 uint16_t* __restrict__ AO) {
    __shared__ uint16_t Ks[64 * 40];               // K tile: 64 t-rows x 32 d (pad 40)
    __shared__ uint16_t Vs[32 * 80];               // V^T tile: 32 d-rows x 64 t (pad 80)
    __shared__ uint16_t Rel[64 * 320];             // padded rel slice (40 KB)

    const int p = blockIdx.x;
    const int h  = p & 7;                          // XCD-pinned head
    const int qq = (p >> 3) & 3;
    const int b  = p >> 5;
    const int tid = threadIdx.x, lane = tid & 63, wv = tid >> 6;
    const int lq = lane & 15, g = lane >> 4;
    const bool godd = (g & 1);
    const bool ghi = (g >= 2);
    const int bh = b * 8 + h;
    const int qw = qq * 128 + wv * 16;             // window-local q base of wave
    const int ti = (qw >> 4);                      // uniform per wave

    s8v qf = *(const s8v*)(Q + ((size_t)bh * 512 + qw + lq) * 32 + g * 8);
    const uint16_t* kg = K + (size_t)bh * 16384;   // K rows t, 32 d each
    const uint16_t* vg = V + (size_t)bh * 16384;   // V^T rows d, 512 t each

    // ---- stage the per-head padded rel slice once (line-dense) ----
    {
        const uint16_t* rsrc = REL2 + (size_t)h * 20480;
        #pragma unroll
        for (int it = 0; it < 5; ++it) {
            int off = it * 4096 + tid * 8;
            *(u8v*)(Rel + off) = *(const u8v*)(rsrc + off);
        }
    }

    // staging indices: lower half stages K, upper half stages V (line-dense)
    const bool isK = (tid < 256);
    const int t2 = tid & 255;
    const int ktrow = t2 >> 2, ktcol = (t2 & 3) * 8;     // 64 rows x 32 elems
    const int vtrow = t2 >> 3, vtcol = (t2 & 7) * 8;     // 32 rows x 64 elems
    const uint16_t* gsrc = isK ? (kg + (size_t)ktrow * 32 + ktcol)
                               : (vg + (size_t)vtrow * 512 + vtcol);
    uint16_t* ldst = isK ? (Ks + ktrow * 40 + ktcol)
                         : (Vs + vtrow * 80 + vtcol);
    const int gstep = isK ? (64 * 32) : 64;        // per-tile advance (elems)

    f4v o0 = {}, o1 = {};
    float mrow = -3.0e38f, lrow = 0.f;

    // prologue: load tile 0 into registers
    u8v sreg = *(const u8v*)(gsrc);

    for (int tile = 0; tile < 8; ++tile) {
        const int t0 = tile * 64;

        __syncthreads();                           // prev tile's LDS reads done
        *(u8v*)(ldst) = sreg;
        __syncthreads();                           // writes visible (incl. Rel @ tile 0)

        // issue-early: next tile's global loads hide under this tile's compute
        if (tile < 7) {
            sreg = *(const u8v*)(gsrc + (size_t)(tile + 1) * gstep);
        }

        // ---- S-tile = bias (C-init from padded LDS rel) + K.Q^T, log2 domain
        f4v a0, a1, a2, a3;
        {
            const int tj0 = t0 >> 4;               // uniform per wave
            const uint16_t* rb = Rel + lq * 20 + g * 4;
            ushort4 z0 = *(const ushort4*)(rb + (ti - tj0 - 0 + 31) * 320);
            ushort4 z1 = *(const ushort4*)(rb + (ti - tj0 - 1 + 31) * 320);
            ushort4 z2 = *(const ushort4*)(rb + (ti - tj0 - 2 + 31) * 320);
            ushort4 z3 = *(const ushort4*)(rb + (ti - tj0 - 3 + 31) * 320);
            a0[0]=bf2f(z0.x); a0[1]=bf2f(z0.y); a0[2]=bf2f(z0.z); a0[3]=bf2f(z0.w);
            a1[0]=bf2f(z1.x); a1[1]=bf2f(z1.y); a1[2]=bf2f(z1.z); a1[3]=bf2f(z1.w);
            a2[0]=bf2f(z2.x); a2[1]=bf2f(z2.y); a2[2]=bf2f(z2.z); a2[3]=bf2f(z2.w);
            a3[0]=bf2f(z3.x); a3[1]=bf2f(z3.y); a3[2]=bf2f(z3.z); a3[3]=bf2f(z3.w);
        }
        a0 = __builtin_amdgcn_mfma_f32_16x16x32_bf16(*(const s8v*)(Ks + ( 0 + lq) * 40 + g * 8), qf, a0, 0, 0, 0);
        a1 = __builtin_amdgcn_mfma_f32_16x16x32_bf16(*(const s8v*)(Ks + (16 + lq) * 40 + g * 8), qf, a1, 0, 0, 0);
        a2 = __builtin_amdgcn_mfma_f32_16x16x32_bf16(*(const s8v*)(Ks + (32 + lq) * 40 + g * 8), qf, a2, 0, 0, 0);
        a3 = __builtin_amdgcn_mfma_f32_16x16x32_bf16(*(const s8v*)(Ks + (48 + lq) * 40 + g * 8), qf, a3, 0, 0, 0);

        // ---- row max (green) ----
        float p01 = fmaxf(fmaxf(a0[0], a0[1]), fmaxf(a0[2], a0[3]));
        float p23 = fmaxf(fmaxf(a1[0], a1[1]), fmaxf(a1[2], a1[3]));
        float p45 = fmaxf(fmaxf(a2[0], a2[1]), fmaxf(a2[2], a2[3]));
        float p67 = fmaxf(fmaxf(a3[0], a3[1]), fmaxf(a3[2], a3[3]));
        float pmax = fmaxf(fmaxf(p01, p23), fmaxf(p45, p67));
        pmax = fmaxf(pmax, __shfl_xor(pmax, 16));
        pmax = fmaxf(pmax, __shfl_xor(pmax, 32));

        // ---- online-softmax update, defer-rescale threshold 8 (green) ----
        if (!__all(pmax - mrow <= 8.0f)) {
            float mnew = fmaxf(mrow, pmax);
            float scale = __builtin_amdgcn_exp2f(mrow - mnew);
            lrow *= scale;
            float s0 = __shfl(scale, g * 4 + 0);
            float s1 = __shfl(scale, g * 4 + 1);
            float s2 = __shfl(scale, g * 4 + 2);
            float s3 = __shfl(scale, g * 4 + 3);
            o0[0] *= s0; o0[1] *= s1; o0[2] *= s2; o0[3] *= s3;
            o1[0] *= s0; o1[1] *= s1; o1[2] *= s2; o1[3] *= s3;
            mrow = mnew;
        }

        // ---- P = exp2(S - m), per-lane partial row-sum (green) ----
        float lsum = 0.f;
        #pragma unroll
        for (int r = 0; r < 4; ++r) {
            a0[r] = __builtin_amdgcn_exp2f(a0[r] - mrow); lsum += a0[r];
            a1[r] = __builtin_amdgcn_exp2f(a1[r] - mrow); lsum += a1[r];
            a2[r] = __builtin_amdgcn_exp2f(a2[r] - mrow); lsum += a2[r];
            a3[r] = __builtin_amdgcn_exp2f(a3[r] - mrow); lsum += a3[r];
        }
        lrow += lsum;

        // ---- in-register re-layout P -> PV A-fragments (green verbatim) ----
        {   // tc = 0: chunks a0,a1 ; V = Vs rows lq (d 0-15) / lq+16 (d 16-31)
            uint32_t A0 = cvtpk(a0[0], a0[1]);
            uint32_t A1 = cvtpk(a0[2], a0[3]);
            uint32_t B0 = cvtpk(a1[0], a1[1]);
            uint32_t B1 = cvtpk(a1[2], a1[3]);
            uint32_t xA0 = (uint32_t)__shfl_xor((int)A0, 32);
            uint32_t xA1 = (uint32_t)__shfl_xor((int)A1, 32);
            uint32_t xB0 = (uint32_t)__shfl_xor((int)B0, 32);
            uint32_t xB1 = (uint32_t)__shfl_xor((int)B1, 32);
            uint32_t Ap0 = ghi ? xB0 : A0, Ap1 = ghi ? xB1 : A1;
            uint32_t Bp0 = ghi ? B0 : xA0, Bp1 = ghi ? B1 : xA1;
            uint32_t Z0 = godd ? Ap0 : Bp0, Z1 = godd ? Ap1 : Bp1;
            uint32_t sZ0 = (uint32_t)__shfl_xor((int)Z0, 16);
            uint32_t sZ1 = (uint32_t)__shfl_xor((int)Z1, 16);
            uint4 wq;
            wq.x = godd ? sZ0 : Ap0; wq.y = godd ? sZ1 : Ap1;
            wq.z = godd ? Bp0 : sZ0; wq.w = godd ? Bp1 : sZ1;
            s8v pf = __builtin_bit_cast(s8v, wq);
            s8v vf0 = *(const s8v*)(Vs + lq * 80 + g * 8);
            s8v vf2 = *(const s8v*)(Vs + (lq + 16) * 80 + g * 8);
            o0 = __builtin_amdgcn_mfma_f32_16x16x32_bf16(pf, vf0, o0, 0, 0, 0);
            o1 = __builtin_amdgcn_mfma_f32_16x16x32_bf16(pf, vf2, o1, 0, 0, 0);
        }
        {   // tc = 1: chunks a2,a3 ; V cols t0+32
            uint32_t A0 = cvtpk(a2[0], a2[1]);
            uint32_t A1 = cvtpk(a2[2], a2[3]);
            uint32_t B0 = cvtpk(a3[0], a3[1]);
            uint32_t B1 = cvtpk(a3[2], a3[3]);
            uint32_t xA0 = (uint32_t)__shfl_xor((int)A0, 32);
            uint32_t xA1 = (uint32_t)__shfl_xor((int)A1, 32);
            uint32_t xB0 = (uint32_t)__shfl_xor((int)B0, 32);
            uint32_t xB1 = (uint32_t)__shfl_xor((int)B1, 32);
            uint32_t Ap0 = ghi ? xB0 : A0, Ap1 = ghi ? xB1 : A1;
            uint32_t Bp0 = ghi ? B0 : xA0, Bp1 = ghi ? B1 : xA1;
            uint32_t Z0 = godd ? Ap0 : Bp0, Z1 = godd ? Ap1 : Bp1;
            uint32_t sZ0 = (uint32_t)__shfl_xor((int)Z0, 16);
            uint32_t sZ1 = (uint32_t)__shfl_xor((int)Z1, 16);
            uint4 wq;
            wq.x = godd ? sZ0 : Ap0; wq.y = godd ? sZ1 : Ap1;
            wq.z = godd ? Bp0 : sZ0; wq.w = godd ? Bp1 : sZ1;
            s8v pf = __builtin_bit_cast(s8v, wq);
            s8v vf1 = *(const s8v*)(Vs + lq * 80 + 32 + g * 8);
            s8v vf3 = *(const s8v*)(Vs + (lq + 16) * 80 + 32 + g * 8);
            o0 = __builtin_amdgcn_mfma_f32_16x16x32_bf16(pf, vf1, o0, 0, 0, 0);
            o1 = __builtin_amdgcn_mfma_f32_16x16x32_bf16(pf, vf3, o1, 0, 0, 0);
        }
    }

    // ---- finalize: row sum across g, normalize, store (green) ----
    lrow += __shfl_xor(lrow, 16);
    lrow += __shfl_xor(lrow, 32);
    const float inv = 1.0f / lrow;                 // valid for row lq
    #pragma unroll
    for (int r = 0; r < 4; ++r) {
        const float iv = __shfl(inv, g * 4 + r);   // row g*4+r's denom
        const int srow = b * 512 + qw + g * 4 + r;
        uint16_t* dst = AO + (size_t)srow * 256 + h * 32 + lq;
        dst[0]  = f2bf(o0[r] * iv);
        dst[16] = f2bf(o1[r] * iv);
    }
}

// ---------------- Kernel 4: output projection (A bf16, W bf16) ---------------
// Grid dim3(256,2): bm = blockIdx.x, bn = blockIdx.y (same-XCD A reuse).
__global__ __launch_bounds__(256) void proj_gemm(const uint16_t* __restrict__ A,
                                                 const uint16_t* __restrict__ W,
                                                 const float* __restrict__ Bv,
                                                 float* __restrict__ Out) {
    __shared__ uint16_t As[128 * 40];
    __shared__ uint16_t Bs[128 * 40];
    const int tid = threadIdx.x;
    const int bn = blockIdx.y * 128;
    const int bm = blockIdx.x * 128;
    const int lane = tid & 63, wv = tid >> 6;
    const int wm = (wv >> 1) * 64, wn = (wv & 1) * 64;
    const int lq = lane & 15, g = lane >> 4;
    const int srow = tid >> 1;
    const int scol = (tid & 1) * 16;

    f4v acc[4][4] = {};

    for (int ks = 0; ks < 8; ++ks) {
        const int k0 = ks * 32;
        __syncthreads();
        {
            const uint16_t* src = A + (size_t)(bm + srow) * 256 + k0 + scol;
            u8v p0 = *(const u8v*)(src);
            u8v p1 = *(const u8v*)(src + 8);
            *(u8v*)(As + srow * 40 + scol)     = p0;
            *(u8v*)(As + srow * 40 + scol + 8) = p1;

            const uint16_t* srcb = W + (size_t)(bn + srow) * 256 + k0 + scol;
            u8v q0 = *(const u8v*)(srcb);
            u8v q1 = *(const u8v*)(srcb + 8);
            *(u8v*)(Bs + srow * 40 + scol)     = q0;
            *(u8v*)(Bs + srow * 40 + scol + 8) = q1;
        }
        __syncthreads();
        s8v af[4], bf[4];
        #pragma unroll
        for (int i = 0; i < 4; ++i) {
            af[i] = *(const s8v*)(As + (wm + i * 16 + lq) * 40 + g * 8);
            bf[i] = *(const s8v*)(Bs + (wn + i * 16 + lq) * 40 + g * 8);
        }
        #pragma unroll
        for (int mt = 0; mt < 4; ++mt)
            #pragma unroll
            for (int nt = 0; nt < 4; ++nt)
                acc[mt][nt] = __builtin_amdgcn_mfma_f32_16x16x32_bf16(af[mt], bf[nt], acc[mt][nt], 0, 0, 0);
    }

    #pragma unroll
    for (int nt = 0; nt < 4; ++nt) {
        const int n = bn + wn + nt * 16 + lq;
        const float bv = Bv[n];
        #pragma unroll
        for (int mt = 0; mt < 4; ++mt) {
            #pragma unroll
            for (int r = 0; r < 4; ++r) {
                const int mm = bm + wm + mt * 16 + g * 4 + r;
                Out[(size_t)mm * 256 + n] = acc[mt][nt][r] + bv;
            }
        }
    }
}

extern "C" void kernel_launch(void* const* d_in, const int* in_sizes, int n_in,
                              void* d_out, int out_size, void* d_ws, size_t ws_size,
                              hipStream_t stream) {
    const float* x      = (const float*)d_in[0];
    const float* qkv_w  = (const float*)d_in[1];
    const float* qkv_b  = (const float*)d_in[2];
    const float* proj_w = (const float*)d_in[3];
    const float* proj_b = (const float*)d_in[4];
    const float* rel    = (const float*)d_in[5];
    float* out = (float*)d_out;

    uint16_t* ws = (uint16_t*)d_ws;
    const size_t QE = (size_t)NB * NH * NS * ND;          // 8,388,608 elems
    uint16_t* Qb   = ws;                                  // 16 MiB
    uint16_t* Kb   = Qb + QE;                             // 16 MiB
    uint16_t* Vb   = Kb + QE;                             // 16 MiB
    uint16_t* Rb   = Vb + QE;                             // 16 MiB: Xbf, then AO
    uint16_t* REL2 = Rb + QE;                             // 8 x 20480 bf16 (320 KiB)
    uint16_t* Wqb  = REL2 + 163840;                       // 768x256 bf16 (384 KiB)
    uint16_t* Wpb  = Wqb + 196608;                        // 256x256 bf16 (128 KiB)

    cvt_f2bf<<<4096, 256, 0, stream>>>(x, Rb);            // X -> bf16
    cvt_f2bf<<<96, 256, 0, stream>>>(qkv_w, Wqb);         // qkv_w -> bf16 (once)
    cvt_f2bf<<<32, 256, 0, stream>>>(proj_w, Wpb);        // proj_w -> bf16 (once)
    rel_fill<<<640, 256, 0, stream>>>(rel, REL2);
    qkv_gemm<<<dim3(256, 6), 256, 0, stream>>>(Rb, Wqb, qkv_b, Qb, Kb, Vb);
    attn_kern<<<2048, 512, 0, stream>>>(Qb, Kb, Vb, REL2, Rb);
    proj_gemm<<<dim3(256, 2), 256, 0, stream>>>(Rb, Wpb, proj_b, out);
}

// Round 16
// 113.385 us; speedup vs baseline: 2.1641x; 1.0686x over previous
//
#include <hip/hip_runtime.h>
#include <stdint.h>

#define NB 64
#define NS 512
#define NC 256
#define NH 8
#define ND 32

typedef __attribute__((ext_vector_type(8))) short s8v;
typedef __attribute__((ext_vector_type(8))) unsigned short u8v;
typedef __attribute__((ext_vector_type(4))) float f4v;

#define LOG2E 1.4426950408889634f

static __device__ __forceinline__ uint16_t f2bf(float f) {
    uint32_t u = __builtin_bit_cast(uint32_t, f);
    u += 0x7fffu + ((u >> 16) & 1u);
    return (uint16_t)(u >> 16);
}
static __device__ __forceinline__ float bf2f(uint16_t h) {
    uint32_t u = ((uint32_t)h) << 16;
    return __builtin_bit_cast(float, u);
}
static __device__ __forceinline__ uint32_t cvtpk(float lo, float hi) {
    uint32_t r;
    asm("v_cvt_pk_bf16_f32 %0, %1, %2" : "=v"(r) : "v"(lo), "v"(hi));
    return r;
}

// permlane pair-swaps (gfx950). Builtins return BOTH halves as distinct SSA
// values -- avoids the R9 register-aliasing bug. Mapping (ISA-verified):
//   permlane32_swap(A,B): dst=[A_lo32,B_lo32], src=[A_hi32,B_hi32]
//   permlane16_swap(A,B): dst=[A_g0,B_g0,A_g2,B_g2], src=[A_g1,B_g1,A_g3,B_g3]
#if __has_builtin(__builtin_amdgcn_permlane32_swap)
static __device__ __forceinline__ void pl32(uint32_t& a, uint32_t& b) {
    auto r = __builtin_amdgcn_permlane32_swap(a, b, false, false);
    a = r[0]; b = r[1];
}
static __device__ __forceinline__ void pl16(uint32_t& a, uint32_t& b) {
    auto r = __builtin_amdgcn_permlane16_swap(a, b, false, false);
    a = r[0]; b = r[1];
}
#else
static __device__ __forceinline__ void pl32(uint32_t& a, uint32_t& b) {
    asm volatile("v_permlane32_swap_b32 %0, %1" : "+v"(a), "+v"(b));
}
static __device__ __forceinline__ void pl16(uint32_t& a, uint32_t& b) {
    asm volatile("v_permlane16_swap_b32 %0, %1" : "+v"(a), "+v"(b));
}
#endif

// ---------------- Kernel 0: fused fp32 -> bf16 convert (x, qkv_w, proj_w) ----
// Region boundaries are 2048-elem (block) aligned: 8388608 / 8585216 / 8650752.
__global__ __launch_bounds__(256) void cvt_all(const float* __restrict__ x,
                                               const float* __restrict__ wq,
                                               const float* __restrict__ wp,
                                               uint16_t* __restrict__ xo,
                                               uint16_t* __restrict__ wqo,
                                               uint16_t* __restrict__ wpo) {
    int i = (blockIdx.x * 256 + threadIdx.x) * 8;
    const float* src; uint16_t* dst; int off;
    if (i < 8388608)      { src = x;  dst = xo;  off = i; }
    else if (i < 8585216) { src = wq; dst = wqo; off = i - 8388608; }
    else                  { src = wp; dst = wpo; off = i - 8585216; }
    f4v a = *(const f4v*)(src + off);
    f4v b = *(const f4v*)(src + off + 4);
    uint4 w;
    w.x = cvtpk(a[0], a[1]); w.y = cvtpk(a[2], a[3]);
    w.z = cvtpk(b[0], b[1]); w.w = cvtpk(b[2], b[3]);
    *(uint4*)(dst + off) = w;
}

// ---------------- Kernel 1: compact per-head rel table, PADDED ---------------
// REL2[h][dt][li*20 + lj], dt in [0,63] (63 used), li-stride 20 (bank-spread).
// Same f2bf(rel * LOG2E) rounding -> bit-identical bias values. Pad = 0.
__global__ __launch_bounds__(256) void rel_fill(const float* __restrict__ rel,
                                                uint16_t* __restrict__ rel2) {
    int id = blockIdx.x * 256 + threadIdx.x;       // 8 * 64 * 320 = 163840
    int h = id / 20480, rem = id % 20480;
    int dt = rem / 320, q = rem % 320;
    int li = q / 20, lj = q % 20;
    float v = (lj < 16 && dt < 63) ? rel[(((dt << 4) + li) * 16 + lj) * 8 + h] * LOG2E : 0.f;
    rel2[id] = f2bf(v);
}

// ---------------- Kernel 2: QKV GEMM (A = bf16 X, B = bf16 W) ----------------
// Grid dim3(256,6): bm = blockIdx.x, bn = blockIdx.y (same-XCD X reuse, R15).
__global__ __launch_bounds__(256) void qkv_gemm(const uint16_t* __restrict__ X,
                                                const uint16_t* __restrict__ W,
                                                const float* __restrict__ Bv,
                                                uint16_t* __restrict__ Qo,
                                                uint16_t* __restrict__ Ko,
                                                uint16_t* __restrict__ Vo) {
    __shared__ uint16_t As[128 * 40];
    __shared__ uint16_t Bs[128 * 40];
    const int tid = threadIdx.x;
    const int bn = blockIdx.y * 128;
    const int bm = blockIdx.x * 128;
    const int lane = tid & 63, wv = tid >> 6;
    const int wm = (wv >> 1) * 64, wn = (wv & 1) * 64;
    const int lq = lane & 15, g = lane >> 4;
    const int srow = tid >> 1;
    const int scol = (tid & 1) * 16;

    f4v acc[4][4] = {};

    for (int ks = 0; ks < 8; ++ks) {
        const int k0 = ks * 32;
        __syncthreads();
        {
            const uint16_t* src = X + (size_t)(bm + srow) * 256 + k0 + scol;
            u8v p0 = *(const u8v*)(src);
            u8v p1 = *(const u8v*)(src + 8);
            *(u8v*)(As + srow * 40 + scol)     = p0;
            *(u8v*)(As + srow * 40 + scol + 8) = p1;

            const uint16_t* srcb = W + (size_t)(bn + srow) * 256 + k0 + scol;
            u8v q0 = *(const u8v*)(srcb);
            u8v q1 = *(const u8v*)(srcb + 8);
            *(u8v*)(Bs + srow * 40 + scol)     = q0;
            *(u8v*)(Bs + srow * 40 + scol + 8) = q1;
        }
        __syncthreads();
        s8v af[4], bf[4];
        #pragma unroll
        for (int i = 0; i < 4; ++i) {
            af[i] = *(const s8v*)(As + (wm + i * 16 + lq) * 40 + g * 8);
            bf[i] = *(const s8v*)(Bs + (wn + i * 16 + lq) * 40 + g * 8);
        }
        #pragma unroll
        for (int mt = 0; mt < 4; ++mt)
            #pragma unroll
            for (int nt = 0; nt < 4; ++nt)
                acc[mt][nt] = __builtin_amdgcn_mfma_f32_16x16x32_bf16(af[mt], bf[nt], acc[mt][nt], 0, 0, 0);
    }

    const int gsel = bn >> 8;   // 0=q, 1=k, 2=v
    const float scl = (gsel == 0) ? (0.35355339059327373f * LOG2E) : 1.0f;
    #pragma unroll
    for (int nt = 0; nt < 4; ++nt) {
        const int ng = bn + wn + nt * 16 + lq;
        const float bv = Bv[ng];
        const int c = ng & 255, hh = c >> 5, dd = c & 31;
        #pragma unroll
        for (int mt = 0; mt < 4; ++mt) {
            #pragma unroll
            for (int r = 0; r < 4; ++r) {
                const int m = bm + wm + mt * 16 + g * 4 + r;
                const int b = m >> 9, s = m & 511;
                const uint16_t val = f2bf((acc[mt][nt][r] + bv) * scl);
                if (gsel == 0)      Qo[((size_t)(b * 8 + hh) * 512 + s) * 32 + dd] = val;
                else if (gsel == 1) Ko[((size_t)(b * 8 + hh) * 512 + s) * 32 + dd] = val;
                else                Vo[((size_t)(b * 8 + hh) * 32 + dd) * 512 + s] = val;
            }
        }
    }
}

// ---------------- Kernel 3: flash attention, 512-thread blocks ---------------
// R15-green structure (LDS-staged K/V/Rel, 8 waves, XCD pin, defer-rescale
// softmax). ONE change: the P->PV relayout's 12 ds_bpermute + 24 cndmask are
// replaced by 8 VALU permlane swaps (exact same lane permutation, ISA-derived;
// max-reduce keeps the verified __shfl_xor).
__global__ __launch_bounds__(512) void attn_kern(const uint16_t* __restrict__ Q,
                                                 const uint16_t* __restrict__ K,
                                                 const uint16_t* __restrict__ V,
                                                 const uint16_t* __restrict__ REL2,
                                                 uint16_t* __restrict__ AO) {
    __shared__ uint16_t Ks[64 * 40];               // K tile: 64 t-rows x 32 d (pad 40)
    __shared__ uint16_t Vs[32 * 80];               // V^T tile: 32 d-rows x 64 t (pad 80)
    __shared__ uint16_t Rel[64 * 320];             // padded rel slice (40 KB)

    const int p = blockIdx.x;
    const int h  = p & 7;                          // XCD-pinned head
    const int qq = (p >> 3) & 3;
    const int b  = p >> 5;
    const int tid = threadIdx.x, lane = tid & 63, wv = tid >> 6;
    const int lq = lane & 15, g = lane >> 4;
    const int bh = b * 8 + h;
    const int qw = qq * 128 + wv * 16;             // window-local q base of wave
    const int ti = (qw >> 4);                      // uniform per wave

    s8v qf = *(const s8v*)(Q + ((size_t)bh * 512 + qw + lq) * 32 + g * 8);
    const uint16_t* kg = K + (size_t)bh * 16384;   // K rows t, 32 d each
    const uint16_t* vg = V + (size_t)bh * 16384;   // V^T rows d, 512 t each

    // ---- stage the per-head padded rel slice once (line-dense) ----
    {
        const uint16_t* rsrc = REL2 + (size_t)h * 20480;
        #pragma unroll
        for (int it = 0; it < 5; ++it) {
            int off = it * 4096 + tid * 8;
            *(u8v*)(Rel + off) = *(const u8v*)(rsrc + off);
        }
    }

    // staging indices: lower half stages K, upper half stages V (line-dense)
    const bool isK = (tid < 256);
    const int t2 = tid & 255;
    const int ktrow = t2 >> 2, ktcol = (t2 & 3) * 8;     // 64 rows x 32 elems
    const int vtrow = t2 >> 3, vtcol = (t2 & 7) * 8;     // 32 rows x 64 elems
    const uint16_t* gsrc = isK ? (kg + (size_t)ktrow * 32 + ktcol)
                               : (vg + (size_t)vtrow * 512 + vtcol);
    uint16_t* ldst = isK ? (Ks + ktrow * 40 + ktcol)
                         : (Vs + vtrow * 80 + vtcol);
    const int gstep = isK ? (64 * 32) : 64;        // per-tile advance (elems)

    f4v o0 = {}, o1 = {};
    float mrow = -3.0e38f, lrow = 0.f;

    // prologue: load tile 0 into registers
    u8v sreg = *(const u8v*)(gsrc);

    for (int tile = 0; tile < 8; ++tile) {
        const int t0 = tile * 64;

        __syncthreads();                           // prev tile's LDS reads done
        *(u8v*)(ldst) = sreg;
        __syncthreads();                           // writes visible (incl. Rel @ tile 0)

        // issue-early: next tile's global loads hide under this tile's compute
        if (tile < 7) {
            sreg = *(const u8v*)(gsrc + (size_t)(tile + 1) * gstep);
        }

        // ---- S-tile = bias (C-init from padded LDS rel) + K.Q^T, log2 domain
        f4v a0, a1, a2, a3;
        {
            const int tj0 = t0 >> 4;               // uniform per wave
            const uint16_t* rb = Rel + lq * 20 + g * 4;
            ushort4 z0 = *(const ushort4*)(rb + (ti - tj0 - 0 + 31) * 320);
            ushort4 z1 = *(const ushort4*)(rb + (ti - tj0 - 1 + 31) * 320);
            ushort4 z2 = *(const ushort4*)(rb + (ti - tj0 - 2 + 31) * 320);
            ushort4 z3 = *(const ushort4*)(rb + (ti - tj0 - 3 + 31) * 320);
            a0[0]=bf2f(z0.x); a0[1]=bf2f(z0.y); a0[2]=bf2f(z0.z); a0[3]=bf2f(z0.w);
            a1[0]=bf2f(z1.x); a1[1]=bf2f(z1.y); a1[2]=bf2f(z1.z); a1[3]=bf2f(z1.w);
            a2[0]=bf2f(z2.x); a2[1]=bf2f(z2.y); a2[2]=bf2f(z2.z); a2[3]=bf2f(z2.w);
            a3[0]=bf2f(z3.x); a3[1]=bf2f(z3.y); a3[2]=bf2f(z3.z); a3[3]=bf2f(z3.w);
        }
        a0 = __builtin_amdgcn_mfma_f32_16x16x32_bf16(*(const s8v*)(Ks + ( 0 + lq) * 40 + g * 8), qf, a0, 0, 0, 0);
        a1 = __builtin_amdgcn_mfma_f32_16x16x32_bf16(*(const s8v*)(Ks + (16 + lq) * 40 + g * 8), qf, a1, 0, 0, 0);
        a2 = __builtin_amdgcn_mfma_f32_16x16x32_bf16(*(const s8v*)(Ks + (32 + lq) * 40 + g * 8), qf, a2, 0, 0, 0);
        a3 = __builtin_amdgcn_mfma_f32_16x16x32_bf16(*(const s8v*)(Ks + (48 + lq) * 40 + g * 8), qf, a3, 0, 0, 0);

        // ---- row max (green) ----
        float p01 = fmaxf(fmaxf(a0[0], a0[1]), fmaxf(a0[2], a0[3]));
        float p23 = fmaxf(fmaxf(a1[0], a1[1]), fmaxf(a1[2], a1[3]));
        float p45 = fmaxf(fmaxf(a2[0], a2[1]), fmaxf(a2[2], a2[3]));
        float p67 = fmaxf(fmaxf(a3[0], a3[1]), fmaxf(a3[2], a3[3]));
        float pmax = fmaxf(fmaxf(p01, p23), fmaxf(p45, p67));
        pmax = fmaxf(pmax, __shfl_xor(pmax, 16));
        pmax = fmaxf(pmax, __shfl_xor(pmax, 32));

        // ---- online-softmax update, defer-rescale threshold 8 (green) ----
        if (!__all(pmax - mrow <= 8.0f)) {
            float mnew = fmaxf(mrow, pmax);
            float scale = __builtin_amdgcn_exp2f(mrow - mnew);
            lrow *= scale;
            float s0 = __shfl(scale, g * 4 + 0);
            float s1 = __shfl(scale, g * 4 + 1);
            float s2 = __shfl(scale, g * 4 + 2);
            float s3 = __shfl(scale, g * 4 + 3);
            o0[0] *= s0; o0[1] *= s1; o0[2] *= s2; o0[3] *= s3;
            o1[0] *= s0; o1[1] *= s1; o1[2] *= s2; o1[3] *= s3;
            mrow = mnew;
        }

        // ---- P = exp2(S - m), per-lane partial row-sum (green) ----
        float lsum = 0.f;
        #pragma unroll
        for (int r = 0; r < 4; ++r) {
            a0[r] = __builtin_amdgcn_exp2f(a0[r] - mrow); lsum += a0[r];
            a1[r] = __builtin_amdgcn_exp2f(a1[r] - mrow); lsum += a1[r];
            a2[r] = __builtin_amdgcn_exp2f(a2[r] - mrow); lsum += a2[r];
            a3[r] = __builtin_amdgcn_exp2f(a3[r] - mrow); lsum += a3[r];
        }
        lrow += lsum;

        // ---- P -> PV A-fragments via permlane swaps (== green lane math) ----
        {   // tc = 0: chunks a0,a1 ; V = Vs rows lq (d 0-15) / lq+16 (d 16-31)
            uint32_t A0 = cvtpk(a0[0], a0[1]);
            uint32_t A1 = cvtpk(a0[2], a0[3]);
            uint32_t B0 = cvtpk(a1[0], a1[1]);
            uint32_t B1 = cvtpk(a1[2], a1[3]);
            pl32(A0, B0);                          // A0=[A_lo,B_lo]=Ap0, B0=Bp0
            pl16(A0, B0);                          // A0=wq.x, B0=wq.z
            pl32(A1, B1);                          // Ap1, Bp1
            pl16(A1, B1);                          // wq.y, wq.w
            uint4 wq; wq.x = A0; wq.y = A1; wq.z = B0; wq.w = B1;
            s8v pf = __builtin_bit_cast(s8v, wq);
            s8v vf0 = *(const s8v*)(Vs + lq * 80 + g * 8);
            s8v vf2 = *(const s8v*)(Vs + (lq + 16) * 80 + g * 8);
            o0 = __builtin_amdgcn_mfma_f32_16x16x32_bf16(pf, vf0, o0, 0, 0, 0);
            o1 = __builtin_amdgcn_mfma_f32_16x16x32_bf16(pf, vf2, o1, 0, 0, 0);
        }
        {   // tc = 1: chunks a2,a3 ; V cols t0+32
            uint32_t A0 = cvtpk(a2[0], a2[1]);
            uint32_t A1 = cvtpk(a2[2], a2[3]);
            uint32_t B0 = cvtpk(a3[0], a3[1]);
            uint32_t B1 = cvtpk(a3[2], a3[3]);
            pl32(A0, B0);
            pl16(A0, B0);
            pl32(A1, B1);
            pl16(A1, B1);
            uint4 wq; wq.x = A0; wq.y = A1; wq.z = B0; wq.w = B1;
            s8v pf = __builtin_bit_cast(s8v, wq);
            s8v vf1 = *(const s8v*)(Vs + lq * 80 + 32 + g * 8);
            s8v vf3 = *(const s8v*)(Vs + (lq + 16) * 80 + 32 + g * 8);
            o0 = __builtin_amdgcn_mfma_f32_16x16x32_bf16(pf, vf1, o0, 0, 0, 0);
            o1 = __builtin_amdgcn_mfma_f32_16x16x32_bf16(pf, vf3, o1, 0, 0, 0);
        }
    }

    // ---- finalize: row sum across g, normalize, store (green) ----
    lrow += __shfl_xor(lrow, 16);
    lrow += __shfl_xor(lrow, 32);
    const float inv = 1.0f / lrow;                 // valid for row lq
    #pragma unroll
    for (int r = 0; r < 4; ++r) {
        const float iv = __shfl(inv, g * 4 + r);   // row g*4+r's denom
        const int srow = b * 512 + qw + g * 4 + r;
        uint16_t* dst = AO + (size_t)srow * 256 + h * 32 + lq;
        dst[0]  = f2bf(o0[r] * iv);
        dst[16] = f2bf(o1[r] * iv);
    }
}

// ---------------- Kernel 4: output projection (A bf16, W bf16) ---------------
// Grid dim3(256,2): bm = blockIdx.x, bn = blockIdx.y (same-XCD A reuse).
__global__ __launch_bounds__(256) void proj_gemm(const uint16_t* __restrict__ A,
                                                 const uint16_t* __restrict__ W,
                                                 const float* __restrict__ Bv,
                                                 float* __restrict__ Out) {
    __shared__ uint16_t As[128 * 40];
    __shared__ uint16_t Bs[128 * 40];
    const int tid = threadIdx.x;
    const int bn = blockIdx.y * 128;
    const int bm = blockIdx.x * 128;
    const int lane = tid & 63, wv = tid >> 6;
    const int wm = (wv >> 1) * 64, wn = (wv & 1) * 64;
    const int lq = lane & 15, g = lane >> 4;
    const int srow = tid >> 1;
    const int scol = (tid & 1) * 16;

    f4v acc[4][4] = {};

    for (int ks = 0; ks < 8; ++ks) {
        const int k0 = ks * 32;
        __syncthreads();
        {
            const uint16_t* src = A + (size_t)(bm + srow) * 256 + k0 + scol;
            u8v p0 = *(const u8v*)(src);
            u8v p1 = *(const u8v*)(src + 8);
            *(u8v*)(As + srow * 40 + scol)     = p0;
            *(u8v*)(As + srow * 40 + scol + 8) = p1;

            const uint16_t* srcb = W + (size_t)(bn + srow) * 256 + k0 + scol;
            u8v q0 = *(const u8v*)(srcb);
            u8v q1 = *(const u8v*)(srcb + 8);
            *(u8v*)(Bs + srow * 40 + scol)     = q0;
            *(u8v*)(Bs + srow * 40 + scol + 8) = q1;
        }
        __syncthreads();
        s8v af[4], bf[4];
        #pragma unroll
        for (int i = 0; i < 4; ++i) {
            af[i] = *(const s8v*)(As + (wm + i * 16 + lq) * 40 + g * 8);
            bf[i] = *(const s8v*)(Bs + (wn + i * 16 + lq) * 40 + g * 8);
        }
        #pragma unroll
        for (int mt = 0; mt < 4; ++mt)
            #pragma unroll
            for (int nt = 0; nt < 4; ++nt)
                acc[mt][nt] = __builtin_amdgcn_mfma_f32_16x16x32_bf16(af[mt], bf[nt], acc[mt][nt], 0, 0, 0);
    }

    #pragma unroll
    for (int nt = 0; nt < 4; ++nt) {
        const int n = bn + wn + nt * 16 + lq;
        const float bv = Bv[n];
        #pragma unroll
        for (int mt = 0; mt < 4; ++mt) {
            #pragma unroll
            for (int r = 0; r < 4; ++r) {
                const int mm = bm + wm + mt * 16 + g * 4 + r;
                Out[(size_t)mm * 256 + n] = acc[mt][nt][r] + bv;
            }
        }
    }
}

extern "C" void kernel_launch(void* const* d_in, const int* in_sizes, int n_in,
                              void* d_out, int out_size, void* d_ws, size_t ws_size,
                              hipStream_t stream) {
    const float* x      = (const float*)d_in[0];
    const float* qkv_w  = (const float*)d_in[1];
    const float* qkv_b  = (const float*)d_in[2];
    const float* proj_w = (const float*)d_in[3];
    const float* proj_b = (const float*)d_in[4];
    const float* rel    = (const float*)d_in[5];
    float* out = (float*)d_out;

    uint16_t* ws = (uint16_t*)d_ws;
    const size_t QE = (size_t)NB * NH * NS * ND;          // 8,388,608 elems
    uint16_t* Qb   = ws;                                  // 16 MiB
    uint16_t* Kb   = Qb + QE;                             // 16 MiB
    uint16_t* Vb   = Kb + QE;                             // 16 MiB
    uint16_t* Rb   = Vb + QE;                             // 16 MiB: Xbf, then AO
    uint16_t* REL2 = Rb + QE;                             // 8 x 20480 bf16 (320 KiB)
    uint16_t* Wqb  = REL2 + 163840;                       // 768x256 bf16 (384 KiB)
    uint16_t* Wpb  = Wqb + 196608;                        // 256x256 bf16 (128 KiB)

    cvt_all<<<4224, 256, 0, stream>>>(x, qkv_w, proj_w, Rb, Wqb, Wpb);
    rel_fill<<<640, 256, 0, stream>>>(rel, REL2);
    qkv_gemm<<<dim3(256, 6), 256, 0, stream>>>(Rb, Wqb, qkv_b, Qb, Kb, Vb);
    attn_kern<<<2048, 512, 0, stream>>>(Qb, Kb, Vb, REL2, Rb);
    proj_gemm<<<dim3(256, 2), 256, 0, stream>>>(Rb, Wpb, proj_b, out);
}

// Round 17
// 109.206 us; speedup vs baseline: 2.2470x; 1.0383x over previous
//
#include <hip/hip_runtime.h>
#include <stdint.h>

#define NB 64
#define NS 512
#define NC 256
#define NH 8
#define ND 32

typedef __attribute__((ext_vector_type(8))) short s8v;
typedef __attribute__((ext_vector_type(8))) unsigned short u8v;
typedef __attribute__((ext_vector_type(4))) float f4v;

#define LOG2E 1.4426950408889634f

static __device__ __forceinline__ uint16_t f2bf(float f) {
    uint32_t u = __builtin_bit_cast(uint32_t, f);
    u += 0x7fffu + ((u >> 16) & 1u);
    return (uint16_t)(u >> 16);
}
static __device__ __forceinline__ float bf2f(uint16_t h) {
    uint32_t u = ((uint32_t)h) << 16;
    return __builtin_bit_cast(float, u);
}
static __device__ __forceinline__ uint32_t cvtpk(float lo, float hi) {
    uint32_t r;
    asm("v_cvt_pk_bf16_f32 %0, %1, %2" : "=v"(r) : "v"(lo), "v"(hi));
    return r;
}

// permlane pair-swaps (gfx950) -- R16-verified.
#if __has_builtin(__builtin_amdgcn_permlane32_swap)
static __device__ __forceinline__ void pl32(uint32_t& a, uint32_t& b) {
    auto r = __builtin_amdgcn_permlane32_swap(a, b, false, false);
    a = r[0]; b = r[1];
}
static __device__ __forceinline__ void pl16(uint32_t& a, uint32_t& b) {
    auto r = __builtin_amdgcn_permlane16_swap(a, b, false, false);
    a = r[0]; b = r[1];
}
#else
static __device__ __forceinline__ void pl32(uint32_t& a, uint32_t& b) {
    asm volatile("v_permlane32_swap_b32 %0, %1" : "+v"(a), "+v"(b));
}
static __device__ __forceinline__ void pl16(uint32_t& a, uint32_t& b) {
    asm volatile("v_permlane16_swap_b32 %0, %1" : "+v"(a), "+v"(b));
}
#endif

// ---------------- Kernel 0: fused fp32 -> bf16 convert (x, qkv_w, proj_w) ----
__global__ __launch_bounds__(256) void cvt_all(const float* __restrict__ x,
                                               const float* __restrict__ wq,
                                               const float* __restrict__ wp,
                                               uint16_t* __restrict__ xo,
                                               uint16_t* __restrict__ wqo,
                                               uint16_t* __restrict__ wpo) {
    int i = (blockIdx.x * 256 + threadIdx.x) * 8;
    const float* src; uint16_t* dst; int off;
    if (i < 8388608)      { src = x;  dst = xo;  off = i; }
    else if (i < 8585216) { src = wq; dst = wqo; off = i - 8388608; }
    else                  { src = wp; dst = wpo; off = i - 8585216; }
    f4v a = *(const f4v*)(src + off);
    f4v b = *(const f4v*)(src + off + 4);
    uint4 w;
    w.x = cvtpk(a[0], a[1]); w.y = cvtpk(a[2], a[3]);
    w.z = cvtpk(b[0], b[1]); w.w = cvtpk(b[2], b[3]);
    *(uint4*)(dst + off) = w;
}

// ---------------- Kernel 1: compact per-head rel table, PADDED ---------------
__global__ __launch_bounds__(256) void rel_fill(const float* __restrict__ rel,
                                                uint16_t* __restrict__ rel2) {
    int id = blockIdx.x * 256 + threadIdx.x;       // 8 * 64 * 320 = 163840
    int h = id / 20480, rem = id % 20480;
    int dt = rem / 320, q = rem % 320;
    int li = q / 20, lj = q % 20;
    float v = (lj < 16 && dt < 63) ? rel[(((dt << 4) + li) * 16 + lj) * 8 + h] * LOG2E : 0.f;
    rel2[id] = f2bf(v);
}

// ---------------- Kernel 2: QKV GEMM, 2-phase pipelined ----------------------
// Double-buffered LDS, issue-early global loads, ONE barrier per k-step.
// Grid dim3(256,6): bm = blockIdx.x, bn = blockIdx.y (same-XCD X reuse, R15).
__global__ __launch_bounds__(256) void qkv_gemm(const uint16_t* __restrict__ X,
                                                const uint16_t* __restrict__ W,
                                                const float* __restrict__ Bv,
                                                uint16_t* __restrict__ Qo,
                                                uint16_t* __restrict__ Ko,
                                                uint16_t* __restrict__ Vo) {
    __shared__ uint16_t As[2][128 * 40];
    __shared__ uint16_t Bs[2][128 * 40];
    const int tid = threadIdx.x;
    const int bn = blockIdx.y * 128;
    const int bm = blockIdx.x * 128;
    const int lane = tid & 63, wv = tid >> 6;
    const int wm = (wv >> 1) * 64, wn = (wv & 1) * 64;
    const int lq = lane & 15, g = lane >> 4;
    const int srow = tid >> 1;
    const int scol = (tid & 1) * 16;

    const uint16_t* xs = X + (size_t)(bm + srow) * 256 + scol;
    const uint16_t* wsrc = W + (size_t)(bn + srow) * 256 + scol;

    f4v acc[4][4] = {};
    u8v xa, xb, wa, wb;

    // prologue: stage k-step 0
    xa = *(const u8v*)(xs);     xb = *(const u8v*)(xs + 8);
    wa = *(const u8v*)(wsrc);   wb = *(const u8v*)(wsrc + 8);
    *(u8v*)(&As[0][srow * 40 + scol])     = xa;
    *(u8v*)(&As[0][srow * 40 + scol + 8]) = xb;
    *(u8v*)(&Bs[0][srow * 40 + scol])     = wa;
    *(u8v*)(&Bs[0][srow * 40 + scol + 8]) = wb;
    __syncthreads();

    for (int ks = 0; ks < 8; ++ks) {
        const int cur = ks & 1;
        // issue-early: next k-step's global loads overlap this step's compute
        if (ks < 7) {
            const int k1 = (ks + 1) * 32;
            xa = *(const u8v*)(xs + k1);   xb = *(const u8v*)(xs + k1 + 8);
            wa = *(const u8v*)(wsrc + k1); wb = *(const u8v*)(wsrc + k1 + 8);
        }
        s8v af[4], bf[4];
        #pragma unroll
        for (int i = 0; i < 4; ++i) {
            af[i] = *(const s8v*)(&As[cur][(wm + i * 16 + lq) * 40 + g * 8]);
            bf[i] = *(const s8v*)(&Bs[cur][(wn + i * 16 + lq) * 40 + g * 8]);
        }
        #pragma unroll
        for (int mt = 0; mt < 4; ++mt)
            #pragma unroll
            for (int nt = 0; nt < 4; ++nt)
                acc[mt][nt] = __builtin_amdgcn_mfma_f32_16x16x32_bf16(af[mt], bf[nt], acc[mt][nt], 0, 0, 0);
        // write landed registers into the other buffer (read next step)
        if (ks < 7) {
            *(u8v*)(&As[cur ^ 1][srow * 40 + scol])     = xa;
            *(u8v*)(&As[cur ^ 1][srow * 40 + scol + 8]) = xb;
            *(u8v*)(&Bs[cur ^ 1][srow * 40 + scol])     = wa;
            *(u8v*)(&Bs[cur ^ 1][srow * 40 + scol + 8]) = wb;
        }
        __syncthreads();
    }

    const int gsel = bn >> 8;   // 0=q, 1=k, 2=v
    const float scl = (gsel == 0) ? (0.35355339059327373f * LOG2E) : 1.0f;
    #pragma unroll
    for (int nt = 0; nt < 4; ++nt) {
        const int ng = bn + wn + nt * 16 + lq;
        const float bv = Bv[ng];
        const int c = ng & 255, hh = c >> 5, dd = c & 31;
        #pragma unroll
        for (int mt = 0; mt < 4; ++mt) {
            #pragma unroll
            for (int r = 0; r < 4; ++r) {
                const int m = bm + wm + mt * 16 + g * 4 + r;
                const int b = m >> 9, s = m & 511;
                const uint16_t val = f2bf((acc[mt][nt][r] + bv) * scl);
                if (gsel == 0)      Qo[((size_t)(b * 8 + hh) * 512 + s) * 32 + dd] = val;
                else if (gsel == 1) Ko[((size_t)(b * 8 + hh) * 512 + s) * 32 + dd] = val;
                else                Vo[((size_t)(b * 8 + hh) * 32 + dd) * 512 + s] = val;
            }
        }
    }
}

// ---------------- Kernel 3: flash attention (R16-green, permlane relayout) ---
__global__ __launch_bounds__(512) void attn_kern(const uint16_t* __restrict__ Q,
                                                 const uint16_t* __restrict__ K,
                                                 const uint16_t* __restrict__ V,
                                                 const uint16_t* __restrict__ REL2,
                                                 uint16_t* __restrict__ AO) {
    __shared__ uint16_t Ks[64 * 40];               // K tile: 64 t-rows x 32 d (pad 40)
    __shared__ uint16_t Vs[32 * 80];               // V^T tile: 32 d-rows x 64 t (pad 80)
    __shared__ uint16_t Rel[64 * 320];             // padded rel slice (40 KB)

    const int p = blockIdx.x;
    const int h  = p & 7;                          // XCD-pinned head
    const int qq = (p >> 3) & 3;
    const int b  = p >> 5;
    const int tid = threadIdx.x, lane = tid & 63, wv = tid >> 6;
    const int lq = lane & 15, g = lane >> 4;
    const int bh = b * 8 + h;
    const int qw = qq * 128 + wv * 16;             // window-local q base of wave
    const int ti = (qw >> 4);                      // uniform per wave

    s8v qf = *(const s8v*)(Q + ((size_t)bh * 512 + qw + lq) * 32 + g * 8);
    const uint16_t* kg = K + (size_t)bh * 16384;   // K rows t, 32 d each
    const uint16_t* vg = V + (size_t)bh * 16384;   // V^T rows d, 512 t each

    // ---- stage the per-head padded rel slice once (line-dense) ----
    {
        const uint16_t* rsrc = REL2 + (size_t)h * 20480;
        #pragma unroll
        for (int it = 0; it < 5; ++it) {
            int off = it * 4096 + tid * 8;
            *(u8v*)(Rel + off) = *(const u8v*)(rsrc + off);
        }
    }

    // staging indices: lower half stages K, upper half stages V (line-dense)
    const bool isK = (tid < 256);
    const int t2 = tid & 255;
    const int ktrow = t2 >> 2, ktcol = (t2 & 3) * 8;     // 64 rows x 32 elems
    const int vtrow = t2 >> 3, vtcol = (t2 & 7) * 8;     // 32 rows x 64 elems
    const uint16_t* gsrc = isK ? (kg + (size_t)ktrow * 32 + ktcol)
                               : (vg + (size_t)vtrow * 512 + vtcol);
    uint16_t* ldst = isK ? (Ks + ktrow * 40 + ktcol)
                         : (Vs + vtrow * 80 + vtcol);
    const int gstep = isK ? (64 * 32) : 64;        // per-tile advance (elems)

    f4v o0 = {}, o1 = {};
    float mrow = -3.0e38f, lrow = 0.f;

    // prologue: load tile 0 into registers
    u8v sreg = *(const u8v*)(gsrc);

    for (int tile = 0; tile < 8; ++tile) {
        const int t0 = tile * 64;

        __syncthreads();                           // prev tile's LDS reads done
        *(u8v*)(ldst) = sreg;
        __syncthreads();                           // writes visible (incl. Rel @ tile 0)

        // issue-early: next tile's global loads hide under this tile's compute
        if (tile < 7) {
            sreg = *(const u8v*)(gsrc + (size_t)(tile + 1) * gstep);
        }

        // ---- S-tile = bias (C-init from padded LDS rel) + K.Q^T, log2 domain
        f4v a0, a1, a2, a3;
        {
            const int tj0 = t0 >> 4;               // uniform per wave
            const uint16_t* rb = Rel + lq * 20 + g * 4;
            ushort4 z0 = *(const ushort4*)(rb + (ti - tj0 - 0 + 31) * 320);
            ushort4 z1 = *(const ushort4*)(rb + (ti - tj0 - 1 + 31) * 320);
            ushort4 z2 = *(const ushort4*)(rb + (ti - tj0 - 2 + 31) * 320);
            ushort4 z3 = *(const ushort4*)(rb + (ti - tj0 - 3 + 31) * 320);
            a0[0]=bf2f(z0.x); a0[1]=bf2f(z0.y); a0[2]=bf2f(z0.z); a0[3]=bf2f(z0.w);
            a1[0]=bf2f(z1.x); a1[1]=bf2f(z1.y); a1[2]=bf2f(z1.z); a1[3]=bf2f(z1.w);
            a2[0]=bf2f(z2.x); a2[1]=bf2f(z2.y); a2[2]=bf2f(z2.z); a2[3]=bf2f(z2.w);
            a3[0]=bf2f(z3.x); a3[1]=bf2f(z3.y); a3[2]=bf2f(z3.z); a3[3]=bf2f(z3.w);
        }
        a0 = __builtin_amdgcn_mfma_f32_16x16x32_bf16(*(const s8v*)(Ks + ( 0 + lq) * 40 + g * 8), qf, a0, 0, 0, 0);
        a1 = __builtin_amdgcn_mfma_f32_16x16x32_bf16(*(const s8v*)(Ks + (16 + lq) * 40 + g * 8), qf, a1, 0, 0, 0);
        a2 = __builtin_amdgcn_mfma_f32_16x16x32_bf16(*(const s8v*)(Ks + (32 + lq) * 40 + g * 8), qf, a2, 0, 0, 0);
        a3 = __builtin_amdgcn_mfma_f32_16x16x32_bf16(*(const s8v*)(Ks + (48 + lq) * 40 + g * 8), qf, a3, 0, 0, 0);

        // ---- row max (green) ----
        float p01 = fmaxf(fmaxf(a0[0], a0[1]), fmaxf(a0[2], a0[3]));
        float p23 = fmaxf(fmaxf(a1[0], a1[1]), fmaxf(a1[2], a1[3]));
        float p45 = fmaxf(fmaxf(a2[0], a2[1]), fmaxf(a2[2], a2[3]));
        float p67 = fmaxf(fmaxf(a3[0], a3[1]), fmaxf(a3[2], a3[3]));
        float pmax = fmaxf(fmaxf(p01, p23), fmaxf(p45, p67));
        pmax = fmaxf(pmax, __shfl_xor(pmax, 16));
        pmax = fmaxf(pmax, __shfl_xor(pmax, 32));

        // ---- online-softmax update, defer-rescale threshold 8 (green) ----
        if (!__all(pmax - mrow <= 8.0f)) {
            float mnew = fmaxf(mrow, pmax);
            float scale = __builtin_amdgcn_exp2f(mrow - mnew);
            lrow *= scale;
            float s0 = __shfl(scale, g * 4 + 0);
            float s1 = __shfl(scale, g * 4 + 1);
            float s2 = __shfl(scale, g * 4 + 2);
            float s3 = __shfl(scale, g * 4 + 3);
            o0[0] *= s0; o0[1] *= s1; o0[2] *= s2; o0[3] *= s3;
            o1[0] *= s0; o1[1] *= s1; o1[2] *= s2; o1[3] *= s3;
            mrow = mnew;
        }

        // ---- P = exp2(S - m), per-lane partial row-sum (green) ----
        float lsum = 0.f;
        #pragma unroll
        for (int r = 0; r < 4; ++r) {
            a0[r] = __builtin_amdgcn_exp2f(a0[r] - mrow); lsum += a0[r];
            a1[r] = __builtin_amdgcn_exp2f(a1[r] - mrow); lsum += a1[r];
            a2[r] = __builtin_amdgcn_exp2f(a2[r] - mrow); lsum += a2[r];
            a3[r] = __builtin_amdgcn_exp2f(a3[r] - mrow); lsum += a3[r];
        }
        lrow += lsum;

        // ---- P -> PV A-fragments via permlane swaps (R16-verified) ----
        {   // tc = 0: chunks a0,a1
            uint32_t A0 = cvtpk(a0[0], a0[1]);
            uint32_t A1 = cvtpk(a0[2], a0[3]);
            uint32_t B0 = cvtpk(a1[0], a1[1]);
            uint32_t B1 = cvtpk(a1[2], a1[3]);
            pl32(A0, B0); pl16(A0, B0);
            pl32(A1, B1); pl16(A1, B1);
            uint4 wq; wq.x = A0; wq.y = A1; wq.z = B0; wq.w = B1;
            s8v pf = __builtin_bit_cast(s8v, wq);
            s8v vf0 = *(const s8v*)(Vs + lq * 80 + g * 8);
            s8v vf2 = *(const s8v*)(Vs + (lq + 16) * 80 + g * 8);
            o0 = __builtin_amdgcn_mfma_f32_16x16x32_bf16(pf, vf0, o0, 0, 0, 0);
            o1 = __builtin_amdgcn_mfma_f32_16x16x32_bf16(pf, vf2, o1, 0, 0, 0);
        }
        {   // tc = 1: chunks a2,a3
            uint32_t A0 = cvtpk(a2[0], a2[1]);
            uint32_t A1 = cvtpk(a2[2], a2[3]);
            uint32_t B0 = cvtpk(a3[0], a3[1]);
            uint32_t B1 = cvtpk(a3[2], a3[3]);
            pl32(A0, B0); pl16(A0, B0);
            pl32(A1, B1); pl16(A1, B1);
            uint4 wq; wq.x = A0; wq.y = A1; wq.z = B0; wq.w = B1;
            s8v pf = __builtin_bit_cast(s8v, wq);
            s8v vf1 = *(const s8v*)(Vs + lq * 80 + 32 + g * 8);
            s8v vf3 = *(const s8v*)(Vs + (lq + 16) * 80 + 32 + g * 8);
            o0 = __builtin_amdgcn_mfma_f32_16x16x32_bf16(pf, vf1, o0, 0, 0, 0);
            o1 = __builtin_amdgcn_mfma_f32_16x16x32_bf16(pf, vf3, o1, 0, 0, 0);
        }
    }

    // ---- finalize: row sum across g, normalize, store (green) ----
    lrow += __shfl_xor(lrow, 16);
    lrow += __shfl_xor(lrow, 32);
    const float inv = 1.0f / lrow;                 // valid for row lq
    #pragma unroll
    for (int r = 0; r < 4; ++r) {
        const float iv = __shfl(inv, g * 4 + r);   // row g*4+r's denom
        const int srow = b * 512 + qw + g * 4 + r;
        uint16_t* dst = AO + (size_t)srow * 256 + h * 32 + lq;
        dst[0]  = f2bf(o0[r] * iv);
        dst[16] = f2bf(o1[r] * iv);
    }
}

// ---------------- Kernel 4: output projection, 2-phase pipelined -------------
// Grid dim3(256,2): bm = blockIdx.x, bn = blockIdx.y (same-XCD A reuse).
__global__ __launch_bounds__(256) void proj_gemm(const uint16_t* __restrict__ A,
                                                 const uint16_t* __restrict__ W,
                                                 const float* __restrict__ Bv,
                                                 float* __restrict__ Out) {
    __shared__ uint16_t As[2][128 * 40];
    __shared__ uint16_t Bs[2][128 * 40];
    const int tid = threadIdx.x;
    const int bn = blockIdx.y * 128;
    const int bm = blockIdx.x * 128;
    const int lane = tid & 63, wv = tid >> 6;
    const int wm = (wv >> 1) * 64, wn = (wv & 1) * 64;
    const int lq = lane & 15, g = lane >> 4;
    const int srow = tid >> 1;
    const int scol = (tid & 1) * 16;

    const uint16_t* as = A + (size_t)(bm + srow) * 256 + scol;
    const uint16_t* wsrc = W + (size_t)(bn + srow) * 256 + scol;

    f4v acc[4][4] = {};
    u8v xa, xb, wa, wb;

    xa = *(const u8v*)(as);     xb = *(const u8v*)(as + 8);
    wa = *(const u8v*)(wsrc);   wb = *(const u8v*)(wsrc + 8);
    *(u8v*)(&As[0][srow * 40 + scol])     = xa;
    *(u8v*)(&As[0][srow * 40 + scol + 8]) = xb;
    *(u8v*)(&Bs[0][srow * 40 + scol])     = wa;
    *(u8v*)(&Bs[0][srow * 40 + scol + 8]) = wb;
    __syncthreads();

    for (int ks = 0; ks < 8; ++ks) {
        const int cur = ks & 1;
        if (ks < 7) {
            const int k1 = (ks + 1) * 32;
            xa = *(const u8v*)(as + k1);   xb = *(const u8v*)(as + k1 + 8);
            wa = *(const u8v*)(wsrc + k1); wb = *(const u8v*)(wsrc + k1 + 8);
        }
        s8v af[4], bf[4];
        #pragma unroll
        for (int i = 0; i < 4; ++i) {
            af[i] = *(const s8v*)(&As[cur][(wm + i * 16 + lq) * 40 + g * 8]);
            bf[i] = *(const s8v*)(&Bs[cur][(wn + i * 16 + lq) * 40 + g * 8]);
        }
        #pragma unroll
        for (int mt = 0; mt < 4; ++mt)
            #pragma unroll
            for (int nt = 0; nt < 4; ++nt)
                acc[mt][nt] = __builtin_amdgcn_mfma_f32_16x16x32_bf16(af[mt], bf[nt], acc[mt][nt], 0, 0, 0);
        if (ks < 7) {
            *(u8v*)(&As[cur ^ 1][srow * 40 + scol])     = xa;
            *(u8v*)(&As[cur ^ 1][srow * 40 + scol + 8]) = xb;
            *(u8v*)(&Bs[cur ^ 1][srow * 40 + scol])     = wa;
            *(u8v*)(&Bs[cur ^ 1][srow * 40 + scol + 8]) = wb;
        }
        __syncthreads();
    }

    #pragma unroll
    for (int nt = 0; nt < 4; ++nt) {
        const int n = bn + wn + nt * 16 + lq;
        const float bv = Bv[n];
        #pragma unroll
        for (int mt = 0; mt < 4; ++mt) {
            #pragma unroll
            for (int r = 0; r < 4; ++r) {
                const int mm = bm + wm + mt * 16 + g * 4 + r;
                Out[(size_t)mm * 256 + n] = acc[mt][nt][r] + bv;
            }
        }
    }
}

extern "C" void kernel_launch(void* const* d_in, const int* in_sizes, int n_in,
                              void* d_out, int out_size, void* d_ws, size_t ws_size,
                              hipStream_t stream) {
    const float* x      = (const float*)d_in[0];
    const float* qkv_w  = (const float*)d_in[1];
    const float* qkv_b  = (const float*)d_in[2];
    const float* proj_w = (const float*)d_in[3];
    const float* proj_b = (const float*)d_in[4];
    const float* rel    = (const float*)d_in[5];
    float* out = (float*)d_out;

    uint16_t* ws = (uint16_t*)d_ws;
    const size_t QE = (size_t)NB * NH * NS * ND;          // 8,388,608 elems
    uint16_t* Qb   = ws;                                  // 16 MiB
    uint16_t* Kb   = Qb + QE;                             // 16 MiB
    uint16_t* Vb   = Kb + QE;                             // 16 MiB
    uint16_t* Rb   = Vb + QE;                             // 16 MiB: Xbf, then AO
    uint16_t* REL2 = Rb + QE;                             // 8 x 20480 bf16 (320 KiB)
    uint16_t* Wqb  = REL2 + 163840;                       // 768x256 bf16 (384 KiB)
    uint16_t* Wpb  = Wqb + 196608;                        // 256x256 bf16 (128 KiB)

    cvt_all<<<4224, 256, 0, stream>>>(x, qkv_w, proj_w, Rb, Wqb, Wpb);
    rel_fill<<<640, 256, 0, stream>>>(rel, REL2);
    qkv_gemm<<<dim3(256, 6), 256, 0, stream>>>(Rb, Wqb, qkv_b, Qb, Kb, Vb);
    attn_kern<<<2048, 512, 0, stream>>>(Qb, Kb, Vb, REL2, Rb);
    proj_gemm<<<dim3(256, 2), 256, 0, stream>>>(Rb, Wpb, proj_b, out);
}

// Round 18
// 103.856 us; speedup vs baseline: 2.3627x; 1.0515x over previous
//
#include <hip/hip_runtime.h>
#include <stdint.h>

#define NB 64
#define NS 512
#define NC 256
#define NH 8
#define ND 32

typedef __attribute__((ext_vector_type(8))) short s8v;
typedef __attribute__((ext_vector_type(8))) unsigned short u8v;
typedef __attribute__((ext_vector_type(4))) float f4v;

#define LOG2E 1.4426950408889634f

static __device__ __forceinline__ uint16_t f2bf(float f) {
    uint32_t u = __builtin_bit_cast(uint32_t, f);
    u += 0x7fffu + ((u >> 16) & 1u);
    return (uint16_t)(u >> 16);
}
static __device__ __forceinline__ float bf2f(uint16_t h) {
    uint32_t u = ((uint32_t)h) << 16;
    return __builtin_bit_cast(float, u);
}
static __device__ __forceinline__ uint32_t cvtpk(float lo, float hi) {
    uint32_t r;
    asm("v_cvt_pk_bf16_f32 %0, %1, %2" : "=v"(r) : "v"(lo), "v"(hi));
    return r;
}

// permlane pair-swaps (gfx950) -- R16-verified.
#if __has_builtin(__builtin_amdgcn_permlane32_swap)
static __device__ __forceinline__ void pl32(uint32_t& a, uint32_t& b) {
    auto r = __builtin_amdgcn_permlane32_swap(a, b, false, false);
    a = r[0]; b = r[1];
}
static __device__ __forceinline__ void pl16(uint32_t& a, uint32_t& b) {
    auto r = __builtin_amdgcn_permlane16_swap(a, b, false, false);
    a = r[0]; b = r[1];
}
#else
static __device__ __forceinline__ void pl32(uint32_t& a, uint32_t& b) {
    asm volatile("v_permlane32_swap_b32 %0, %1" : "+v"(a), "+v"(b));
}
static __device__ __forceinline__ void pl16(uint32_t& a, uint32_t& b) {
    asm volatile("v_permlane16_swap_b32 %0, %1" : "+v"(a), "+v"(b));
}
#endif

// ---------------- Kernel 0: weights fp32 -> bf16 (qkv_w 196608 + proj_w 65536)
__global__ __launch_bounds__(256) void cvt_w(const float* __restrict__ wq,
                                             const float* __restrict__ wp,
                                             uint16_t* __restrict__ wqo,
                                             uint16_t* __restrict__ wpo) {
    int i = (blockIdx.x * 256 + threadIdx.x) * 8;
    const float* src; uint16_t* dst; int off;
    if (i < 196608) { src = wq; dst = wqo; off = i; }
    else            { src = wp; dst = wpo; off = i - 196608; }
    f4v a = *(const f4v*)(src + off);
    f4v b = *(const f4v*)(src + off + 4);
    uint4 w;
    w.x = cvtpk(a[0], a[1]); w.y = cvtpk(a[2], a[3]);
    w.z = cvtpk(b[0], b[1]); w.w = cvtpk(b[2], b[3]);
    *(uint4*)(dst + off) = w;
}

// ---------------- Kernel 1: compact per-head rel table, PADDED ---------------
__global__ __launch_bounds__(256) void rel_fill(const float* __restrict__ rel,
                                                uint16_t* __restrict__ rel2) {
    int id = blockIdx.x * 256 + threadIdx.x;       // 8 * 64 * 320 = 163840
    int h = id / 20480, rem = id % 20480;
    int dt = rem / 320, q = rem % 320;
    int li = q / 20, lj = q % 20;
    float v = (lj < 16 && dt < 63) ? rel[(((dt << 4) + li) * 16 + lj) * 8 + h] * LOG2E : 0.f;
    rel2[id] = f2bf(v);
}

// ---------------- Kernel 2: QKV GEMM (A = fp32 X cvt-on-stage, B = bf16 W) ---
// 2-phase pipelined (R17). V blocks store via permlane transform: lane holds
// 8 consecutive s for its column dd -> one uint4 (16B) line-dense store.
// Grid dim3(256,6): bm = blockIdx.x, bn = blockIdx.y (same-XCD X reuse, R15).
__global__ __launch_bounds__(256) void qkv_gemm(const float* __restrict__ X,
                                                const uint16_t* __restrict__ W,
                                                const float* __restrict__ Bv,
                                                uint16_t* __restrict__ Qo,
                                                uint16_t* __restrict__ Ko,
                                                uint16_t* __restrict__ Vo) {
    __shared__ uint16_t As[2][128 * 40];
    __shared__ uint16_t Bs[2][128 * 40];
    const int tid = threadIdx.x;
    const int bn = blockIdx.y * 128;
    const int bm = blockIdx.x * 128;
    const int lane = tid & 63, wv = tid >> 6;
    const int wm = (wv >> 1) * 64, wn = (wv & 1) * 64;
    const int lq = lane & 15, g = lane >> 4;
    const int srow = tid >> 1;
    const int scol = (tid & 1) * 16;

    const float* xs = X + (size_t)(bm + srow) * 256 + scol;
    const uint16_t* wsrc = W + (size_t)(bn + srow) * 256 + scol;

    f4v acc[4][4] = {};
    f4v x0, x1, x2, x3;
    u8v wa, wb;

    // prologue: stage k-step 0 (convert X on the fly)
    x0 = *(const f4v*)(xs);      x1 = *(const f4v*)(xs + 4);
    x2 = *(const f4v*)(xs + 8);  x3 = *(const f4v*)(xs + 12);
    wa = *(const u8v*)(wsrc);    wb = *(const u8v*)(wsrc + 8);
    {
        uint4 q0, q1;
        q0.x = cvtpk(x0[0], x0[1]); q0.y = cvtpk(x0[2], x0[3]);
        q0.z = cvtpk(x1[0], x1[1]); q0.w = cvtpk(x1[2], x1[3]);
        q1.x = cvtpk(x2[0], x2[1]); q1.y = cvtpk(x2[2], x2[3]);
        q1.z = cvtpk(x3[0], x3[1]); q1.w = cvtpk(x3[2], x3[3]);
        *(uint4*)(&As[0][srow * 40 + scol])     = q0;
        *(uint4*)(&As[0][srow * 40 + scol + 8]) = q1;
    }
    *(u8v*)(&Bs[0][srow * 40 + scol])     = wa;
    *(u8v*)(&Bs[0][srow * 40 + scol + 8]) = wb;
    __syncthreads();

    for (int ks = 0; ks < 8; ++ks) {
        const int cur = ks & 1;
        // issue-early: next k-step's global loads overlap this step's compute
        if (ks < 7) {
            const int k1 = (ks + 1) * 32;
            x0 = *(const f4v*)(xs + k1);      x1 = *(const f4v*)(xs + k1 + 4);
            x2 = *(const f4v*)(xs + k1 + 8);  x3 = *(const f4v*)(xs + k1 + 12);
            wa = *(const u8v*)(wsrc + k1);    wb = *(const u8v*)(wsrc + k1 + 8);
        }
        s8v af[4], bf[4];
        #pragma unroll
        for (int i = 0; i < 4; ++i) {
            af[i] = *(const s8v*)(&As[cur][(wm + i * 16 + lq) * 40 + g * 8]);
            bf[i] = *(const s8v*)(&Bs[cur][(wn + i * 16 + lq) * 40 + g * 8]);
        }
        #pragma unroll
        for (int mt = 0; mt < 4; ++mt)
            #pragma unroll
            for (int nt = 0; nt < 4; ++nt)
                acc[mt][nt] = __builtin_amdgcn_mfma_f32_16x16x32_bf16(af[mt], bf[nt], acc[mt][nt], 0, 0, 0);
        // write landed registers into the other buffer (read next step)
        if (ks < 7) {
            uint4 q0, q1;
            q0.x = cvtpk(x0[0], x0[1]); q0.y = cvtpk(x0[2], x0[3]);
            q0.z = cvtpk(x1[0], x1[1]); q0.w = cvtpk(x1[2], x1[3]);
            q1.x = cvtpk(x2[0], x2[1]); q1.y = cvtpk(x2[2], x2[3]);
            q1.z = cvtpk(x3[0], x3[1]); q1.w = cvtpk(x3[2], x3[3]);
            *(uint4*)(&As[cur ^ 1][srow * 40 + scol])     = q0;
            *(uint4*)(&As[cur ^ 1][srow * 40 + scol + 8]) = q1;
            *(u8v*)(&Bs[cur ^ 1][srow * 40 + scol])     = wa;
            *(u8v*)(&Bs[cur ^ 1][srow * 40 + scol + 8]) = wb;
        }
        __syncthreads();
    }

    const int gsel = bn >> 8;   // 0=q, 1=k, 2=v
    if (gsel == 2) {
        // ---- V: transform C-frag pairs -> 8 consecutive s per lane, 16B store
        #pragma unroll
        for (int nt = 0; nt < 4; ++nt) {
            const int ng = bn + wn + nt * 16 + lq;
            const float bv = Bv[ng];
            const int c = ng & 255, hh = c >> 5, dd = c & 31;
            #pragma unroll
            for (int mtp = 0; mtp < 2; ++mtp) {
                f4v u = acc[mtp * 2][nt], v = acc[mtp * 2 + 1][nt];
                uint32_t A0 = cvtpk(u[0] + bv, u[1] + bv);
                uint32_t A1 = cvtpk(u[2] + bv, u[3] + bv);
                uint32_t B0 = cvtpk(v[0] + bv, v[1] + bv);
                uint32_t B1 = cvtpk(v[2] + bv, v[3] + bv);
                pl32(A0, B0); pl16(A0, B0);
                pl32(A1, B1); pl16(A1, B1);
                uint4 wq; wq.x = A0; wq.y = A1; wq.z = B0; wq.w = B1;
                const int m0 = bm + wm + mtp * 32;
                const int b = m0 >> 9;
                const int s0 = (m0 & 511) + g * 8;
                *(uint4*)(Vo + ((size_t)(b * 8 + hh) * 32 + dd) * 512 + s0) = wq;
            }
        }
    } else {
        const float scl = (gsel == 0) ? (0.35355339059327373f * LOG2E) : 1.0f;
        #pragma unroll
        for (int nt = 0; nt < 4; ++nt) {
            const int ng = bn + wn + nt * 16 + lq;
            const float bv = Bv[ng];
            const int c = ng & 255, hh = c >> 5, dd = c & 31;
            #pragma unroll
            for (int mt = 0; mt < 4; ++mt) {
                #pragma unroll
                for (int r = 0; r < 4; ++r) {
                    const int m = bm + wm + mt * 16 + g * 4 + r;
                    const int b = m >> 9, s = m & 511;
                    const uint16_t val = f2bf((acc[mt][nt][r] + bv) * scl);
                    if (gsel == 0) Qo[((size_t)(b * 8 + hh) * 512 + s) * 32 + dd] = val;
                    else           Ko[((size_t)(b * 8 + hh) * 512 + s) * 32 + dd] = val;
                }
            }
        }
    }
}

// ---------------- Kernel 3: flash attention (R16-green, permlane relayout) ---
__global__ __launch_bounds__(512) void attn_kern(const uint16_t* __restrict__ Q,
                                                 const uint16_t* __restrict__ K,
                                                 const uint16_t* __restrict__ V,
                                                 const uint16_t* __restrict__ REL2,
                                                 uint16_t* __restrict__ AO) {
    __shared__ uint16_t Ks[64 * 40];               // K tile: 64 t-rows x 32 d (pad 40)
    __shared__ uint16_t Vs[32 * 80];               // V^T tile: 32 d-rows x 64 t (pad 80)
    __shared__ uint16_t Rel[64 * 320];             // padded rel slice (40 KB)

    const int p = blockIdx.x;
    const int h  = p & 7;                          // XCD-pinned head
    const int qq = (p >> 3) & 3;
    const int b  = p >> 5;
    const int tid = threadIdx.x, lane = tid & 63, wv = tid >> 6;
    const int lq = lane & 15, g = lane >> 4;
    const int bh = b * 8 + h;
    const int qw = qq * 128 + wv * 16;             // window-local q base of wave
    const int ti = (qw >> 4);                      // uniform per wave

    s8v qf = *(const s8v*)(Q + ((size_t)bh * 512 + qw + lq) * 32 + g * 8);
    const uint16_t* kg = K + (size_t)bh * 16384;   // K rows t, 32 d each
    const uint16_t* vg = V + (size_t)bh * 16384;   // V^T rows d, 512 t each

    // ---- stage the per-head padded rel slice once (line-dense) ----
    {
        const uint16_t* rsrc = REL2 + (size_t)h * 20480;
        #pragma unroll
        for (int it = 0; it < 5; ++it) {
            int off = it * 4096 + tid * 8;
            *(u8v*)(Rel + off) = *(const u8v*)(rsrc + off);
        }
    }

    // staging indices: lower half stages K, upper half stages V (line-dense)
    const bool isK = (tid < 256);
    const int t2 = tid & 255;
    const int ktrow = t2 >> 2, ktcol = (t2 & 3) * 8;     // 64 rows x 32 elems
    const int vtrow = t2 >> 3, vtcol = (t2 & 7) * 8;     // 32 rows x 64 elems
    const uint16_t* gsrc = isK ? (kg + (size_t)ktrow * 32 + ktcol)
                               : (vg + (size_t)vtrow * 512 + vtcol);
    uint16_t* ldst = isK ? (Ks + ktrow * 40 + ktcol)
                         : (Vs + vtrow * 80 + vtcol);
    const int gstep = isK ? (64 * 32) : 64;        // per-tile advance (elems)

    f4v o0 = {}, o1 = {};
    float mrow = -3.0e38f, lrow = 0.f;

    // prologue: load tile 0 into registers
    u8v sreg = *(const u8v*)(gsrc);

    for (int tile = 0; tile < 8; ++tile) {
        const int t0 = tile * 64;

        __syncthreads();                           // prev tile's LDS reads done
        *(u8v*)(ldst) = sreg;
        __syncthreads();                           // writes visible (incl. Rel @ tile 0)

        // issue-early: next tile's global loads hide under this tile's compute
        if (tile < 7) {
            sreg = *(const u8v*)(gsrc + (size_t)(tile + 1) * gstep);
        }

        // ---- S-tile = bias (C-init from padded LDS rel) + K.Q^T, log2 domain
        f4v a0, a1, a2, a3;
        {
            const int tj0 = t0 >> 4;               // uniform per wave
            const uint16_t* rb = Rel + lq * 20 + g * 4;
            ushort4 z0 = *(const ushort4*)(rb + (ti - tj0 - 0 + 31) * 320);
            ushort4 z1 = *(const ushort4*)(rb + (ti - tj0 - 1 + 31) * 320);
            ushort4 z2 = *(const ushort4*)(rb + (ti - tj0 - 2 + 31) * 320);
            ushort4 z3 = *(const ushort4*)(rb + (ti - tj0 - 3 + 31) * 320);
            a0[0]=bf2f(z0.x); a0[1]=bf2f(z0.y); a0[2]=bf2f(z0.z); a0[3]=bf2f(z0.w);
            a1[0]=bf2f(z1.x); a1[1]=bf2f(z1.y); a1[2]=bf2f(z1.z); a1[3]=bf2f(z1.w);
            a2[0]=bf2f(z2.x); a2[1]=bf2f(z2.y); a2[2]=bf2f(z2.z); a2[3]=bf2f(z2.w);
            a3[0]=bf2f(z3.x); a3[1]=bf2f(z3.y); a3[2]=bf2f(z3.z); a3[3]=bf2f(z3.w);
        }
        a0 = __builtin_amdgcn_mfma_f32_16x16x32_bf16(*(const s8v*)(Ks + ( 0 + lq) * 40 + g * 8), qf, a0, 0, 0, 0);
        a1 = __builtin_amdgcn_mfma_f32_16x16x32_bf16(*(const s8v*)(Ks + (16 + lq) * 40 + g * 8), qf, a1, 0, 0, 0);
        a2 = __builtin_amdgcn_mfma_f32_16x16x32_bf16(*(const s8v*)(Ks + (32 + lq) * 40 + g * 8), qf, a2, 0, 0, 0);
        a3 = __builtin_amdgcn_mfma_f32_16x16x32_bf16(*(const s8v*)(Ks + (48 + lq) * 40 + g * 8), qf, a3, 0, 0, 0);

        // ---- row max (green) ----
        float p01 = fmaxf(fmaxf(a0[0], a0[1]), fmaxf(a0[2], a0[3]));
        float p23 = fmaxf(fmaxf(a1[0], a1[1]), fmaxf(a1[2], a1[3]));
        float p45 = fmaxf(fmaxf(a2[0], a2[1]), fmaxf(a2[2], a2[3]));
        float p67 = fmaxf(fmaxf(a3[0], a3[1]), fmaxf(a3[2], a3[3]));
        float pmax = fmaxf(fmaxf(p01, p23), fmaxf(p45, p67));
        pmax = fmaxf(pmax, __shfl_xor(pmax, 16));
        pmax = fmaxf(pmax, __shfl_xor(pmax, 32));

        // ---- online-softmax update, defer-rescale threshold 8 (green) ----
        if (!__all(pmax - mrow <= 8.0f)) {
            float mnew = fmaxf(mrow, pmax);
            float scale = __builtin_amdgcn_exp2f(mrow - mnew);
            lrow *= scale;
            float s0 = __shfl(scale, g * 4 + 0);
            float s1 = __shfl(scale, g * 4 + 1);
            float s2 = __shfl(scale, g * 4 + 2);
            float s3 = __shfl(scale, g * 4 + 3);
            o0[0] *= s0; o0[1] *= s1; o0[2] *= s2; o0[3] *= s3;
            o1[0] *= s0; o1[1] *= s1; o1[2] *= s2; o1[3] *= s3;
            mrow = mnew;
        }

        // ---- P = exp2(S - m), per-lane partial row-sum (green) ----
        float lsum = 0.f;
        #pragma unroll
        for (int r = 0; r < 4; ++r) {
            a0[r] = __builtin_amdgcn_exp2f(a0[r] - mrow); lsum += a0[r];
            a1[r] = __builtin_amdgcn_exp2f(a1[r] - mrow); lsum += a1[r];
            a2[r] = __builtin_amdgcn_exp2f(a2[r] - mrow); lsum += a2[r];
            a3[r] = __builtin_amdgcn_exp2f(a3[r] - mrow); lsum += a3[r];
        }
        lrow += lsum;

        // ---- P -> PV A-fragments via permlane swaps (R16-verified) ----
        {   // tc = 0: chunks a0,a1
            uint32_t A0 = cvtpk(a0[0], a0[1]);
            uint32_t A1 = cvtpk(a0[2], a0[3]);
            uint32_t B0 = cvtpk(a1[0], a1[1]);
            uint32_t B1 = cvtpk(a1[2], a1[3]);
            pl32(A0, B0); pl16(A0, B0);
            pl32(A1, B1); pl16(A1, B1);
            uint4 wq; wq.x = A0; wq.y = A1; wq.z = B0; wq.w = B1;
            s8v pf = __builtin_bit_cast(s8v, wq);
            s8v vf0 = *(const s8v*)(Vs + lq * 80 + g * 8);
            s8v vf2 = *(const s8v*)(Vs + (lq + 16) * 80 + g * 8);
            o0 = __builtin_amdgcn_mfma_f32_16x16x32_bf16(pf, vf0, o0, 0, 0, 0);
            o1 = __builtin_amdgcn_mfma_f32_16x16x32_bf16(pf, vf2, o1, 0, 0, 0);
        }
        {   // tc = 1: chunks a2,a3
            uint32_t A0 = cvtpk(a2[0], a2[1]);
            uint32_t A1 = cvtpk(a2[2], a2[3]);
            uint32_t B0 = cvtpk(a3[0], a3[1]);
            uint32_t B1 = cvtpk(a3[2], a3[3]);
            pl32(A0, B0); pl16(A0, B0);
            pl32(A1, B1); pl16(A1, B1);
            uint4 wq; wq.x = A0; wq.y = A1; wq.z = B0; wq.w = B1;
            s8v pf = __builtin_bit_cast(s8v, wq);
            s8v vf1 = *(const s8v*)(Vs + lq * 80 + 32 + g * 8);
            s8v vf3 = *(const s8v*)(Vs + (lq + 16) * 80 + 32 + g * 8);
            o0 = __builtin_amdgcn_mfma_f32_16x16x32_bf16(pf, vf1, o0, 0, 0, 0);
            o1 = __builtin_amdgcn_mfma_f32_16x16x32_bf16(pf, vf3, o1, 0, 0, 0);
        }
    }

    // ---- finalize: row sum across g, normalize, store (green) ----
    lrow += __shfl_xor(lrow, 16);
    lrow += __shfl_xor(lrow, 32);
    const float inv = 1.0f / lrow;                 // valid for row lq
    #pragma unroll
    for (int r = 0; r < 4; ++r) {
        const float iv = __shfl(inv, g * 4 + r);   // row g*4+r's denom
        const int srow = b * 512 + qw + g * 4 + r;
        uint16_t* dst = AO + (size_t)srow * 256 + h * 32 + lq;
        dst[0]  = f2bf(o0[r] * iv);
        dst[16] = f2bf(o1[r] * iv);
    }
}

// ---------------- Kernel 4: output projection, 2-phase pipelined -------------
// Grid dim3(256,2): bm = blockIdx.x, bn = blockIdx.y (same-XCD A reuse).
__global__ __launch_bounds__(256) void proj_gemm(const uint16_t* __restrict__ A,
                                                 const uint16_t* __restrict__ W,
                                                 const float* __restrict__ Bv,
                                                 float* __restrict__ Out) {
    __shared__ uint16_t As[2][128 * 40];
    __shared__ uint16_t Bs[2][128 * 40];
    const int tid = threadIdx.x;
    const int bn = blockIdx.y * 128;
    const int bm = blockIdx.x * 128;
    const int lane = tid & 63, wv = tid >> 6;
    const int wm = (wv >> 1) * 64, wn = (wv & 1) * 64;
    const int lq = lane & 15, g = lane >> 4;
    const int srow = tid >> 1;
    const int scol = (tid & 1) * 16;

    const uint16_t* as = A + (size_t)(bm + srow) * 256 + scol;
    const uint16_t* wsrc = W + (size_t)(bn + srow) * 256 + scol;

    f4v acc[4][4] = {};
    u8v xa, xb, wa, wb;

    xa = *(const u8v*)(as);     xb = *(const u8v*)(as + 8);
    wa = *(const u8v*)(wsrc);   wb = *(const u8v*)(wsrc + 8);
    *(u8v*)(&As[0][srow * 40 + scol])     = xa;
    *(u8v*)(&As[0][srow * 40 + scol + 8]) = xb;
    *(u8v*)(&Bs[0][srow * 40 + scol])     = wa;
    *(u8v*)(&Bs[0][srow * 40 + scol + 8]) = wb;
    __syncthreads();

    for (int ks = 0; ks < 8; ++ks) {
        const int cur = ks & 1;
        if (ks < 7) {
            const int k1 = (ks + 1) * 32;
            xa = *(const u8v*)(as + k1);   xb = *(const u8v*)(as + k1 + 8);
            wa = *(const u8v*)(wsrc + k1); wb = *(const u8v*)(wsrc + k1 + 8);
        }
        s8v af[4], bf[4];
        #pragma unroll
        for (int i = 0; i < 4; ++i) {
            af[i] = *(const s8v*)(&As[cur][(wm + i * 16 + lq) * 40 + g * 8]);
            bf[i] = *(const s8v*)(&Bs[cur][(wn + i * 16 + lq) * 40 + g * 8]);
        }
        #pragma unroll
        for (int mt = 0; mt < 4; ++mt)
            #pragma unroll
            for (int nt = 0; nt < 4; ++nt)
                acc[mt][nt] = __builtin_amdgcn_mfma_f32_16x16x32_bf16(af[mt], bf[nt], acc[mt][nt], 0, 0, 0);
        if (ks < 7) {
            *(u8v*)(&As[cur ^ 1][srow * 40 + scol])     = xa;
            *(u8v*)(&As[cur ^ 1][srow * 40 + scol + 8]) = xb;
            *(u8v*)(&Bs[cur ^ 1][srow * 40 + scol])     = wa;
            *(u8v*)(&Bs[cur ^ 1][srow * 40 + scol + 8]) = wb;
        }
        __syncthreads();
    }

    #pragma unroll
    for (int nt = 0; nt < 4; ++nt) {
        const int n = bn + wn + nt * 16 + lq;
        const float bv = Bv[n];
        #pragma unroll
        for (int mt = 0; mt < 4; ++mt) {
            #pragma unroll
            for (int r = 0; r < 4; ++r) {
                const int mm = bm + wm + mt * 16 + g * 4 + r;
                Out[(size_t)mm * 256 + n] = acc[mt][nt][r] + bv;
            }
        }
    }
}

extern "C" void kernel_launch(void* const* d_in, const int* in_sizes, int n_in,
                              void* d_out, int out_size, void* d_ws, size_t ws_size,
                              hipStream_t stream) {
    const float* x      = (const float*)d_in[0];
    const float* qkv_w  = (const float*)d_in[1];
    const float* qkv_b  = (const float*)d_in[2];
    const float* proj_w = (const float*)d_in[3];
    const float* proj_b = (const float*)d_in[4];
    const float* rel    = (const float*)d_in[5];
    float* out = (float*)d_out;

    uint16_t* ws = (uint16_t*)d_ws;
    const size_t QE = (size_t)NB * NH * NS * ND;          // 8,388,608 elems
    uint16_t* Qb   = ws;                                  // 16 MiB
    uint16_t* Kb   = Qb + QE;                             // 16 MiB
    uint16_t* Vb   = Kb + QE;                             // 16 MiB
    uint16_t* Rb   = Vb + QE;                             // 16 MiB: AO
    uint16_t* REL2 = Rb + QE;                             // 8 x 20480 bf16 (320 KiB)
    uint16_t* Wqb  = REL2 + 163840;                       // 768x256 bf16 (384 KiB)
    uint16_t* Wpb  = Wqb + 196608;                        // 256x256 bf16 (128 KiB)

    cvt_w<<<128, 256, 0, stream>>>(qkv_w, proj_w, Wqb, Wpb);
    rel_fill<<<640, 256, 0, stream>>>(rel, REL2);
    qkv_gemm<<<dim3(256, 6), 256, 0, stream>>>(x, Wqb, qkv_b, Qb, Kb, Vb);
    attn_kern<<<2048, 512, 0, stream>>>(Qb, Kb, Vb, REL2, Rb);
    proj_gemm<<<dim3(256, 2), 256, 0, stream>>>(Rb, Wpb, proj_b, out);
}

// Round 19
// 99.462 us; speedup vs baseline: 2.4671x; 1.0442x over previous
//
#include <hip/hip_runtime.h>
#include <stdint.h>

#define NB 64
#define NS 512
#define NC 256
#define NH 8
#define ND 32

typedef __attribute__((ext_vector_type(8))) short s8v;
typedef __attribute__((ext_vector_type(8))) unsigned short u8v;
typedef __attribute__((ext_vector_type(4))) float f4v;

#define LOG2E 1.4426950408889634f

static __device__ __forceinline__ uint16_t f2bf(float f) {
    uint32_t u = __builtin_bit_cast(uint32_t, f);
    u += 0x7fffu + ((u >> 16) & 1u);
    return (uint16_t)(u >> 16);
}
static __device__ __forceinline__ float bf2f(uint16_t h) {
    uint32_t u = ((uint32_t)h) << 16;
    return __builtin_bit_cast(float, u);
}
static __device__ __forceinline__ uint32_t cvtpk(float lo, float hi) {
    uint32_t r;
    asm("v_cvt_pk_bf16_f32 %0, %1, %2" : "=v"(r) : "v"(lo), "v"(hi));
    return r;
}

// permlane pair-swaps (gfx950) -- R16-verified.
#if __has_builtin(__builtin_amdgcn_permlane32_swap)
static __device__ __forceinline__ void pl32(uint32_t& a, uint32_t& b) {
    auto r = __builtin_amdgcn_permlane32_swap(a, b, false, false);
    a = r[0]; b = r[1];
}
static __device__ __forceinline__ void pl16(uint32_t& a, uint32_t& b) {
    auto r = __builtin_amdgcn_permlane16_swap(a, b, false, false);
    a = r[0]; b = r[1];
}
#else
static __device__ __forceinline__ void pl32(uint32_t& a, uint32_t& b) {
    asm volatile("v_permlane32_swap_b32 %0, %1" : "+v"(a), "+v"(b));
}
static __device__ __forceinline__ void pl16(uint32_t& a, uint32_t& b) {
    asm volatile("v_permlane16_swap_b32 %0, %1" : "+v"(a), "+v"(b));
}
#endif

// ---------------- Kernel 0: merged setup (rel table + weight converts) -------
// Blocks [0,640): rel_fill body verbatim. Blocks [640,768): cvt_w body.
__global__ __launch_bounds__(256) void setup_kern(const float* __restrict__ rel,
                                                  const float* __restrict__ wq,
                                                  const float* __restrict__ wp,
                                                  uint16_t* __restrict__ rel2,
                                                  uint16_t* __restrict__ wqo,
                                                  uint16_t* __restrict__ wpo) {
    const int bid = blockIdx.x;
    if (bid < 640) {
        int id = bid * 256 + threadIdx.x;          // 8 * 64 * 320 = 163840
        int h = id / 20480, rem = id % 20480;
        int dt = rem / 320, q = rem % 320;
        int li = q / 20, lj = q % 20;
        float v = (lj < 16 && dt < 63) ? rel[(((dt << 4) + li) * 16 + lj) * 8 + h] * LOG2E : 0.f;
        rel2[id] = f2bf(v);
    } else {
        int i = ((bid - 640) * 256 + threadIdx.x) * 8;
        const float* src; uint16_t* dst; int off;
        if (i < 196608) { src = wq; dst = wqo; off = i; }
        else            { src = wp; dst = wpo; off = i - 196608; }
        f4v a = *(const f4v*)(src + off);
        f4v b = *(const f4v*)(src + off + 4);
        uint4 w;
        w.x = cvtpk(a[0], a[1]); w.y = cvtpk(a[2], a[3]);
        w.z = cvtpk(b[0], b[1]); w.w = cvtpk(b[2], b[3]);
        *(uint4*)(dst + off) = w;
    }
}

// ---------------- Kernel 2: QKV GEMM, depth-2 register pipeline --------------
// A = fp32 X (cvt-on-stage), B = bf16 W. Loads issued TWO k-steps ahead so the
// pre-ds_write vmcnt wait is covered by ~1.5 steps of compute. One barrier per
// step. V-epilogue permlane 16B stores (R18). Grid dim3(256,6) same-XCD reuse.
__global__ __launch_bounds__(256) void qkv_gemm(const float* __restrict__ X,
                                                const uint16_t* __restrict__ W,
                                                const float* __restrict__ Bv,
                                                uint16_t* __restrict__ Qo,
                                                uint16_t* __restrict__ Ko,
                                                uint16_t* __restrict__ Vo) {
    __shared__ uint16_t As[2][128 * 40];
    __shared__ uint16_t Bs[2][128 * 40];
    const int tid = threadIdx.x;
    const int bn = blockIdx.y * 128;
    const int bm = blockIdx.x * 128;
    const int lane = tid & 63, wv = tid >> 6;
    const int wm = (wv >> 1) * 64, wn = (wv & 1) * 64;
    const int lq = lane & 15, g = lane >> 4;
    const int srow = tid >> 1;
    const int scol = (tid & 1) * 16;

    const float* xs = X + (size_t)(bm + srow) * 256 + scol;
    const uint16_t* wsrc = W + (size_t)(bn + srow) * 256 + scol;

    f4v acc[4][4] = {};
    f4v xr[2][4];
    u8v wr[2][2];

#define LOAD_S(set, kel)                                                    \
    do {                                                                    \
        xr[set][0] = *(const f4v*)(xs + (kel));                             \
        xr[set][1] = *(const f4v*)(xs + (kel) + 4);                         \
        xr[set][2] = *(const f4v*)(xs + (kel) + 8);                         \
        xr[set][3] = *(const f4v*)(xs + (kel) + 12);                        \
        wr[set][0] = *(const u8v*)(wsrc + (kel));                           \
        wr[set][1] = *(const u8v*)(wsrc + (kel) + 8);                       \
    } while (0)

#define STORE_S(buf, set)                                                   \
    do {                                                                    \
        uint4 q0, q1;                                                       \
        q0.x = cvtpk(xr[set][0][0], xr[set][0][1]);                         \
        q0.y = cvtpk(xr[set][0][2], xr[set][0][3]);                         \
        q0.z = cvtpk(xr[set][1][0], xr[set][1][1]);                         \
        q0.w = cvtpk(xr[set][1][2], xr[set][1][3]);                         \
        q1.x = cvtpk(xr[set][2][0], xr[set][2][1]);                         \
        q1.y = cvtpk(xr[set][2][2], xr[set][2][3]);                         \
        q1.z = cvtpk(xr[set][3][0], xr[set][3][1]);                         \
        q1.w = cvtpk(xr[set][3][2], xr[set][3][3]);                         \
        *(uint4*)(&As[buf][srow * 40 + scol])     = q0;                     \
        *(uint4*)(&As[buf][srow * 40 + scol + 8]) = q1;                     \
        *(u8v*)(&Bs[buf][srow * 40 + scol])     = wr[set][0];               \
        *(u8v*)(&Bs[buf][srow * 40 + scol + 8]) = wr[set][1];               \
    } while (0)

    // prologue: k0 -> set0, k1 -> set1; set0 -> buf0
    LOAD_S(0, 0);
    LOAD_S(1, 32);
    STORE_S(0, 0);
    __syncthreads();

    #pragma unroll
    for (int ks = 0; ks < 8; ++ks) {
        const int cur = ks & 1;
        if (ks + 2 < 8) LOAD_S(cur, (ks + 2) * 32);  // set[cur] was consumed
        s8v af[4], bf[4];
        #pragma unroll
        for (int i = 0; i < 4; ++i) {
            af[i] = *(const s8v*)(&As[cur][(wm + i * 16 + lq) * 40 + g * 8]);
            bf[i] = *(const s8v*)(&Bs[cur][(wn + i * 16 + lq) * 40 + g * 8]);
        }
        #pragma unroll
        for (int mt = 0; mt < 4; ++mt)
            #pragma unroll
            for (int nt = 0; nt < 4; ++nt)
                acc[mt][nt] = __builtin_amdgcn_mfma_f32_16x16x32_bf16(af[mt], bf[nt], acc[mt][nt], 0, 0, 0);
        if (ks < 7) STORE_S(cur ^ 1, (ks + 1) & 1);  // k(ks+1), issued step ks-1
        __syncthreads();
    }
#undef LOAD_S
#undef STORE_S

    const int gsel = bn >> 8;   // 0=q, 1=k, 2=v
    if (gsel == 2) {
        // ---- V: permlane transform -> 8 consecutive s per lane, 16B store
        #pragma unroll
        for (int nt = 0; nt < 4; ++nt) {
            const int ng = bn + wn + nt * 16 + lq;
            const float bv = Bv[ng];
            const int c = ng & 255, hh = c >> 5, dd = c & 31;
            #pragma unroll
            for (int mtp = 0; mtp < 2; ++mtp) {
                f4v u = acc[mtp * 2][nt], v = acc[mtp * 2 + 1][nt];
                uint32_t A0 = cvtpk(u[0] + bv, u[1] + bv);
                uint32_t A1 = cvtpk(u[2] + bv, u[3] + bv);
                uint32_t B0 = cvtpk(v[0] + bv, v[1] + bv);
                uint32_t B1 = cvtpk(v[2] + bv, v[3] + bv);
                pl32(A0, B0); pl16(A0, B0);
                pl32(A1, B1); pl16(A1, B1);
                uint4 wq; wq.x = A0; wq.y = A1; wq.z = B0; wq.w = B1;
                const int m0 = bm + wm + mtp * 32;
                const int b = m0 >> 9;
                const int s0 = (m0 & 511) + g * 8;
                *(uint4*)(Vo + ((size_t)(b * 8 + hh) * 32 + dd) * 512 + s0) = wq;
            }
        }
    } else {
        const float scl = (gsel == 0) ? (0.35355339059327373f * LOG2E) : 1.0f;
        #pragma unroll
        for (int nt = 0; nt < 4; ++nt) {
            const int ng = bn + wn + nt * 16 + lq;
            const float bv = Bv[ng];
            const int c = ng & 255, hh = c >> 5, dd = c & 31;
            #pragma unroll
            for (int mt = 0; mt < 4; ++mt) {
                #pragma unroll
                for (int r = 0; r < 4; ++r) {
                    const int m = bm + wm + mt * 16 + g * 4 + r;
                    const int b = m >> 9, s = m & 511;
                    const uint16_t val = f2bf((acc[mt][nt][r] + bv) * scl);
                    if (gsel == 0) Qo[((size_t)(b * 8 + hh) * 512 + s) * 32 + dd] = val;
                    else           Ko[((size_t)(b * 8 + hh) * 512 + s) * 32 + dd] = val;
                }
            }
        }
    }
}

// ---------------- Kernel 3: flash attention (R18-green, unchanged) -----------
__global__ __launch_bounds__(512) void attn_kern(const uint16_t* __restrict__ Q,
                                                 const uint16_t* __restrict__ K,
                                                 const uint16_t* __restrict__ V,
                                                 const uint16_t* __restrict__ REL2,
                                                 uint16_t* __restrict__ AO) {
    __shared__ uint16_t Ks[64 * 40];               // K tile: 64 t-rows x 32 d (pad 40)
    __shared__ uint16_t Vs[32 * 80];               // V^T tile: 32 d-rows x 64 t (pad 80)
    __shared__ uint16_t Rel[64 * 320];             // padded rel slice (40 KB)

    const int p = blockIdx.x;
    const int h  = p & 7;                          // XCD-pinned head
    const int qq = (p >> 3) & 3;
    const int b  = p >> 5;
    const int tid = threadIdx.x, lane = tid & 63, wv = tid >> 6;
    const int lq = lane & 15, g = lane >> 4;
    const int bh = b * 8 + h;
    const int qw = qq * 128 + wv * 16;             // window-local q base of wave
    const int ti = (qw >> 4);                      // uniform per wave

    s8v qf = *(const s8v*)(Q + ((size_t)bh * 512 + qw + lq) * 32 + g * 8);
    const uint16_t* kg = K + (size_t)bh * 16384;   // K rows t, 32 d each
    const uint16_t* vg = V + (size_t)bh * 16384;   // V^T rows d, 512 t each

    // ---- stage the per-head padded rel slice once (line-dense) ----
    {
        const uint16_t* rsrc = REL2 + (size_t)h * 20480;
        #pragma unroll
        for (int it = 0; it < 5; ++it) {
            int off = it * 4096 + tid * 8;
            *(u8v*)(Rel + off) = *(const u8v*)(rsrc + off);
        }
    }

    // staging indices: lower half stages K, upper half stages V (line-dense)
    const bool isK = (tid < 256);
    const int t2 = tid & 255;
    const int ktrow = t2 >> 2, ktcol = (t2 & 3) * 8;     // 64 rows x 32 elems
    const int vtrow = t2 >> 3, vtcol = (t2 & 7) * 8;     // 32 rows x 64 elems
    const uint16_t* gsrc = isK ? (kg + (size_t)ktrow * 32 + ktcol)
                               : (vg + (size_t)vtrow * 512 + vtcol);
    uint16_t* ldst = isK ? (Ks + ktrow * 40 + ktcol)
                         : (Vs + vtrow * 80 + vtcol);
    const int gstep = isK ? (64 * 32) : 64;        // per-tile advance (elems)

    f4v o0 = {}, o1 = {};
    float mrow = -3.0e38f, lrow = 0.f;

    // prologue: load tile 0 into registers
    u8v sreg = *(const u8v*)(gsrc);

    for (int tile = 0; tile < 8; ++tile) {
        const int t0 = tile * 64;

        __syncthreads();                           // prev tile's LDS reads done
        *(u8v*)(ldst) = sreg;
        __syncthreads();                           // writes visible (incl. Rel @ tile 0)

        // issue-early: next tile's global loads hide under this tile's compute
        if (tile < 7) {
            sreg = *(const u8v*)(gsrc + (size_t)(tile + 1) * gstep);
        }

        // ---- S-tile = bias (C-init from padded LDS rel) + K.Q^T, log2 domain
        f4v a0, a1, a2, a3;
        {
            const int tj0 = t0 >> 4;               // uniform per wave
            const uint16_t* rb = Rel + lq * 20 + g * 4;
            ushort4 z0 = *(const ushort4*)(rb + (ti - tj0 - 0 + 31) * 320);
            ushort4 z1 = *(const ushort4*)(rb + (ti - tj0 - 1 + 31) * 320);
            ushort4 z2 = *(const ushort4*)(rb + (ti - tj0 - 2 + 31) * 320);
            ushort4 z3 = *(const ushort4*)(rb + (ti - tj0 - 3 + 31) * 320);
            a0[0]=bf2f(z0.x); a0[1]=bf2f(z0.y); a0[2]=bf2f(z0.z); a0[3]=bf2f(z0.w);
            a1[0]=bf2f(z1.x); a1[1]=bf2f(z1.y); a1[2]=bf2f(z1.z); a1[3]=bf2f(z1.w);
            a2[0]=bf2f(z2.x); a2[1]=bf2f(z2.y); a2[2]=bf2f(z2.z); a2[3]=bf2f(z2.w);
            a3[0]=bf2f(z3.x); a3[1]=bf2f(z3.y); a3[2]=bf2f(z3.z); a3[3]=bf2f(z3.w);
        }
        a0 = __builtin_amdgcn_mfma_f32_16x16x32_bf16(*(const s8v*)(Ks + ( 0 + lq) * 40 + g * 8), qf, a0, 0, 0, 0);
        a1 = __builtin_amdgcn_mfma_f32_16x16x32_bf16(*(const s8v*)(Ks + (16 + lq) * 40 + g * 8), qf, a1, 0, 0, 0);
        a2 = __builtin_amdgcn_mfma_f32_16x16x32_bf16(*(const s8v*)(Ks + (32 + lq) * 40 + g * 8), qf, a2, 0, 0, 0);
        a3 = __builtin_amdgcn_mfma_f32_16x16x32_bf16(*(const s8v*)(Ks + (48 + lq) * 40 + g * 8), qf, a3, 0, 0, 0);

        // ---- row max (green) ----
        float p01 = fmaxf(fmaxf(a0[0], a0[1]), fmaxf(a0[2], a0[3]));
        float p23 = fmaxf(fmaxf(a1[0], a1[1]), fmaxf(a1[2], a1[3]));
        float p45 = fmaxf(fmaxf(a2[0], a2[1]), fmaxf(a2[2], a2[3]));
        float p67 = fmaxf(fmaxf(a3[0], a3[1]), fmaxf(a3[2], a3[3]));
        float pmax = fmaxf(fmaxf(p01, p23), fmaxf(p45, p67));
        pmax = fmaxf(pmax, __shfl_xor(pmax, 16));
        pmax = fmaxf(pmax, __shfl_xor(pmax, 32));

        // ---- online-softmax update, defer-rescale threshold 8 (green) ----
        if (!__all(pmax - mrow <= 8.0f)) {
            float mnew = fmaxf(mrow, pmax);
            float scale = __builtin_amdgcn_exp2f(mrow - mnew);
            lrow *= scale;
            float s0 = __shfl(scale, g * 4 + 0);
            float s1 = __shfl(scale, g * 4 + 1);
            float s2 = __shfl(scale, g * 4 + 2);
            float s3 = __shfl(scale, g * 4 + 3);
            o0[0] *= s0; o0[1] *= s1; o0[2] *= s2; o0[3] *= s3;
            o1[0] *= s0; o1[1] *= s1; o1[2] *= s2; o1[3] *= s3;
            mrow = mnew;
        }

        // ---- P = exp2(S - m), per-lane partial row-sum (green) ----
        float lsum = 0.f;
        #pragma unroll
        for (int r = 0; r < 4; ++r) {
            a0[r] = __builtin_amdgcn_exp2f(a0[r] - mrow); lsum += a0[r];
            a1[r] = __builtin_amdgcn_exp2f(a1[r] - mrow); lsum += a1[r];
            a2[r] = __builtin_amdgcn_exp2f(a2[r] - mrow); lsum += a2[r];
            a3[r] = __builtin_amdgcn_exp2f(a3[r] - mrow); lsum += a3[r];
        }
        lrow += lsum;

        // ---- P -> PV A-fragments via permlane swaps (R16-verified) ----
        {   // tc = 0: chunks a0,a1
            uint32_t A0 = cvtpk(a0[0], a0[1]);
            uint32_t A1 = cvtpk(a0[2], a0[3]);
            uint32_t B0 = cvtpk(a1[0], a1[1]);
            uint32_t B1 = cvtpk(a1[2], a1[3]);
            pl32(A0, B0); pl16(A0, B0);
            pl32(A1, B1); pl16(A1, B1);
            uint4 wq; wq.x = A0; wq.y = A1; wq.z = B0; wq.w = B1;
            s8v pf = __builtin_bit_cast(s8v, wq);
            s8v vf0 = *(const s8v*)(Vs + lq * 80 + g * 8);
            s8v vf2 = *(const s8v*)(Vs + (lq + 16) * 80 + g * 8);
            o0 = __builtin_amdgcn_mfma_f32_16x16x32_bf16(pf, vf0, o0, 0, 0, 0);
            o1 = __builtin_amdgcn_mfma_f32_16x16x32_bf16(pf, vf2, o1, 0, 0, 0);
        }
        {   // tc = 1: chunks a2,a3
            uint32_t A0 = cvtpk(a2[0], a2[1]);
            uint32_t A1 = cvtpk(a2[2], a2[3]);
            uint32_t B0 = cvtpk(a3[0], a3[1]);
            uint32_t B1 = cvtpk(a3[2], a3[3]);
            pl32(A0, B0); pl16(A0, B0);
            pl32(A1, B1); pl16(A1, B1);
            uint4 wq; wq.x = A0; wq.y = A1; wq.z = B0; wq.w = B1;
            s8v pf = __builtin_bit_cast(s8v, wq);
            s8v vf1 = *(const s8v*)(Vs + lq * 80 + 32 + g * 8);
            s8v vf3 = *(const s8v*)(Vs + (lq + 16) * 80 + 32 + g * 8);
            o0 = __builtin_amdgcn_mfma_f32_16x16x32_bf16(pf, vf1, o0, 0, 0, 0);
            o1 = __builtin_amdgcn_mfma_f32_16x16x32_bf16(pf, vf3, o1, 0, 0, 0);
        }
    }

    // ---- finalize: row sum across g, normalize, store (green) ----
    lrow += __shfl_xor(lrow, 16);
    lrow += __shfl_xor(lrow, 32);
    const float inv = 1.0f / lrow;                 // valid for row lq
    #pragma unroll
    for (int r = 0; r < 4; ++r) {
        const float iv = __shfl(inv, g * 4 + r);   // row g*4+r's denom
        const int srow = b * 512 + qw + g * 4 + r;
        uint16_t* dst = AO + (size_t)srow * 256 + h * 32 + lq;
        dst[0]  = f2bf(o0[r] * iv);
        dst[16] = f2bf(o1[r] * iv);
    }
}

// ---------------- Kernel 4: output projection, depth-2 pipeline --------------
// Grid dim3(256,2): bm = blockIdx.x, bn = blockIdx.y (same-XCD A reuse).
__global__ __launch_bounds__(256) void proj_gemm(const uint16_t* __restrict__ A,
                                                 const uint16_t* __restrict__ W,
                                                 const float* __restrict__ Bv,
                                                 float* __restrict__ Out) {
    __shared__ uint16_t As[2][128 * 40];
    __shared__ uint16_t Bs[2][128 * 40];
    const int tid = threadIdx.x;
    const int bn = blockIdx.y * 128;
    const int bm = blockIdx.x * 128;
    const int lane = tid & 63, wv = tid >> 6;
    const int wm = (wv >> 1) * 64, wn = (wv & 1) * 64;
    const int lq = lane & 15, g = lane >> 4;
    const int srow = tid >> 1;
    const int scol = (tid & 1) * 16;

    const uint16_t* as = A + (size_t)(bm + srow) * 256 + scol;
    const uint16_t* wsrc = W + (size_t)(bn + srow) * 256 + scol;

    f4v acc[4][4] = {};
    u8v ar[2][2], wr[2][2];

#define LOAD_P(set, kel)                                                    \
    do {                                                                    \
        ar[set][0] = *(const u8v*)(as + (kel));                             \
        ar[set][1] = *(const u8v*)(as + (kel) + 8);                         \
        wr[set][0] = *(const u8v*)(wsrc + (kel));                           \
        wr[set][1] = *(const u8v*)(wsrc + (kel) + 8);                       \
    } while (0)

#define STORE_P(buf, set)                                                   \
    do {                                                                    \
        *(u8v*)(&As[buf][srow * 40 + scol])     = ar[set][0];               \
        *(u8v*)(&As[buf][srow * 40 + scol + 8]) = ar[set][1];               \
        *(u8v*)(&Bs[buf][srow * 40 + scol])     = wr[set][0];               \
        *(u8v*)(&Bs[buf][srow * 40 + scol + 8]) = wr[set][1];               \
    } while (0)

    LOAD_P(0, 0);
    LOAD_P(1, 32);
    STORE_P(0, 0);
    __syncthreads();

    #pragma unroll
    for (int ks = 0; ks < 8; ++ks) {
        const int cur = ks & 1;
        if (ks + 2 < 8) LOAD_P(cur, (ks + 2) * 32);
        s8v af[4], bf[4];
        #pragma unroll
        for (int i = 0; i < 4; ++i) {
            af[i] = *(const s8v*)(&As[cur][(wm + i * 16 + lq) * 40 + g * 8]);
            bf[i] = *(const s8v*)(&Bs[cur][(wn + i * 16 + lq) * 40 + g * 8]);
        }
        #pragma unroll
        for (int mt = 0; mt < 4; ++mt)
            #pragma unroll
            for (int nt = 0; nt < 4; ++nt)
                acc[mt][nt] = __builtin_amdgcn_mfma_f32_16x16x32_bf16(af[mt], bf[nt], acc[mt][nt], 0, 0, 0);
        if (ks < 7) STORE_P(cur ^ 1, (ks + 1) & 1);
        __syncthreads();
    }
#undef LOAD_P
#undef STORE_P

    #pragma unroll
    for (int nt = 0; nt < 4; ++nt) {
        const int n = bn + wn + nt * 16 + lq;
        const float bv = Bv[n];
        #pragma unroll
        for (int mt = 0; mt < 4; ++mt) {
            #pragma unroll
            for (int r = 0; r < 4; ++r) {
                const int mm = bm + wm + mt * 16 + g * 4 + r;
                Out[(size_t)mm * 256 + n] = acc[mt][nt][r] + bv;
            }
        }
    }
}

extern "C" void kernel_launch(void* const* d_in, const int* in_sizes, int n_in,
                              void* d_out, int out_size, void* d_ws, size_t ws_size,
                              hipStream_t stream) {
    const float* x      = (const float*)d_in[0];
    const float* qkv_w  = (const float*)d_in[1];
    const float* qkv_b  = (const float*)d_in[2];
    const float* proj_w = (const float*)d_in[3];
    const float* proj_b = (const float*)d_in[4];
    const float* rel    = (const float*)d_in[5];
    float* out = (float*)d_out;

    uint16_t* ws = (uint16_t*)d_ws;
    const size_t QE = (size_t)NB * NH * NS * ND;          // 8,388,608 elems
    uint16_t* Qb   = ws;                                  // 16 MiB
    uint16_t* Kb   = Qb + QE;                             // 16 MiB
    uint16_t* Vb   = Kb + QE;                             // 16 MiB
    uint16_t* Rb   = Vb + QE;                             // 16 MiB: AO
    uint16_t* REL2 = Rb + QE;                             // 8 x 20480 bf16 (320 KiB)
    uint16_t* Wqb  = REL2 + 163840;                       // 768x256 bf16 (384 KiB)
    uint16_t* Wpb  = Wqb + 196608;                        // 256x256 bf16 (128 KiB)

    setup_kern<<<768, 256, 0, stream>>>(rel, qkv_w, proj_w, REL2, Wqb, Wpb);
    qkv_gemm<<<dim3(256, 6), 256, 0, stream>>>(x, Wqb, qkv_b, Qb, Kb, Vb);
    attn_kern<<<2048, 512, 0, stream>>>(Qb, Kb, Vb, REL2, Rb);
    proj_gemm<<<dim3(256, 2), 256, 0, stream>>>(Rb, Wpb, proj_b, out);
}

// Round 20
// 98.660 us; speedup vs baseline: 2.4871x; 1.0081x over previous
//
#include <hip/hip_runtime.h>
#include <stdint.h>

#define NB 64
#define NS 512
#define NC 256
#define NH 8
#define ND 32

typedef __attribute__((ext_vector_type(8))) short s8v;
typedef __attribute__((ext_vector_type(8))) unsigned short u8v;
typedef __attribute__((ext_vector_type(4))) float f4v;

#define LOG2E 1.4426950408889634f

static __device__ __forceinline__ uint16_t f2bf(float f) {
    uint32_t u = __builtin_bit_cast(uint32_t, f);
    u += 0x7fffu + ((u >> 16) & 1u);
    return (uint16_t)(u >> 16);
}
static __device__ __forceinline__ float bf2f(uint16_t h) {
    uint32_t u = ((uint32_t)h) << 16;
    return __builtin_bit_cast(float, u);
}
static __device__ __forceinline__ uint32_t cvtpk(float lo, float hi) {
    uint32_t r;
    asm("v_cvt_pk_bf16_f32 %0, %1, %2" : "=v"(r) : "v"(lo), "v"(hi));
    return r;
}

// permlane pair-swaps (gfx950) -- R16-verified.
#if __has_builtin(__builtin_amdgcn_permlane32_swap)
static __device__ __forceinline__ void pl32(uint32_t& a, uint32_t& b) {
    auto r = __builtin_amdgcn_permlane32_swap(a, b, false, false);
    a = r[0]; b = r[1];
}
static __device__ __forceinline__ void pl16(uint32_t& a, uint32_t& b) {
    auto r = __builtin_amdgcn_permlane16_swap(a, b, false, false);
    a = r[0]; b = r[1];
}
#else
static __device__ __forceinline__ void pl32(uint32_t& a, uint32_t& b) {
    asm volatile("v_permlane32_swap_b32 %0, %1" : "+v"(a), "+v"(b));
}
static __device__ __forceinline__ void pl16(uint32_t& a, uint32_t& b) {
    asm volatile("v_permlane16_swap_b32 %0, %1" : "+v"(a), "+v"(b));
}
#endif

// ---------------- Kernel 0: merged setup (rel table + weight converts) -------
__global__ __launch_bounds__(256) void setup_kern(const float* __restrict__ rel,
                                                  const float* __restrict__ wq,
                                                  const float* __restrict__ wp,
                                                  uint16_t* __restrict__ rel2,
                                                  uint16_t* __restrict__ wqo,
                                                  uint16_t* __restrict__ wpo) {
    const int bid = blockIdx.x;
    if (bid < 640) {
        int id = bid * 256 + threadIdx.x;          // 8 * 64 * 320 = 163840
        int h = id / 20480, rem = id % 20480;
        int dt = rem / 320, q = rem % 320;
        int li = q / 20, lj = q % 20;
        float v = (lj < 16 && dt < 63) ? rel[(((dt << 4) + li) * 16 + lj) * 8 + h] * LOG2E : 0.f;
        rel2[id] = f2bf(v);
    } else {
        int i = ((bid - 640) * 256 + threadIdx.x) * 8;
        const float* src; uint16_t* dst; int off;
        if (i < 196608) { src = wq; dst = wqo; off = i; }
        else            { src = wp; dst = wpo; off = i - 196608; }
        f4v a = *(const f4v*)(src + off);
        f4v b = *(const f4v*)(src + off + 4);
        uint4 w;
        w.x = cvtpk(a[0], a[1]); w.y = cvtpk(a[2], a[3]);
        w.z = cvtpk(b[0], b[1]); w.w = cvtpk(b[2], b[3]);
        *(uint4*)(dst + off) = w;
    }
}

// ---------------- Kernel 2: QKV GEMM, depth-2 register pipeline (R19) --------
__global__ __launch_bounds__(256) void qkv_gemm(const float* __restrict__ X,
                                                const uint16_t* __restrict__ W,
                                                const float* __restrict__ Bv,
                                                uint16_t* __restrict__ Qo,
                                                uint16_t* __restrict__ Ko,
                                                uint16_t* __restrict__ Vo) {
    __shared__ uint16_t As[2][128 * 40];
    __shared__ uint16_t Bs[2][128 * 40];
    const int tid = threadIdx.x;
    const int bn = blockIdx.y * 128;
    const int bm = blockIdx.x * 128;
    const int lane = tid & 63, wv = tid >> 6;
    const int wm = (wv >> 1) * 64, wn = (wv & 1) * 64;
    const int lq = lane & 15, g = lane >> 4;
    const int srow = tid >> 1;
    const int scol = (tid & 1) * 16;

    const float* xs = X + (size_t)(bm + srow) * 256 + scol;
    const uint16_t* wsrc = W + (size_t)(bn + srow) * 256 + scol;

    f4v acc[4][4] = {};
    f4v xr[2][4];
    u8v wr[2][2];

#define LOAD_S(set, kel)                                                    \
    do {                                                                    \
        xr[set][0] = *(const f4v*)(xs + (kel));                             \
        xr[set][1] = *(const f4v*)(xs + (kel) + 4);                         \
        xr[set][2] = *(const f4v*)(xs + (kel) + 8);                         \
        xr[set][3] = *(const f4v*)(xs + (kel) + 12);                        \
        wr[set][0] = *(const u8v*)(wsrc + (kel));                           \
        wr[set][1] = *(const u8v*)(wsrc + (kel) + 8);                       \
    } while (0)

#define STORE_S(buf, set)                                                   \
    do {                                                                    \
        uint4 q0, q1;                                                       \
        q0.x = cvtpk(xr[set][0][0], xr[set][0][1]);                         \
        q0.y = cvtpk(xr[set][0][2], xr[set][0][3]);                         \
        q0.z = cvtpk(xr[set][1][0], xr[set][1][1]);                         \
        q0.w = cvtpk(xr[set][1][2], xr[set][1][3]);                         \
        q1.x = cvtpk(xr[set][2][0], xr[set][2][1]);                         \
        q1.y = cvtpk(xr[set][2][2], xr[set][2][3]);                         \
        q1.z = cvtpk(xr[set][3][0], xr[set][3][1]);                         \
        q1.w = cvtpk(xr[set][3][2], xr[set][3][3]);                         \
        *(uint4*)(&As[buf][srow * 40 + scol])     = q0;                     \
        *(uint4*)(&As[buf][srow * 40 + scol + 8]) = q1;                     \
        *(u8v*)(&Bs[buf][srow * 40 + scol])     = wr[set][0];               \
        *(u8v*)(&Bs[buf][srow * 40 + scol + 8]) = wr[set][1];               \
    } while (0)

    LOAD_S(0, 0);
    LOAD_S(1, 32);
    STORE_S(0, 0);
    __syncthreads();

    #pragma unroll
    for (int ks = 0; ks < 8; ++ks) {
        const int cur = ks & 1;
        if (ks + 2 < 8) LOAD_S(cur, (ks + 2) * 32);
        s8v af[4], bf[4];
        #pragma unroll
        for (int i = 0; i < 4; ++i) {
            af[i] = *(const s8v*)(&As[cur][(wm + i * 16 + lq) * 40 + g * 8]);
            bf[i] = *(const s8v*)(&Bs[cur][(wn + i * 16 + lq) * 40 + g * 8]);
        }
        #pragma unroll
        for (int mt = 0; mt < 4; ++mt)
            #pragma unroll
            for (int nt = 0; nt < 4; ++nt)
                acc[mt][nt] = __builtin_amdgcn_mfma_f32_16x16x32_bf16(af[mt], bf[nt], acc[mt][nt], 0, 0, 0);
        if (ks < 7) STORE_S(cur ^ 1, (ks + 1) & 1);
        __syncthreads();
    }
#undef LOAD_S
#undef STORE_S

    const int gsel = bn >> 8;   // 0=q, 1=k, 2=v
    if (gsel == 2) {
        #pragma unroll
        for (int nt = 0; nt < 4; ++nt) {
            const int ng = bn + wn + nt * 16 + lq;
            const float bv = Bv[ng];
            const int c = ng & 255, hh = c >> 5, dd = c & 31;
            #pragma unroll
            for (int mtp = 0; mtp < 2; ++mtp) {
                f4v u = acc[mtp * 2][nt], v = acc[mtp * 2 + 1][nt];
                uint32_t A0 = cvtpk(u[0] + bv, u[1] + bv);
                uint32_t A1 = cvtpk(u[2] + bv, u[3] + bv);
                uint32_t B0 = cvtpk(v[0] + bv, v[1] + bv);
                uint32_t B1 = cvtpk(v[2] + bv, v[3] + bv);
                pl32(A0, B0); pl16(A0, B0);
                pl32(A1, B1); pl16(A1, B1);
                uint4 wq; wq.x = A0; wq.y = A1; wq.z = B0; wq.w = B1;
                const int m0 = bm + wm + mtp * 32;
                const int b = m0 >> 9;
                const int s0 = (m0 & 511) + g * 8;
                *(uint4*)(Vo + ((size_t)(b * 8 + hh) * 32 + dd) * 512 + s0) = wq;
            }
        }
    } else {
        const float scl = (gsel == 0) ? (0.35355339059327373f * LOG2E) : 1.0f;
        #pragma unroll
        for (int nt = 0; nt < 4; ++nt) {
            const int ng = bn + wn + nt * 16 + lq;
            const float bv = Bv[ng];
            const int c = ng & 255, hh = c >> 5, dd = c & 31;
            #pragma unroll
            for (int mt = 0; mt < 4; ++mt) {
                #pragma unroll
                for (int r = 0; r < 4; ++r) {
                    const int m = bm + wm + mt * 16 + g * 4 + r;
                    const int b = m >> 9, s = m & 511;
                    const uint16_t val = f2bf((acc[mt][nt][r] + bv) * scl);
                    if (gsel == 0) Qo[((size_t)(b * 8 + hh) * 512 + s) * 32 + dd] = val;
                    else           Ko[((size_t)(b * 8 + hh) * 512 + s) * 32 + dd] = val;
                }
            }
        }
    }
}

// ---------------- Kernel 3: flash attention, l via ones-column MFMA ----------
// R19-green structure. ONE change: the softmax denominator is accumulated by
// ol = mfma(pf, ones, ol) on the (13%-idle) matrix pipe -- B = all-ones makes
// every column of C the row-sum, so lane (g,lq) reg r holds l for row 4g+r
// directly. Deletes 16 lsum adds/tile + lrow bookkeeping + the 6-shuffle
// epilogue reduction. Rescale scales ol with the same per-row factors.
__global__ __launch_bounds__(512) void attn_kern(const uint16_t* __restrict__ Q,
                                                 const uint16_t* __restrict__ K,
                                                 const uint16_t* __restrict__ V,
                                                 const uint16_t* __restrict__ REL2,
                                                 uint16_t* __restrict__ AO) {
    __shared__ uint16_t Ks[64 * 40];               // K tile: 64 t-rows x 32 d (pad 40)
    __shared__ uint16_t Vs[32 * 80];               // V^T tile: 32 d-rows x 64 t (pad 80)
    __shared__ uint16_t Rel[64 * 320];             // padded rel slice (40 KB)

    const int p = blockIdx.x;
    const int h  = p & 7;                          // XCD-pinned head
    const int qq = (p >> 3) & 3;
    const int b  = p >> 5;
    const int tid = threadIdx.x, lane = tid & 63, wv = tid >> 6;
    const int lq = lane & 15, g = lane >> 4;
    const int bh = b * 8 + h;
    const int qw = qq * 128 + wv * 16;             // window-local q base of wave
    const int ti = (qw >> 4);                      // uniform per wave

    s8v qf = *(const s8v*)(Q + ((size_t)bh * 512 + qw + lq) * 32 + g * 8);
    const uint16_t* kg = K + (size_t)bh * 16384;   // K rows t, 32 d each
    const uint16_t* vg = V + (size_t)bh * 16384;   // V^T rows d, 512 t each

    // all-ones bf16 B-operand for the denominator MFMA
    const uint32_t one2 = 0x3F803F80u;
    uint4 onesw; onesw.x = one2; onesw.y = one2; onesw.z = one2; onesw.w = one2;
    const s8v onesv = __builtin_bit_cast(s8v, onesw);

    // ---- stage the per-head padded rel slice once (line-dense) ----
    {
        const uint16_t* rsrc = REL2 + (size_t)h * 20480;
        #pragma unroll
        for (int it = 0; it < 5; ++it) {
            int off = it * 4096 + tid * 8;
            *(u8v*)(Rel + off) = *(const u8v*)(rsrc + off);
        }
    }

    // staging indices: lower half stages K, upper half stages V (line-dense)
    const bool isK = (tid < 256);
    const int t2 = tid & 255;
    const int ktrow = t2 >> 2, ktcol = (t2 & 3) * 8;     // 64 rows x 32 elems
    const int vtrow = t2 >> 3, vtcol = (t2 & 7) * 8;     // 32 rows x 64 elems
    const uint16_t* gsrc = isK ? (kg + (size_t)ktrow * 32 + ktcol)
                               : (vg + (size_t)vtrow * 512 + vtcol);
    uint16_t* ldst = isK ? (Ks + ktrow * 40 + ktcol)
                         : (Vs + vtrow * 80 + vtcol);
    const int gstep = isK ? (64 * 32) : 64;        // per-tile advance (elems)

    f4v o0 = {}, o1 = {}, ol = {};
    float mrow = -3.0e38f;

    // prologue: load tile 0 into registers
    u8v sreg = *(const u8v*)(gsrc);

    for (int tile = 0; tile < 8; ++tile) {
        const int t0 = tile * 64;

        __syncthreads();                           // prev tile's LDS reads done
        *(u8v*)(ldst) = sreg;
        __syncthreads();                           // writes visible (incl. Rel @ tile 0)

        // issue-early: next tile's global loads hide under this tile's compute
        if (tile < 7) {
            sreg = *(const u8v*)(gsrc + (size_t)(tile + 1) * gstep);
        }

        // ---- S-tile = bias (C-init from padded LDS rel) + K.Q^T, log2 domain
        f4v a0, a1, a2, a3;
        {
            const int tj0 = t0 >> 4;               // uniform per wave
            const uint16_t* rb = Rel + lq * 20 + g * 4;
            ushort4 z0 = *(const ushort4*)(rb + (ti - tj0 - 0 + 31) * 320);
            ushort4 z1 = *(const ushort4*)(rb + (ti - tj0 - 1 + 31) * 320);
            ushort4 z2 = *(const ushort4*)(rb + (ti - tj0 - 2 + 31) * 320);
            ushort4 z3 = *(const ushort4*)(rb + (ti - tj0 - 3 + 31) * 320);
            a0[0]=bf2f(z0.x); a0[1]=bf2f(z0.y); a0[2]=bf2f(z0.z); a0[3]=bf2f(z0.w);
            a1[0]=bf2f(z1.x); a1[1]=bf2f(z1.y); a1[2]=bf2f(z1.z); a1[3]=bf2f(z1.w);
            a2[0]=bf2f(z2.x); a2[1]=bf2f(z2.y); a2[2]=bf2f(z2.z); a2[3]=bf2f(z2.w);
            a3[0]=bf2f(z3.x); a3[1]=bf2f(z3.y); a3[2]=bf2f(z3.z); a3[3]=bf2f(z3.w);
        }
        a0 = __builtin_amdgcn_mfma_f32_16x16x32_bf16(*(const s8v*)(Ks + ( 0 + lq) * 40 + g * 8), qf, a0, 0, 0, 0);
        a1 = __builtin_amdgcn_mfma_f32_16x16x32_bf16(*(const s8v*)(Ks + (16 + lq) * 40 + g * 8), qf, a1, 0, 0, 0);
        a2 = __builtin_amdgcn_mfma_f32_16x16x32_bf16(*(const s8v*)(Ks + (32 + lq) * 40 + g * 8), qf, a2, 0, 0, 0);
        a3 = __builtin_amdgcn_mfma_f32_16x16x32_bf16(*(const s8v*)(Ks + (48 + lq) * 40 + g * 8), qf, a3, 0, 0, 0);

        // ---- row max (green) ----
        float p01 = fmaxf(fmaxf(a0[0], a0[1]), fmaxf(a0[2], a0[3]));
        float p23 = fmaxf(fmaxf(a1[0], a1[1]), fmaxf(a1[2], a1[3]));
        float p45 = fmaxf(fmaxf(a2[0], a2[1]), fmaxf(a2[2], a2[3]));
        float p67 = fmaxf(fmaxf(a3[0], a3[1]), fmaxf(a3[2], a3[3]));
        float pmax = fmaxf(fmaxf(p01, p23), fmaxf(p45, p67));
        pmax = fmaxf(pmax, __shfl_xor(pmax, 16));
        pmax = fmaxf(pmax, __shfl_xor(pmax, 32));

        // ---- online-softmax update, defer-rescale threshold 8 (green) ----
        if (!__all(pmax - mrow <= 8.0f)) {
            float mnew = fmaxf(mrow, pmax);
            float scale = __builtin_amdgcn_exp2f(mrow - mnew);
            float s0 = __shfl(scale, g * 4 + 0);
            float s1 = __shfl(scale, g * 4 + 1);
            float s2 = __shfl(scale, g * 4 + 2);
            float s3 = __shfl(scale, g * 4 + 3);
            o0[0] *= s0; o0[1] *= s1; o0[2] *= s2; o0[3] *= s3;
            o1[0] *= s0; o1[1] *= s1; o1[2] *= s2; o1[3] *= s3;
            ol[0] *= s0; ol[1] *= s1; ol[2] *= s2; ol[3] *= s3;
            mrow = mnew;
        }

        // ---- P = exp2(S - m) (no scalar row-sum; l comes from MFMA) ----
        #pragma unroll
        for (int r = 0; r < 4; ++r) {
            a0[r] = __builtin_amdgcn_exp2f(a0[r] - mrow);
            a1[r] = __builtin_amdgcn_exp2f(a1[r] - mrow);
            a2[r] = __builtin_amdgcn_exp2f(a2[r] - mrow);
            a3[r] = __builtin_amdgcn_exp2f(a3[r] - mrow);
        }

        // ---- P -> PV A-fragments via permlane swaps (R16-verified) ----
        {   // tc = 0: chunks a0,a1
            uint32_t A0 = cvtpk(a0[0], a0[1]);
            uint32_t A1 = cvtpk(a0[2], a0[3]);
            uint32_t B0 = cvtpk(a1[0], a1[1]);
            uint32_t B1 = cvtpk(a1[2], a1[3]);
            pl32(A0, B0); pl16(A0, B0);
            pl32(A1, B1); pl16(A1, B1);
            uint4 wq; wq.x = A0; wq.y = A1; wq.z = B0; wq.w = B1;
            s8v pf = __builtin_bit_cast(s8v, wq);
            s8v vf0 = *(const s8v*)(Vs + lq * 80 + g * 8);
            s8v vf2 = *(const s8v*)(Vs + (lq + 16) * 80 + g * 8);
            o0 = __builtin_amdgcn_mfma_f32_16x16x32_bf16(pf, vf0, o0, 0, 0, 0);
            o1 = __builtin_amdgcn_mfma_f32_16x16x32_bf16(pf, vf2, o1, 0, 0, 0);
            ol = __builtin_amdgcn_mfma_f32_16x16x32_bf16(pf, onesv, ol, 0, 0, 0);
        }
        {   // tc = 1: chunks a2,a3
            uint32_t A0 = cvtpk(a2[0], a2[1]);
            uint32_t A1 = cvtpk(a2[2], a2[3]);
            uint32_t B0 = cvtpk(a3[0], a3[1]);
            uint32_t B1 = cvtpk(a3[2], a3[3]);
            pl32(A0, B0); pl16(A0, B0);
            pl32(A1, B1); pl16(A1, B1);
            uint4 wq; wq.x = A0; wq.y = A1; wq.z = B0; wq.w = B1;
            s8v pf = __builtin_bit_cast(s8v, wq);
            s8v vf1 = *(const s8v*)(Vs + lq * 80 + 32 + g * 8);
            s8v vf3 = *(const s8v*)(Vs + (lq + 16) * 80 + 32 + g * 8);
            o0 = __builtin_amdgcn_mfma_f32_16x16x32_bf16(pf, vf1, o0, 0, 0, 0);
            o1 = __builtin_amdgcn_mfma_f32_16x16x32_bf16(pf, vf3, o1, 0, 0, 0);
            ol = __builtin_amdgcn_mfma_f32_16x16x32_bf16(pf, onesv, ol, 0, 0, 0);
        }
    }

    // ---- finalize: lane already holds l for row 4g+r in ol[r] ----
    #pragma unroll
    for (int r = 0; r < 4; ++r) {
        const float iv = 1.0f / ol[r];
        const int srow = b * 512 + qw + g * 4 + r;
        uint16_t* dst = AO + (size_t)srow * 256 + h * 32 + lq;
        dst[0]  = f2bf(o0[r] * iv);
        dst[16] = f2bf(o1[r] * iv);
    }
}

// ---------------- Kernel 4: output projection, depth-2 pipeline (R19) --------
__global__ __launch_bounds__(256) void proj_gemm(const uint16_t* __restrict__ A,
                                                 const uint16_t* __restrict__ W,
                                                 const float* __restrict__ Bv,
                                                 float* __restrict__ Out) {
    __shared__ uint16_t As[2][128 * 40];
    __shared__ uint16_t Bs[2][128 * 40];
    const int tid = threadIdx.x;
    const int bn = blockIdx.y * 128;
    const int bm = blockIdx.x * 128;
    const int lane = tid & 63, wv = tid >> 6;
    const int wm = (wv >> 1) * 64, wn = (wv & 1) * 64;
    const int lq = lane & 15, g = lane >> 4;
    const int srow = tid >> 1;
    const int scol = (tid & 1) * 16;

    const uint16_t* as = A + (size_t)(bm + srow) * 256 + scol;
    const uint16_t* wsrc = W + (size_t)(bn + srow) * 256 + scol;

    f4v acc[4][4] = {};
    u8v ar[2][2], wr[2][2];

#define LOAD_P(set, kel)                                                    \
    do {                                                                    \
        ar[set][0] = *(const u8v*)(as + (kel));                             \
        ar[set][1] = *(const u8v*)(as + (kel) + 8);                         \
        wr[set][0] = *(const u8v*)(wsrc + (kel));                           \
        wr[set][1] = *(const u8v*)(wsrc + (kel) + 8);                       \
    } while (0)

#define STORE_P(buf, set)                                                   \
    do {                                                                    \
        *(u8v*)(&As[buf][srow * 40 + scol])     = ar[set][0];               \
        *(u8v*)(&As[buf][srow * 40 + scol + 8]) = ar[set][1];               \
        *(u8v*)(&Bs[buf][srow * 40 + scol])     = wr[set][0];               \
        *(u8v*)(&Bs[buf][srow * 40 + scol + 8]) = wr[set][1];               \
    } while (0)

    LOAD_P(0, 0);
    LOAD_P(1, 32);
    STORE_P(0, 0);
    __syncthreads();

    #pragma unroll
    for (int ks = 0; ks < 8; ++ks) {
        const int cur = ks & 1;
        if (ks + 2 < 8) LOAD_P(cur, (ks + 2) * 32);
        s8v af[4], bf[4];
        #pragma unroll
        for (int i = 0; i < 4; ++i) {
            af[i] = *(const s8v*)(&As[cur][(wm + i * 16 + lq) * 40 + g * 8]);
            bf[i] = *(const s8v*)(&Bs[cur][(wn + i * 16 + lq) * 40 + g * 8]);
        }
        #pragma unroll
        for (int mt = 0; mt < 4; ++mt)
            #pragma unroll
            for (int nt = 0; nt < 4; ++nt)
                acc[mt][nt] = __builtin_amdgcn_mfma_f32_16x16x32_bf16(af[mt], bf[nt], acc[mt][nt], 0, 0, 0);
        if (ks < 7) STORE_P(cur ^ 1, (ks + 1) & 1);
        __syncthreads();
    }
#undef LOAD_P
#undef STORE_P

    #pragma unroll
    for (int nt = 0; nt < 4; ++nt) {
        const int n = bn + wn + nt * 16 + lq;
        const float bv = Bv[n];
        #pragma unroll
        for (int mt = 0; mt < 4; ++mt) {
            #pragma unroll
            for (int r = 0; r < 4; ++r) {
                const int mm = bm + wm + mt * 16 + g * 4 + r;
                Out[(size_t)mm * 256 + n] = acc[mt][nt][r] + bv;
            }
        }
    }
}

extern "C" void kernel_launch(void* const* d_in, const int* in_sizes, int n_in,
                              void* d_out, int out_size, void* d_ws, size_t ws_size,
                              hipStream_t stream) {
    const float* x      = (const float*)d_in[0];
    const float* qkv_w  = (const float*)d_in[1];
    const float* qkv_b  = (const float*)d_in[2];
    const float* proj_w = (const float*)d_in[3];
    const float* proj_b = (const float*)d_in[4];
    const float* rel    = (const float*)d_in[5];
    float* out = (float*)d_out;

    uint16_t* ws = (uint16_t*)d_ws;
    const size_t QE = (size_t)NB * NH * NS * ND;          // 8,388,608 elems
    uint16_t* Qb   = ws;                                  // 16 MiB
    uint16_t* Kb   = Qb + QE;                             // 16 MiB
    uint16_t* Vb   = Kb + QE;                             // 16 MiB
    uint16_t* Rb   = Vb + QE;                             // 16 MiB: AO
    uint16_t* REL2 = Rb + QE;                             // 8 x 20480 bf16 (320 KiB)
    uint16_t* Wqb  = REL2 + 163840;                       // 768x256 bf16 (384 KiB)
    uint16_t* Wpb  = Wqb + 196608;                        // 256x256 bf16 (128 KiB)

    setup_kern<<<768, 256, 0, stream>>>(rel, qkv_w, proj_w, REL2, Wqb, Wpb);
    qkv_gemm<<<dim3(256, 6), 256, 0, stream>>>(x, Wqb, qkv_b, Qb, Kb, Vb);
    attn_kern<<<2048, 512, 0, stream>>>(Qb, Kb, Vb, REL2, Rb);
    proj_gemm<<<dim3(256, 2), 256, 0, stream>>>(Rb, Wpb, proj_b, out);
}